// Round 5
// baseline (1551.626 us; speedup 1.0000x reference)
//
#include <hip/hip_runtime.h>
#include <math.h>

// B=128, S=256, G=8, CMAX=6, T=32, E=64, NH=4, dh=16, L=2, DFF=256, Z=3

typedef short bf16x8 __attribute__((ext_vector_type(8)));
typedef float f32x4 __attribute__((ext_vector_type(4)));

__device__ __forceinline__ unsigned short f2bf(float f) {
  unsigned u = __float_as_uint(f);
  u += 0x7fffu + ((u >> 16) & 1u);   // RNE
  return (unsigned short)(u >> 16);
}

__device__ __forceinline__ bf16x8 ldfrag(const unsigned short* p) {
  return *reinterpret_cast<const bf16x8*>(p);
}

__device__ __forceinline__ void ld4(const float* p, float* dst) {
  float4 t = *reinterpret_cast<const float4*>(p);
  dst[0] = t.x; dst[1] = t.y; dst[2] = t.z; dst[3] = t.w;
}

__device__ __forceinline__ bool is_masked(const void* mask_, int flag, int idx) {
  return flag ? (((const unsigned char*)mask_)[idx] != 0)
              : (((const int*)mask_)[idx] != 0);
}

// Detect mask dtype (int32 vs byte-packed bool); zero counters.
__global__ void detect_mask_kernel(const unsigned int* __restrict__ mw,
                                   int* __restrict__ flag, int* __restrict__ counts,
                                   int* __restrict__ lens) {
  __shared__ int sh;
  if (threadIdx.x == 0) sh = 0;
  __syncthreads();
  int bad = 0;
  for (int i = threadIdx.x; i < 8192; i += 256)
    if (mw[i] > 1u) bad = 1;
  if (bad) atomicOr(&sh, 1);
  if (threadIdx.x < 8) counts[threadIdx.x] = 0;
  if (threadIdx.x < 128) lens[threadIdx.x] = 0;
  __syncthreads();
  if (threadIdx.x == 0) *flag = sh;
}

// Bin active tokens by shank id. Hierarchical atomics (8-way LDS -> 1 global/g).
__global__ __launch_bounds__(256) void bin_kernel(
    const int* __restrict__ sid, const void* __restrict__ mask_,
    const int* __restrict__ flagp, int* __restrict__ counts,
    int* __restrict__ lens, int* __restrict__ idxbuf) {
  __shared__ int lcnt[8];
  __shared__ int lbase[8];
  int b = blockIdx.x, tid = threadIdx.x;
  int n = b * 256 + tid;
  int flag = *flagp;
  bool act = !is_masked(mask_, flag, n);
  int g = act ? sid[n] : 0;
  if (tid < 8) lcnt[tid] = 0;
  __syncthreads();
  int pos = 0;
  if (act) pos = atomicAdd(&lcnt[g], 1);
  __syncthreads();
  if (tid < 8) lbase[tid] = atomicAdd(&counts[tid], lcnt[tid]);
  if (tid == 0)
    lens[b] = lcnt[0] + lcnt[1] + lcnt[2] + lcnt[3] +
              lcnt[4] + lcnt[5] + lcnt[6] + lcnt[7];
  __syncthreads();
  if (act) idxbuf[g * 32768 + lbase[g] + pos] = n;
}

// Base embedding: shank_emb[sid] + positional encoding.
__global__ __launch_bounds__(256) void init_emb_kernel(
    const int* __restrict__ sid, const float* __restrict__ shank_emb,
    float* __restrict__ hout) {
  int i = blockIdx.x * 256 + threadIdx.x;
  int n = i >> 6, e = i & 63, s = n & 255;
  int g = sid[n];
  float div = __expf(-(float)(e & ~1) * (9.21034037f / 64.f));
  float angle = (float)s * div;
  float pe = (e & 1) ? cosf(angle) : sinf(angle);
  hout[i] = shank_emb[g * 64 + e] + pe;
}

// Conv encoder via bf16 MFMA, vectorized float4 waveform staging.
#define CONV_BPG 64
__global__ __launch_bounds__(256) void conv_mfma_kernel(
    const int* __restrict__ idxbuf, const int* __restrict__ counts,
    const float* __restrict__ wav,
    const float* __restrict__ w1_, const float* __restrict__ b1_,
    const float* __restrict__ w2_, const float* __restrict__ b2_,
    float* __restrict__ hout) {
  __shared__ __align__(16) unsigned short w1f[5][32][8];    // [tap][oc][ic pad8]
  __shared__ __align__(16) unsigned short w2f[3][64][40];   // [tap][e][ic pad40]
  __shared__ float b1s[32];
  __shared__ float b2s[64];
  __shared__ __align__(16) unsigned short xT[8][36][8];     // [tok][tpad][ic pad8]
  __shared__ __align__(16) unsigned short h1T[8][34][40];   // [tok][tpad][oc pad40]
  int g = blockIdx.x & 7, bib = blockIdx.x >> 3;
  int tid = threadIdx.x;
  int wv = tid >> 6, lane = tid & 63, quad = lane >> 4, l15 = lane & 15;
  for (int i = tid; i < 1280; i += 256) {
    int k = i >> 8, rest = i & 255, oc = rest >> 3, ic = rest & 7;
    w1f[k][oc][ic] = (ic < 6) ? f2bf(w1_[g * 960 + oc * 30 + ic * 5 + k]) : 0;
  }
  for (int i = tid; i < 7680; i += 256) {
    int k = i / 2560, rest = i % 2560, e = rest / 40, ic = rest % 40;
    w2f[k][e][ic] = (ic < 32) ? f2bf(w2_[g * 6144 + e * 96 + ic * 3 + k]) : 0;
  }
  if (tid < 32) b1s[tid] = b1_[g * 32 + tid];
  if (tid < 64) b2s[tid] = b2_[g * 64 + tid];
  // zero entire xT once (pads + ic 6,7 stay zero forever)
  {
    unsigned int* xz = (unsigned int*)&xT[0][0][0];
    for (int i = tid; i < 1152; i += 256) xz[i] = 0;
  }
  for (int i = tid; i < 640; i += 256) {
    int tok = i / 80, rest = i % 80;
    h1T[tok][(rest >= 40) ? 33 : 0][rest % 40] = 0;
  }
  __syncthreads();
  bf16x8 zf = {0, 0, 0, 0, 0, 0, 0, 0};
  bf16x8 bf1[2], bf1k4[2], bf2[3][4];
#pragma unroll
  for (int nt = 0; nt < 2; nt++) {
    bf1[nt] = ldfrag(&w1f[quad][nt * 16 + l15][0]);
    bf1k4[nt] = (quad == 0) ? ldfrag(&w1f[4][nt * 16 + l15][0]) : zf;
  }
#pragma unroll
  for (int k = 0; k < 3; k++)
#pragma unroll
    for (int nt = 0; nt < 4; nt++)
      bf2[k][nt] = ldfrag(&w2f[k][nt * 16 + l15][quad * 8]);
  float b1v0 = b1s[l15], b1v1 = b1s[16 + l15];
  int cnt = counts[g];
  for (int base = bib * 8; base < cnt; base += CONV_BPG * 8) {
    __syncthreads();
    // vectorized staging: 8 tok x 6 ic x 8 t-quads of float4
    for (int i = tid; i < 384; i += 256) {
      int tok = i / 48, rem = i % 48, ic = rem >> 3, tq = rem & 7;
      int ti = base + tok;
      float4 v = make_float4(0.f, 0.f, 0.f, 0.f);
      if (ti < cnt)
        v = *(const float4*)&wav[idxbuf[g * 32768 + ti] * 192 + ic * 32 + tq * 4];
      int r0 = tq * 4 + 2;
      xT[tok][r0 + 0][ic] = f2bf(v.x);
      xT[tok][r0 + 1][ic] = f2bf(v.y);
      xT[tok][r0 + 2][ic] = f2bf(v.z);
      xT[tok][r0 + 3][ic] = f2bf(v.w);
    }
    __syncthreads();
#pragma unroll
    for (int ts = 0; ts < 2; ts++) {
      int tk = wv * 2 + ts;
      f32x4 c1[2][2];
#pragma unroll
      for (int mt = 0; mt < 2; mt++) {
        c1[mt][0] = (f32x4){b1v0, b1v0, b1v0, b1v0};
        c1[mt][1] = (f32x4){b1v1, b1v1, b1v1, b1v1};
      }
#pragma unroll
      for (int mt = 0; mt < 2; mt++) {
        bf16x8 afm = ldfrag(&xT[tk][mt * 16 + l15 + quad][0]);
        bf16x8 af4 = (quad == 0) ? ldfrag(&xT[tk][mt * 16 + l15 + 4][0]) : zf;
#pragma unroll
        for (int nt = 0; nt < 2; nt++) {
          c1[mt][nt] = __builtin_amdgcn_mfma_f32_16x16x32_bf16(afm, bf1[nt], c1[mt][nt], 0, 0, 0);
          c1[mt][nt] = __builtin_amdgcn_mfma_f32_16x16x32_bf16(af4, bf1k4[nt], c1[mt][nt], 0, 0, 0);
        }
      }
#pragma unroll
      for (int mt = 0; mt < 2; mt++)
#pragma unroll
        for (int nt = 0; nt < 2; nt++)
#pragma unroll
          for (int r = 0; r < 4; r++) {
            int t = mt * 16 + quad * 4 + r;
            h1T[tk][t + 1][nt * 16 + l15] = f2bf(fmaxf(c1[mt][nt][r], 0.f));
          }
    }
    __syncthreads();
#pragma unroll
    for (int ts = 0; ts < 2; ts++) {
      int tk = wv * 2 + ts;
      f32x4 c2[2][4];
#pragma unroll
      for (int mt = 0; mt < 2; mt++)
#pragma unroll
        for (int nt = 0; nt < 4; nt++) {
          float bv = b2s[nt * 16 + l15];
          c2[mt][nt] = (f32x4){bv, bv, bv, bv};
        }
#pragma unroll
      for (int k = 0; k < 3; k++)
#pragma unroll
        for (int mt = 0; mt < 2; mt++) {
          bf16x8 af = ldfrag(&h1T[tk][mt * 16 + l15 + k][quad * 8]);
#pragma unroll
          for (int nt = 0; nt < 4; nt++)
            c2[mt][nt] = __builtin_amdgcn_mfma_f32_16x16x32_bf16(af, bf2[k][nt], c2[mt][nt], 0, 0, 0);
        }
      int ti = base + tk;
      float sums[4];
#pragma unroll
      for (int nt = 0; nt < 4; nt++) {
        float s = 0.f;
#pragma unroll
        for (int mt = 0; mt < 2; mt++)
#pragma unroll
          for (int r = 0; r < 4; r++) s += fmaxf(c2[mt][nt][r], 0.f);
        s += __shfl_xor(s, 16);
        s += __shfl_xor(s, 32);
        sums[nt] = s;
      }
      if (ti < cnt && quad == 0) {
        int n = idxbuf[g * 32768 + ti];
#pragma unroll
        for (int nt = 0; nt < 4; nt++)
          hout[n * 64 + nt * 16 + l15] += sums[nt] * (1.f / 32.f);
      }
    }
  }
}

// bf16-MFMA GEMM, full-N per block: out = A[M][K] @ W[N][K]^T + bias.
// MODE 0: store C. MODE 1: relu, store C. MODE 2 (NT==4): H = LayerNorm(H + out).
template <int NT, int MODE>
__global__ __launch_bounds__(256) void gemm_nt(
    const float* __restrict__ A, const float* __restrict__ W,
    const float* __restrict__ bias, float* __restrict__ C,
    float* __restrict__ H, const float* __restrict__ lng,
    const float* __restrict__ lnb, int K) {
  constexpr int N = NT * 16;
  __shared__ __align__(16) unsigned short As[64][72];
  __shared__ __align__(16) unsigned short Bs[N][72];
  int m0 = blockIdx.x * 64;
  int tid = threadIdx.x;
  int wv = tid >> 6, lane = tid & 63, quad = lane >> 4, l15 = lane & 15;
  f32x4 acc[NT];
#pragma unroll
  for (int nt = 0; nt < NT; nt++) {
    float b = bias[nt * 16 + l15];
    acc[nt] = (f32x4){b, b, b, b};
  }
  for (int kc = 0; kc < K; kc += 64) {
    __syncthreads();
    for (int i = tid; i < 1024; i += 256) {
      int r = i >> 4, c4 = (i & 15) << 2;
      float4 av = *(const float4*)&A[(size_t)(m0 + r) * K + kc + c4];
      short4 t;
      t.x = (short)f2bf(av.x); t.y = (short)f2bf(av.y);
      t.z = (short)f2bf(av.z); t.w = (short)f2bf(av.w);
      *(short4*)&As[r][c4] = t;
    }
    for (int i = tid; i < N * 16; i += 256) {
      int r = i >> 4, c4 = (i & 15) << 2;
      float4 wv4 = *(const float4*)&W[(size_t)r * K + kc + c4];
      short4 u;
      u.x = (short)f2bf(wv4.x); u.y = (short)f2bf(wv4.y);
      u.z = (short)f2bf(wv4.z); u.w = (short)f2bf(wv4.w);
      *(short4*)&Bs[r][c4] = u;
    }
    __syncthreads();
#pragma unroll
    for (int ks = 0; ks < 64; ks += 32) {
      bf16x8 af = ldfrag(&As[wv * 16 + l15][ks + quad * 8]);
#pragma unroll
      for (int nt = 0; nt < NT; nt++) {
        bf16x8 bfr = ldfrag(&Bs[nt * 16 + l15][ks + quad * 8]);
        acc[nt] = __builtin_amdgcn_mfma_f32_16x16x32_bf16(af, bfr, acc[nt], 0, 0, 0);
      }
    }
  }
  int mrow = m0 + wv * 16 + quad * 4;
  if (MODE <= 1) {
#pragma unroll
    for (int nt = 0; nt < NT; nt++)
#pragma unroll
      for (int r = 0; r < 4; r++) {
        float v = acc[nt][r];
        if (MODE == 1) v = fmaxf(v, 0.f);
        C[(size_t)(mrow + r) * N + nt * 16 + l15] = v;
      }
  } else {
#pragma unroll
    for (int r = 0; r < 4; r++) {
      float rv[4];
      float s = 0.f;
#pragma unroll
      for (int nt = 0; nt < 4; nt++) {
        float v = acc[nt][r] + H[(size_t)(mrow + r) * 64 + nt * 16 + l15];
        rv[nt] = v; s += v;
      }
      s += __shfl_xor(s, 1); s += __shfl_xor(s, 2);
      s += __shfl_xor(s, 4); s += __shfl_xor(s, 8);
      float mean = s * (1.f / 64.f);
      float vsum = 0.f;
#pragma unroll
      for (int nt = 0; nt < 4; nt++) { rv[nt] -= mean; vsum += rv[nt] * rv[nt]; }
      vsum += __shfl_xor(vsum, 1); vsum += __shfl_xor(vsum, 2);
      vsum += __shfl_xor(vsum, 4); vsum += __shfl_xor(vsum, 8);
      float inv = rsqrtf(vsum * (1.f / 64.f) + 1e-5f);
#pragma unroll
      for (int nt = 0; nt < 4; nt++) {
        int col = nt * 16 + l15;
        H[(size_t)(mrow + r) * 64 + col] = rv[nt] * inv * lng[col] + lnb[col];
      }
    }
  }
}

// Attention: block = (b, head); thread = (4 queries, key-slice of 4).
// K/V staged once per block; chunk-of-4 online softmax; shfl merge over slices.
__global__ __launch_bounds__(256) void attn_kernel(
    const float* __restrict__ qkv, const int* __restrict__ lens,
    float* __restrict__ o) {
  __shared__ __align__(16) float ks[256][16];
  __shared__ __align__(16) float vs[256][16];
  int bh = blockIdx.x;
  int b_ = bh >> 2, hd = bh & 3;
  int tid = threadIdx.x;
  int len = lens[b_];
  const float* base = qkv + b_ * 256 * 192;
  for (int i = tid; i < 1024; i += 256) {
    int s = i >> 2, c = (i & 3) << 2;
    *(float4*)&ks[s][c] = *(const float4*)&base[s * 192 + 64 + hd * 16 + c];
    *(float4*)&vs[s][c] = *(const float4*)&base[s * 192 + 128 + hd * 16 + c];
  }
  __syncthreads();
  int qg = tid >> 2, slice = tid & 3;
  float qv[4][16];
#pragma unroll
  for (int j = 0; j < 4; j++) {
    const float* qp = base + (qg * 4 + j) * 192 + hd * 16;
#pragma unroll
    for (int d = 0; d < 16; d++) qv[j][d] = qp[d] * 0.25f;
  }
  float m[4] = {-1e30f, -1e30f, -1e30f, -1e30f};
  float l[4] = {};
  float acc[4][16] = {};
  for (int c0 = slice; c0 < len; c0 += 16) {
    float scb[4][4];
#pragma unroll
    for (int u = 0; u < 4; u++) {
      int kk = c0 + u * 4;
      int kc = min(kk, 255);
      float kv[16];
#pragma unroll
      for (int c = 0; c < 4; c++) ld4(&ks[kc][c * 4], &kv[c * 4]);
#pragma unroll
      for (int j = 0; j < 4; j++) {
        float sc = 0.f;
#pragma unroll
        for (int d = 0; d < 16; d++) sc += qv[j][d] * kv[d];
        scb[j][u] = (kk < len) ? sc : -1e30f;
      }
    }
#pragma unroll
    for (int j = 0; j < 4; j++) {
      float cm = fmaxf(fmaxf(scb[j][0], scb[j][1]), fmaxf(scb[j][2], scb[j][3]));
      float mn = fmaxf(m[j], cm);
      float al = __expf(m[j] - mn);
      l[j] *= al;
#pragma unroll
      for (int d = 0; d < 16; d++) acc[j][d] *= al;
      m[j] = mn;
#pragma unroll
      for (int u = 0; u < 4; u++) {
        float pu = __expf(scb[j][u] - mn);
        l[j] += pu;
        scb[j][u] = pu;
      }
    }
#pragma unroll
    for (int u = 0; u < 4; u++) {
      int kc = min(c0 + u * 4, 255);
      float vv[16];
#pragma unroll
      for (int c = 0; c < 4; c++) ld4(&vs[kc][c * 4], &vv[c * 4]);
#pragma unroll
      for (int j = 0; j < 4; j++)
#pragma unroll
        for (int d = 0; d < 16; d++) acc[j][d] += scb[j][u] * vv[d];
    }
  }
  // merge the 4 key-slices (lanes differing in bits 0-1)
#pragma unroll
  for (int off = 1; off <= 2; off <<= 1) {
#pragma unroll
    for (int j = 0; j < 4; j++) {
      float mo = __shfl_xor(m[j], off);
      float lo = __shfl_xor(l[j], off);
      float mn = fmaxf(m[j], mo);
      float sa = __expf(m[j] - mn), sb = __expf(mo - mn);
      l[j] = l[j] * sa + lo * sb;
#pragma unroll
      for (int d = 0; d < 16; d++) {
        float ao = __shfl_xor(acc[j][d], off);
        acc[j][d] = acc[j][d] * sa + ao * sb;
      }
      m[j] = mn;
    }
  }
#pragma unroll
  for (int j = 0; j < 4; j++) {
    float inv = 1.f / l[j];
    float* op = o + (b_ * 256 + qg * 4 + j) * 64 + hd * 16 + slice * 4;
    float4 w;
    w.x = acc[j][slice * 4 + 0] * inv;
    w.y = acc[j][slice * 4 + 1] * inv;
    w.z = acc[j][slice * 4 + 2] * inv;
    w.w = acc[j][slice * 4 + 3] * inv;
    *(float4*)op = w;
  }
}

// Masked mean pool using per-b active length.
__global__ __launch_bounds__(256) void pool_kernel(
    const float* __restrict__ h, const int* __restrict__ lens,
    float* __restrict__ pooled) {
  __shared__ float ps[4][64];
  int b = blockIdx.x;
  int e = threadIdx.x & 63, sp = threadIdx.x >> 6;
  int len = lens[b];
  float sum = 0.f;
  int send = min(sp * 64 + 64, len);
  for (int s = sp * 64; s < send; s++) sum += h[(b * 256 + s) * 64 + e];
  ps[sp][e] = sum;
  __syncthreads();
  if (sp == 0) {
    float tot = ps[0][e] + ps[1][e] + ps[2][e] + ps[3][e];
    pooled[b * 64 + e] = tot / ((float)len + 1e-8f);
  }
}

// Fused heads: cls(3), mus(6), sigmas(6), d(1) -> 16 outputs per b.
__global__ __launch_bounds__(64) void heads_kernel(
    const float* __restrict__ pooled,
    const float* __restrict__ cls_w1, const float* __restrict__ cls_b1,
    const float* __restrict__ cls_w2, const float* __restrict__ cls_b2,
    const float* __restrict__ mu_w1, const float* __restrict__ mu_b1,
    const float* __restrict__ mu_w2, const float* __restrict__ mu_b2,
    const float* __restrict__ ls_w1, const float* __restrict__ ls_b1,
    const float* __restrict__ ls_w2, const float* __restrict__ ls_b2,
    const float* __restrict__ d_w1, const float* __restrict__ d_b1,
    const float* __restrict__ d_w2, const float* __restrict__ d_b2,
    float* __restrict__ out) {
  int b = blockIdx.x, e = threadIdx.x;
  __shared__ float p[64];
  __shared__ float t1[64];
  p[e] = pooled[b * 64 + e];
  __syncthreads();
  {
    float a = cls_b1[e];
    for (int j = 0; j < 64; j++) a += p[j] * cls_w1[e * 64 + j];
    t1[e] = fmaxf(a, 0.f);
  }
  __syncthreads();
  if (e < 3) {
    float a2 = cls_b2[e];
    for (int j = 0; j < 64; j++) a2 += t1[j] * cls_w2[e * 64 + j];
    out[b * 16 + e] = a2;
  }
  for (int z = 0; z < 3; z++) {
    __syncthreads();
    {
      float a = mu_b1[z * 64 + e];
      for (int j = 0; j < 64; j++) a += p[j] * mu_w1[(z * 64 + e) * 64 + j];
      t1[e] = fmaxf(a, 0.f);
    }
    __syncthreads();
    if (e < 2) {
      float a2 = mu_b2[z * 2 + e];
      for (int j = 0; j < 64; j++) a2 += t1[j] * mu_w2[(z * 2 + e) * 64 + j];
      out[b * 16 + 3 + z * 2 + e] = a2;
    }
    __syncthreads();
    {
      float a = ls_b1[z * 64 + e];
      for (int j = 0; j < 64; j++) a += p[j] * ls_w1[(z * 64 + e) * 64 + j];
      t1[e] = fmaxf(a, 0.f);
    }
    __syncthreads();
    if (e < 2) {
      float a2 = ls_b2[z * 2 + e];
      for (int j = 0; j < 64; j++) a2 += t1[j] * ls_w2[(z * 2 + e) * 64 + j];
      out[b * 16 + 9 + z * 2 + e] = __expf(a2);
    }
  }
  __syncthreads();
  {
    float a = d_b1[e];
    for (int j = 0; j < 64; j++) a += p[j] * d_w1[e * 64 + j];
    t1[e] = fmaxf(a, 0.f);
  }
  __syncthreads();
  if (e == 0) {
    float a2 = d_b2[0];
    for (int j = 0; j < 64; j++) a2 += t1[j] * d_w2[j];
    out[b * 16 + 15] = 1.f / (1.f + __expf(-a2));
  }
}

extern "C" void kernel_launch(void* const* d_in, const int* in_sizes, int n_in,
                              void* d_out, int out_size, void* d_ws, size_t ws_size,
                              hipStream_t stream) {
  const float* wav       = (const float*)d_in[0];
  const int*   sid       = (const int*)d_in[1];
  const void*  mask      = d_in[2];
  const float* conv1_w   = (const float*)d_in[3];
  const float* conv1_b   = (const float*)d_in[4];
  const float* conv2_w   = (const float*)d_in[5];
  const float* conv2_b   = (const float*)d_in[6];
  const float* shank_emb = (const float*)d_in[7];
  const float* in_proj_w = (const float*)d_in[8];
  const float* in_proj_b = (const float*)d_in[9];
  const float* out_proj_w= (const float*)d_in[10];
  const float* out_proj_b= (const float*)d_in[11];
  const float* ln1_g     = (const float*)d_in[12];
  const float* ln1_b     = (const float*)d_in[13];
  const float* ff1_w     = (const float*)d_in[14];
  const float* ff1_b     = (const float*)d_in[15];
  const float* ff2_w     = (const float*)d_in[16];
  const float* ff2_b     = (const float*)d_in[17];
  const float* ln2_g     = (const float*)d_in[18];
  const float* ln2_b     = (const float*)d_in[19];
  const float* cls_w1    = (const float*)d_in[20];
  const float* cls_b1    = (const float*)d_in[21];
  const float* cls_w2    = (const float*)d_in[22];
  const float* cls_b2    = (const float*)d_in[23];
  const float* mu_w1     = (const float*)d_in[24];
  const float* mu_b1     = (const float*)d_in[25];
  const float* mu_w2     = (const float*)d_in[26];
  const float* mu_b2     = (const float*)d_in[27];
  const float* ls_w1     = (const float*)d_in[28];
  const float* ls_b1     = (const float*)d_in[29];
  const float* ls_w2     = (const float*)d_in[30];
  const float* ls_b2     = (const float*)d_in[31];
  const float* d_w1      = (const float*)d_in[32];
  const float* d_b1      = (const float*)d_in[33];
  const float* d_w2      = (const float*)d_in[34];
  const float* d_b2      = (const float*)d_in[35];
  float* out = (float*)d_out;

  float* ws = (float*)d_ws;
  float* h      = ws;                    // [32768,64]
  float* qkv    = ws + 2097152;          // [32768,192]
  float* obuf   = ws + 8388608;          // [32768,64] attn out
  float* ff     = ws + 2097152;          // [32768,256] aliases qkv+obuf (dead by ff1)
  float* pooled = ws + 10485760;         // [128,64]
  int*   ip     = (int*)(ws + 10493952);
  int*   flag   = ip;
  int*   counts = ip + 8;
  int*   lens   = ip + 16;               // [128]
  int*   idxbuf = ip + 144;              // [8][32768]

  detect_mask_kernel<<<1, 256, 0, stream>>>((const unsigned int*)mask, flag, counts, lens);
  bin_kernel<<<128, 256, 0, stream>>>(sid, mask, flag, counts, lens, idxbuf);
  init_emb_kernel<<<8192, 256, 0, stream>>>(sid, shank_emb, h);
  conv_mfma_kernel<<<CONV_BPG * 8, 256, 0, stream>>>(idxbuf, counts, wav, conv1_w, conv1_b,
                                                     conv2_w, conv2_b, h);
  for (int l = 0; l < 2; l++) {
    gemm_nt<12, 0><<<512, 256, 0, stream>>>(
        h, in_proj_w + l * 12288, in_proj_b + l * 192, qkv, nullptr, nullptr, nullptr, 64);
    attn_kernel<<<512, 256, 0, stream>>>(qkv, lens, obuf);
    gemm_nt<4, 2><<<512, 256, 0, stream>>>(
        obuf, out_proj_w + l * 4096, out_proj_b + l * 64, nullptr, h,
        ln1_g + l * 64, ln1_b + l * 64, 64);
    gemm_nt<16, 1><<<512, 256, 0, stream>>>(
        h, ff1_w + l * 16384, ff1_b + l * 256, ff, nullptr, nullptr, nullptr, 64);
    gemm_nt<4, 2><<<512, 256, 0, stream>>>(
        ff, ff2_w + l * 16384, ff2_b + l * 64, nullptr, h,
        ln2_g + l * 64, ln2_b + l * 64, 256);
  }
  pool_kernel<<<128, 256, 0, stream>>>(h, lens, pooled);
  heads_kernel<<<128, 64, 0, stream>>>(pooled, cls_w1, cls_b1, cls_w2, cls_b2,
                                       mu_w1, mu_b1, mu_w2, mu_b2,
                                       ls_w1, ls_b1, ls_w2, ls_b2,
                                       d_w1, d_b1, d_w2, d_b2, out);
}

// Round 6
// 485.860 us; speedup vs baseline: 3.1936x; 3.1936x over previous
//
#include <hip/hip_runtime.h>
#include <math.h>

// B=128, S=256, G=8, CMAX=6, T=32, E=64, NH=4, dh=16, L=2, DFF=256, Z=3

typedef short bf16x8 __attribute__((ext_vector_type(8)));
typedef float f32x4 __attribute__((ext_vector_type(4)));

__device__ __forceinline__ unsigned short f2bf(float f) {
  unsigned u = __float_as_uint(f);
  u += 0x7fffu + ((u >> 16) & 1u);   // RNE
  return (unsigned short)(u >> 16);
}

__device__ __forceinline__ float bflo(unsigned u) { return __uint_as_float(u << 16); }
__device__ __forceinline__ float bfhi(unsigned u) { return __uint_as_float(u & 0xffff0000u); }

__device__ __forceinline__ bf16x8 ldfrag(const unsigned short* p) {
  return *reinterpret_cast<const bf16x8*>(p);
}

__device__ __forceinline__ void ld4(const float* p, float* dst) {
  float4 t = *reinterpret_cast<const float4*>(p);
  dst[0] = t.x; dst[1] = t.y; dst[2] = t.z; dst[3] = t.w;
}

__device__ __forceinline__ bool is_masked(const void* mask_, int flag, int idx) {
  return flag ? (((const unsigned char*)mask_)[idx] != 0)
              : (((const int*)mask_)[idx] != 0);
}

// Detect mask dtype (int32 vs byte-packed bool); zero counters.
__global__ void detect_mask_kernel(const unsigned int* __restrict__ mw,
                                   int* __restrict__ flag, int* __restrict__ counts,
                                   int* __restrict__ lens) {
  __shared__ int sh;
  if (threadIdx.x == 0) sh = 0;
  __syncthreads();
  int bad = 0;
  for (int i = threadIdx.x; i < 8192; i += 256)
    if (mw[i] > 1u) bad = 1;
  if (bad) atomicOr(&sh, 1);
  if (threadIdx.x < 8) counts[threadIdx.x] = 0;
  if (threadIdx.x < 128) lens[threadIdx.x] = 0;
  __syncthreads();
  if (threadIdx.x == 0) *flag = sh;
}

// Bin active tokens by shank id. Hierarchical atomics (8-way LDS -> 1 global/g).
__global__ __launch_bounds__(256) void bin_kernel(
    const int* __restrict__ sid, const void* __restrict__ mask_,
    const int* __restrict__ flagp, int* __restrict__ counts,
    int* __restrict__ lens, int* __restrict__ idxbuf) {
  __shared__ int lcnt[8];
  __shared__ int lbase[8];
  int b = blockIdx.x, tid = threadIdx.x;
  int n = b * 256 + tid;
  int flag = *flagp;
  bool act = !is_masked(mask_, flag, n);
  int g = act ? sid[n] : 0;
  if (tid < 8) lcnt[tid] = 0;
  __syncthreads();
  int pos = 0;
  if (act) pos = atomicAdd(&lcnt[g], 1);
  __syncthreads();
  if (tid < 8) lbase[tid] = atomicAdd(&counts[tid], lcnt[tid]);
  if (tid == 0)
    lens[b] = lcnt[0] + lcnt[1] + lcnt[2] + lcnt[3] +
              lcnt[4] + lcnt[5] + lcnt[6] + lcnt[7];
  __syncthreads();
  if (act) idxbuf[g * 32768 + lbase[g] + pos] = n;
}

// Base embedding: shank_emb[sid] + positional encoding.
__global__ __launch_bounds__(256) void init_emb_kernel(
    const int* __restrict__ sid, const float* __restrict__ shank_emb,
    float* __restrict__ hout) {
  int i = blockIdx.x * 256 + threadIdx.x;
  int n = i >> 6, e = i & 63, s = n & 255;
  int g = sid[n];
  float div = __expf(-(float)(e & ~1) * (9.21034037f / 64.f));
  float angle = (float)s * div;
  float pe = (e & 1) ? cosf(angle) : sinf(angle);
  hout[i] = shank_emb[g * 64 + e] + pe;
}

// Conv encoder via bf16 MFMA, vectorized float4 waveform staging.
#define CONV_BPG 64
__global__ __launch_bounds__(256) void conv_mfma_kernel(
    const int* __restrict__ idxbuf, const int* __restrict__ counts,
    const float* __restrict__ wav,
    const float* __restrict__ w1_, const float* __restrict__ b1_,
    const float* __restrict__ w2_, const float* __restrict__ b2_,
    float* __restrict__ hout) {
  __shared__ __align__(16) unsigned short w1f[5][32][8];    // [tap][oc][ic pad8]
  __shared__ __align__(16) unsigned short w2f[3][64][40];   // [tap][e][ic pad40]
  __shared__ float b1s[32];
  __shared__ float b2s[64];
  __shared__ __align__(16) unsigned short xT[8][36][8];     // [tok][tpad][ic pad8]
  __shared__ __align__(16) unsigned short h1T[8][34][40];   // [tok][tpad][oc pad40]
  int g = blockIdx.x & 7, bib = blockIdx.x >> 3;
  int tid = threadIdx.x;
  int wv = tid >> 6, lane = tid & 63, quad = lane >> 4, l15 = lane & 15;
  for (int i = tid; i < 1280; i += 256) {
    int k = i >> 8, rest = i & 255, oc = rest >> 3, ic = rest & 7;
    w1f[k][oc][ic] = (ic < 6) ? f2bf(w1_[g * 960 + oc * 30 + ic * 5 + k]) : 0;
  }
  for (int i = tid; i < 7680; i += 256) {
    int k = i / 2560, rest = i % 2560, e = rest / 40, ic = rest % 40;
    w2f[k][e][ic] = (ic < 32) ? f2bf(w2_[g * 6144 + e * 96 + ic * 3 + k]) : 0;
  }
  if (tid < 32) b1s[tid] = b1_[g * 32 + tid];
  if (tid < 64) b2s[tid] = b2_[g * 64 + tid];
  // zero entire xT once (pads + ic 6,7 stay zero forever)
  {
    unsigned int* xz = (unsigned int*)&xT[0][0][0];
    for (int i = tid; i < 1152; i += 256) xz[i] = 0;
  }
  for (int i = tid; i < 640; i += 256) {
    int tok = i / 80, rest = i % 80;
    h1T[tok][(rest >= 40) ? 33 : 0][rest % 40] = 0;
  }
  __syncthreads();
  bf16x8 zf = {0, 0, 0, 0, 0, 0, 0, 0};
  bf16x8 bf1[2], bf1k4[2], bf2[3][4];
#pragma unroll
  for (int nt = 0; nt < 2; nt++) {
    bf1[nt] = ldfrag(&w1f[quad][nt * 16 + l15][0]);
    bf1k4[nt] = (quad == 0) ? ldfrag(&w1f[4][nt * 16 + l15][0]) : zf;
  }
#pragma unroll
  for (int k = 0; k < 3; k++)
#pragma unroll
    for (int nt = 0; nt < 4; nt++)
      bf2[k][nt] = ldfrag(&w2f[k][nt * 16 + l15][quad * 8]);
  float b1v0 = b1s[l15], b1v1 = b1s[16 + l15];
  int cnt = counts[g];
  for (int base = bib * 8; base < cnt; base += CONV_BPG * 8) {
    __syncthreads();
    // vectorized staging: 8 tok x 6 ic x 8 t-quads of float4
    for (int i = tid; i < 384; i += 256) {
      int tok = i / 48, rem = i % 48, ic = rem >> 3, tq = rem & 7;
      int ti = base + tok;
      float4 v = make_float4(0.f, 0.f, 0.f, 0.f);
      if (ti < cnt)
        v = *(const float4*)&wav[idxbuf[g * 32768 + ti] * 192 + ic * 32 + tq * 4];
      int r0 = tq * 4 + 2;
      xT[tok][r0 + 0][ic] = f2bf(v.x);
      xT[tok][r0 + 1][ic] = f2bf(v.y);
      xT[tok][r0 + 2][ic] = f2bf(v.z);
      xT[tok][r0 + 3][ic] = f2bf(v.w);
    }
    __syncthreads();
#pragma unroll
    for (int ts = 0; ts < 2; ts++) {
      int tk = wv * 2 + ts;
      f32x4 c1[2][2];
#pragma unroll
      for (int mt = 0; mt < 2; mt++) {
        c1[mt][0] = (f32x4){b1v0, b1v0, b1v0, b1v0};
        c1[mt][1] = (f32x4){b1v1, b1v1, b1v1, b1v1};
      }
#pragma unroll
      for (int mt = 0; mt < 2; mt++) {
        bf16x8 afm = ldfrag(&xT[tk][mt * 16 + l15 + quad][0]);
        bf16x8 af4 = (quad == 0) ? ldfrag(&xT[tk][mt * 16 + l15 + 4][0]) : zf;
#pragma unroll
        for (int nt = 0; nt < 2; nt++) {
          c1[mt][nt] = __builtin_amdgcn_mfma_f32_16x16x32_bf16(afm, bf1[nt], c1[mt][nt], 0, 0, 0);
          c1[mt][nt] = __builtin_amdgcn_mfma_f32_16x16x32_bf16(af4, bf1k4[nt], c1[mt][nt], 0, 0, 0);
        }
      }
#pragma unroll
      for (int mt = 0; mt < 2; mt++)
#pragma unroll
        for (int nt = 0; nt < 2; nt++)
#pragma unroll
          for (int r = 0; r < 4; r++) {
            int t = mt * 16 + quad * 4 + r;
            h1T[tk][t + 1][nt * 16 + l15] = f2bf(fmaxf(c1[mt][nt][r], 0.f));
          }
    }
    __syncthreads();
#pragma unroll
    for (int ts = 0; ts < 2; ts++) {
      int tk = wv * 2 + ts;
      f32x4 c2[2][4];
#pragma unroll
      for (int mt = 0; mt < 2; mt++)
#pragma unroll
        for (int nt = 0; nt < 4; nt++) {
          float bv = b2s[nt * 16 + l15];
          c2[mt][nt] = (f32x4){bv, bv, bv, bv};
        }
#pragma unroll
      for (int k = 0; k < 3; k++)
#pragma unroll
        for (int mt = 0; mt < 2; mt++) {
          bf16x8 af = ldfrag(&h1T[tk][mt * 16 + l15 + k][quad * 8]);
#pragma unroll
          for (int nt = 0; nt < 4; nt++)
            c2[mt][nt] = __builtin_amdgcn_mfma_f32_16x16x32_bf16(af, bf2[k][nt], c2[mt][nt], 0, 0, 0);
        }
      int ti = base + tk;
      float sums[4];
#pragma unroll
      for (int nt = 0; nt < 4; nt++) {
        float s = 0.f;
#pragma unroll
        for (int mt = 0; mt < 2; mt++)
#pragma unroll
          for (int r = 0; r < 4; r++) s += fmaxf(c2[mt][nt][r], 0.f);
        s += __shfl_xor(s, 16);
        s += __shfl_xor(s, 32);
        sums[nt] = s;
      }
      if (ti < cnt && quad == 0) {
        int n = idxbuf[g * 32768 + ti];
#pragma unroll
        for (int nt = 0; nt < 4; nt++)
          hout[n * 64 + nt * 16 + l15] += sums[nt] * (1.f / 32.f);
      }
    }
  }
}

// bf16-MFMA GEMM, full-N per block: out = A[M][K] @ W[N][K]^T + bias.
// MODE 0: store C. MODE 1: relu, store C. MODE 2 (NT==4): H = LayerNorm(H + out).
template <int NT, int MODE>
__global__ __launch_bounds__(256) void gemm_nt(
    const float* __restrict__ A, const float* __restrict__ W,
    const float* __restrict__ bias, float* __restrict__ C,
    float* __restrict__ H, const float* __restrict__ lng,
    const float* __restrict__ lnb, int K) {
  constexpr int N = NT * 16;
  __shared__ __align__(16) unsigned short As[64][72];
  __shared__ __align__(16) unsigned short Bs[N][72];
  int m0 = blockIdx.x * 64;
  int tid = threadIdx.x;
  int wv = tid >> 6, lane = tid & 63, quad = lane >> 4, l15 = lane & 15;
  f32x4 acc[NT];
#pragma unroll
  for (int nt = 0; nt < NT; nt++) {
    float b = bias[nt * 16 + l15];
    acc[nt] = (f32x4){b, b, b, b};
  }
  for (int kc = 0; kc < K; kc += 64) {
    __syncthreads();
    for (int i = tid; i < 1024; i += 256) {
      int r = i >> 4, c4 = (i & 15) << 2;
      float4 av = *(const float4*)&A[(size_t)(m0 + r) * K + kc + c4];
      short4 t;
      t.x = (short)f2bf(av.x); t.y = (short)f2bf(av.y);
      t.z = (short)f2bf(av.z); t.w = (short)f2bf(av.w);
      *(short4*)&As[r][c4] = t;
    }
    for (int i = tid; i < N * 16; i += 256) {
      int r = i >> 4, c4 = (i & 15) << 2;
      float4 wv4 = *(const float4*)&W[(size_t)r * K + kc + c4];
      short4 u;
      u.x = (short)f2bf(wv4.x); u.y = (short)f2bf(wv4.y);
      u.z = (short)f2bf(wv4.z); u.w = (short)f2bf(wv4.w);
      *(short4*)&Bs[r][c4] = u;
    }
    __syncthreads();
#pragma unroll
    for (int ks = 0; ks < 64; ks += 32) {
      bf16x8 af = ldfrag(&As[wv * 16 + l15][ks + quad * 8]);
#pragma unroll
      for (int nt = 0; nt < NT; nt++) {
        bf16x8 bfr = ldfrag(&Bs[nt * 16 + l15][ks + quad * 8]);
        acc[nt] = __builtin_amdgcn_mfma_f32_16x16x32_bf16(af, bfr, acc[nt], 0, 0, 0);
      }
    }
  }
  int mrow = m0 + wv * 16 + quad * 4;
  if (MODE <= 1) {
#pragma unroll
    for (int nt = 0; nt < NT; nt++)
#pragma unroll
      for (int r = 0; r < 4; r++) {
        float v = acc[nt][r];
        if (MODE == 1) v = fmaxf(v, 0.f);
        C[(size_t)(mrow + r) * N + nt * 16 + l15] = v;
      }
  } else {
#pragma unroll
    for (int r = 0; r < 4; r++) {
      float rv[4];
      float s = 0.f;
#pragma unroll
      for (int nt = 0; nt < 4; nt++) {
        float v = acc[nt][r] + H[(size_t)(mrow + r) * 64 + nt * 16 + l15];
        rv[nt] = v; s += v;
      }
      s += __shfl_xor(s, 1); s += __shfl_xor(s, 2);
      s += __shfl_xor(s, 4); s += __shfl_xor(s, 8);
      float mean = s * (1.f / 64.f);
      float vsum = 0.f;
#pragma unroll
      for (int nt = 0; nt < 4; nt++) { rv[nt] -= mean; vsum += rv[nt] * rv[nt]; }
      vsum += __shfl_xor(vsum, 1); vsum += __shfl_xor(vsum, 2);
      vsum += __shfl_xor(vsum, 4); vsum += __shfl_xor(vsum, 8);
      float inv = rsqrtf(vsum * (1.f / 64.f) + 1e-5f);
#pragma unroll
      for (int nt = 0; nt < 4; nt++) {
        int col = nt * 16 + l15;
        H[(size_t)(mrow + r) * 64 + col] = rv[nt] * inv * lng[col] + lnb[col];
      }
    }
  }
}

// Attention: block = (b, head), 256 threads, ONE query per thread (all state
// static-indexed registers, ~70 VGPR -> no spill). K/V staged once per block
// as bf16 (halves ds_read_b128 issue vs fp32). Serial online softmax over len.
__global__ __launch_bounds__(256) void attn_kernel(
    const float* __restrict__ qkv, const int* __restrict__ lens,
    float* __restrict__ o) {
  __shared__ __align__(16) unsigned short ks[256][16];
  __shared__ __align__(16) unsigned short vs[256][16];
  int bh = blockIdx.x;
  int b_ = bh >> 2, hd = bh & 3;
  int tid = threadIdx.x;
  int len = lens[b_];
  const float* base = qkv + b_ * 256 * 192;
  for (int i = tid; i < 1024; i += 256) {
    int s = i >> 2, c = (i & 3) << 2;
    float4 k4 = *(const float4*)&base[s * 192 + 64 + hd * 16 + c];
    float4 v4 = *(const float4*)&base[s * 192 + 128 + hd * 16 + c];
    short4 kp, vp;
    kp.x = (short)f2bf(k4.x); kp.y = (short)f2bf(k4.y);
    kp.z = (short)f2bf(k4.z); kp.w = (short)f2bf(k4.w);
    vp.x = (short)f2bf(v4.x); vp.y = (short)f2bf(v4.y);
    vp.z = (short)f2bf(v4.z); vp.w = (short)f2bf(v4.w);
    *(short4*)&ks[s][c] = kp;
    *(short4*)&vs[s][c] = vp;
  }
  __syncthreads();
  float qv[16];
  const float* qp = base + tid * 192 + hd * 16;
#pragma unroll
  for (int c = 0; c < 4; c++) ld4(&qp[c * 4], &qv[c * 4]);
#pragma unroll
  for (int d = 0; d < 16; d++) qv[d] *= 0.25f;   // 1/sqrt(16)
  float m = -1e30f, l = 0.f;
  float acc[16] = {};
  for (int kk = 0; kk < len; kk++) {
    uint4 kr0 = *(const uint4*)&ks[kk][0];
    uint4 kr1 = *(const uint4*)&ks[kk][8];
    // dot with 4 partial sums for ILP
    float s0 = qv[0] * bflo(kr0.x) + qv[4] * bflo(kr0.z);
    float s1 = qv[1] * bfhi(kr0.x) + qv[5] * bfhi(kr0.z);
    float s2 = qv[2] * bflo(kr0.y) + qv[6] * bflo(kr0.w);
    float s3 = qv[3] * bfhi(kr0.y) + qv[7] * bfhi(kr0.w);
    s0 += qv[8] * bflo(kr1.x) + qv[12] * bflo(kr1.z);
    s1 += qv[9] * bfhi(kr1.x) + qv[13] * bfhi(kr1.z);
    s2 += qv[10] * bflo(kr1.y) + qv[14] * bflo(kr1.w);
    s3 += qv[11] * bfhi(kr1.y) + qv[15] * bfhi(kr1.w);
    float sc = (s0 + s1) + (s2 + s3);
    uint4 vr0 = *(const uint4*)&vs[kk][0];
    uint4 vr1 = *(const uint4*)&vs[kk][8];
    float mn = fmaxf(m, sc);
    float al = __expf(m - mn), pp = __expf(sc - mn);
    l = l * al + pp;
    m = mn;
    float vvv[16];
    vvv[0] = bflo(vr0.x);  vvv[1] = bfhi(vr0.x);
    vvv[2] = bflo(vr0.y);  vvv[3] = bfhi(vr0.y);
    vvv[4] = bflo(vr0.z);  vvv[5] = bfhi(vr0.z);
    vvv[6] = bflo(vr0.w);  vvv[7] = bfhi(vr0.w);
    vvv[8] = bflo(vr1.x);  vvv[9] = bfhi(vr1.x);
    vvv[10] = bflo(vr1.y); vvv[11] = bfhi(vr1.y);
    vvv[12] = bflo(vr1.z); vvv[13] = bfhi(vr1.z);
    vvv[14] = bflo(vr1.w); vvv[15] = bfhi(vr1.w);
#pragma unroll
    for (int d = 0; d < 16; d++) acc[d] = acc[d] * al + pp * vvv[d];
  }
  float inv = 1.f / l;
  float* op = o + (b_ * 256 + tid) * 64 + hd * 16;
#pragma unroll
  for (int c = 0; c < 4; c++) {
    float4 w;
    w.x = acc[c * 4 + 0] * inv;
    w.y = acc[c * 4 + 1] * inv;
    w.z = acc[c * 4 + 2] * inv;
    w.w = acc[c * 4 + 3] * inv;
    *(float4*)&op[c * 4] = w;
  }
}

// Masked mean pool using per-b active length.
__global__ __launch_bounds__(256) void pool_kernel(
    const float* __restrict__ h, const int* __restrict__ lens,
    float* __restrict__ pooled) {
  __shared__ float ps[4][64];
  int b = blockIdx.x;
  int e = threadIdx.x & 63, sp = threadIdx.x >> 6;
  int len = lens[b];
  float sum = 0.f;
  int send = min(sp * 64 + 64, len);
  for (int s = sp * 64; s < send; s++) sum += h[(b * 256 + s) * 64 + e];
  ps[sp][e] = sum;
  __syncthreads();
  if (sp == 0) {
    float tot = ps[0][e] + ps[1][e] + ps[2][e] + ps[3][e];
    pooled[b * 64 + e] = tot / ((float)len + 1e-8f);
  }
}

// Fused heads: cls(3), mus(6), sigmas(6), d(1) -> 16 outputs per b.
__global__ __launch_bounds__(64) void heads_kernel(
    const float* __restrict__ pooled,
    const float* __restrict__ cls_w1, const float* __restrict__ cls_b1,
    const float* __restrict__ cls_w2, const float* __restrict__ cls_b2,
    const float* __restrict__ mu_w1, const float* __restrict__ mu_b1,
    const float* __restrict__ mu_w2, const float* __restrict__ mu_b2,
    const float* __restrict__ ls_w1, const float* __restrict__ ls_b1,
    const float* __restrict__ ls_w2, const float* __restrict__ ls_b2,
    const float* __restrict__ d_w1, const float* __restrict__ d_b1,
    const float* __restrict__ d_w2, const float* __restrict__ d_b2,
    float* __restrict__ out) {
  int b = blockIdx.x, e = threadIdx.x;
  __shared__ float p[64];
  __shared__ float t1[64];
  p[e] = pooled[b * 64 + e];
  __syncthreads();
  {
    float a = cls_b1[e];
    for (int j = 0; j < 64; j++) a += p[j] * cls_w1[e * 64 + j];
    t1[e] = fmaxf(a, 0.f);
  }
  __syncthreads();
  if (e < 3) {
    float a2 = cls_b2[e];
    for (int j = 0; j < 64; j++) a2 += t1[j] * cls_w2[e * 64 + j];
    out[b * 16 + e] = a2;
  }
  for (int z = 0; z < 3; z++) {
    __syncthreads();
    {
      float a = mu_b1[z * 64 + e];
      for (int j = 0; j < 64; j++) a += p[j] * mu_w1[(z * 64 + e) * 64 + j];
      t1[e] = fmaxf(a, 0.f);
    }
    __syncthreads();
    if (e < 2) {
      float a2 = mu_b2[z * 2 + e];
      for (int j = 0; j < 64; j++) a2 += t1[j] * mu_w2[(z * 2 + e) * 64 + j];
      out[b * 16 + 3 + z * 2 + e] = a2;
    }
    __syncthreads();
    {
      float a = ls_b1[z * 64 + e];
      for (int j = 0; j < 64; j++) a += p[j] * ls_w1[(z * 64 + e) * 64 + j];
      t1[e] = fmaxf(a, 0.f);
    }
    __syncthreads();
    if (e < 2) {
      float a2 = ls_b2[z * 2 + e];
      for (int j = 0; j < 64; j++) a2 += t1[j] * ls_w2[(z * 2 + e) * 64 + j];
      out[b * 16 + 9 + z * 2 + e] = __expf(a2);
    }
  }
  __syncthreads();
  {
    float a = d_b1[e];
    for (int j = 0; j < 64; j++) a += p[j] * d_w1[e * 64 + j];
    t1[e] = fmaxf(a, 0.f);
  }
  __syncthreads();
  if (e == 0) {
    float a2 = d_b2[0];
    for (int j = 0; j < 64; j++) a2 += t1[j] * d_w2[j];
    out[b * 16 + 15] = 1.f / (1.f + __expf(-a2));
  }
}

extern "C" void kernel_launch(void* const* d_in, const int* in_sizes, int n_in,
                              void* d_out, int out_size, void* d_ws, size_t ws_size,
                              hipStream_t stream) {
  const float* wav       = (const float*)d_in[0];
  const int*   sid       = (const int*)d_in[1];
  const void*  mask      = d_in[2];
  const float* conv1_w   = (const float*)d_in[3];
  const float* conv1_b   = (const float*)d_in[4];
  const float* conv2_w   = (const float*)d_in[5];
  const float* conv2_b   = (const float*)d_in[6];
  const float* shank_emb = (const float*)d_in[7];
  const float* in_proj_w = (const float*)d_in[8];
  const float* in_proj_b = (const float*)d_in[9];
  const float* out_proj_w= (const float*)d_in[10];
  const float* out_proj_b= (const float*)d_in[11];
  const float* ln1_g     = (const float*)d_in[12];
  const float* ln1_b     = (const float*)d_in[13];
  const float* ff1_w     = (const float*)d_in[14];
  const float* ff1_b     = (const float*)d_in[15];
  const float* ff2_w     = (const float*)d_in[16];
  const float* ff2_b     = (const float*)d_in[17];
  const float* ln2_g     = (const float*)d_in[18];
  const float* ln2_b     = (const float*)d_in[19];
  const float* cls_w1    = (const float*)d_in[20];
  const float* cls_b1    = (const float*)d_in[21];
  const float* cls_w2    = (const float*)d_in[22];
  const float* cls_b2    = (const float*)d_in[23];
  const float* mu_w1     = (const float*)d_in[24];
  const float* mu_b1     = (const float*)d_in[25];
  const float* mu_w2     = (const float*)d_in[26];
  const float* mu_b2     = (const float*)d_in[27];
  const float* ls_w1     = (const float*)d_in[28];
  const float* ls_b1     = (const float*)d_in[29];
  const float* ls_w2     = (const float*)d_in[30];
  const float* ls_b2     = (const float*)d_in[31];
  const float* d_w1      = (const float*)d_in[32];
  const float* d_b1      = (const float*)d_in[33];
  const float* d_w2      = (const float*)d_in[34];
  const float* d_b2      = (const float*)d_in[35];
  float* out = (float*)d_out;

  float* ws = (float*)d_ws;
  float* h      = ws;                    // [32768,64]
  float* qkv    = ws + 2097152;          // [32768,192]
  float* obuf   = ws + 8388608;          // [32768,64] attn out
  float* ff     = ws + 2097152;          // [32768,256] aliases qkv+obuf (dead by ff1)
  float* pooled = ws + 10485760;         // [128,64]
  int*   ip     = (int*)(ws + 10493952);
  int*   flag   = ip;
  int*   counts = ip + 8;
  int*   lens   = ip + 16;               // [128]
  int*   idxbuf = ip + 144;              // [8][32768]

  detect_mask_kernel<<<1, 256, 0, stream>>>((const unsigned int*)mask, flag, counts, lens);
  bin_kernel<<<128, 256, 0, stream>>>(sid, mask, flag, counts, lens, idxbuf);
  init_emb_kernel<<<8192, 256, 0, stream>>>(sid, shank_emb, h);
  conv_mfma_kernel<<<CONV_BPG * 8, 256, 0, stream>>>(idxbuf, counts, wav, conv1_w, conv1_b,
                                                     conv2_w, conv2_b, h);
  for (int l = 0; l < 2; l++) {
    gemm_nt<12, 0><<<512, 256, 0, stream>>>(
        h, in_proj_w + l * 12288, in_proj_b + l * 192, qkv, nullptr, nullptr, nullptr, 64);
    attn_kernel<<<512, 256, 0, stream>>>(qkv, lens, obuf);
    gemm_nt<4, 2><<<512, 256, 0, stream>>>(
        obuf, out_proj_w + l * 4096, out_proj_b + l * 64, nullptr, h,
        ln1_g + l * 64, ln1_b + l * 64, 64);
    gemm_nt<16, 1><<<512, 256, 0, stream>>>(
        h, ff1_w + l * 16384, ff1_b + l * 256, ff, nullptr, nullptr, nullptr, 64);
    gemm_nt<4, 2><<<512, 256, 0, stream>>>(
        ff, ff2_w + l * 16384, ff2_b + l * 64, nullptr, h,
        ln2_g + l * 64, ln2_b + l * 64, 256);
  }
  pool_kernel<<<128, 256, 0, stream>>>(h, lens, pooled);
  heads_kernel<<<128, 64, 0, stream>>>(pooled, cls_w1, cls_b1, cls_w2, cls_b2,
                                       mu_w1, mu_b1, mu_w2, mu_b2,
                                       ls_w1, ls_b1, ls_w2, ls_b2,
                                       d_w1, d_b1, d_w2, d_b2, out);
}

// Round 7
// 373.308 us; speedup vs baseline: 4.1564x; 1.3015x over previous
//
#include <hip/hip_runtime.h>
#include <math.h>

// B=128, S=256, G=8, CMAX=6, T=32, E=64, NH=4, dh=16, L=2, DFF=256, Z=3

typedef short bf16x8 __attribute__((ext_vector_type(8)));
typedef float f32x4 __attribute__((ext_vector_type(4)));

__device__ __forceinline__ unsigned short f2bf(float f) {
  unsigned u = __float_as_uint(f);
  u += 0x7fffu + ((u >> 16) & 1u);   // RNE
  return (unsigned short)(u >> 16);
}

__device__ __forceinline__ bf16x8 ldfrag(const unsigned short* p) {
  return *reinterpret_cast<const bf16x8*>(p);
}

__device__ __forceinline__ void ld4(const float* p, float* dst) {
  float4 t = *reinterpret_cast<const float4*>(p);
  dst[0] = t.x; dst[1] = t.y; dst[2] = t.z; dst[3] = t.w;
}

__device__ __forceinline__ bool is_masked(const void* mask_, int flag, int idx) {
  return flag ? (((const unsigned char*)mask_)[idx] != 0)
              : (((const int*)mask_)[idx] != 0);
}

// Detect mask dtype (int32 vs byte-packed bool); zero counters.
__global__ void detect_mask_kernel(const unsigned int* __restrict__ mw,
                                   int* __restrict__ flag, int* __restrict__ counts,
                                   int* __restrict__ lens) {
  __shared__ int sh;
  if (threadIdx.x == 0) sh = 0;
  __syncthreads();
  int bad = 0;
  for (int i = threadIdx.x; i < 8192; i += 256)
    if (mw[i] > 1u) bad = 1;
  if (bad) atomicOr(&sh, 1);
  if (threadIdx.x < 8) counts[threadIdx.x] = 0;
  if (threadIdx.x < 128) lens[threadIdx.x] = 0;
  __syncthreads();
  if (threadIdx.x == 0) *flag = sh;
}

// Bin active tokens by shank id. Hierarchical atomics (8-way LDS -> 1 global/g).
__global__ __launch_bounds__(256) void bin_kernel(
    const int* __restrict__ sid, const void* __restrict__ mask_,
    const int* __restrict__ flagp, int* __restrict__ counts,
    int* __restrict__ lens, int* __restrict__ idxbuf) {
  __shared__ int lcnt[8];
  __shared__ int lbase[8];
  int b = blockIdx.x, tid = threadIdx.x;
  int n = b * 256 + tid;
  int flag = *flagp;
  bool act = !is_masked(mask_, flag, n);
  int g = act ? sid[n] : 0;
  if (tid < 8) lcnt[tid] = 0;
  __syncthreads();
  int pos = 0;
  if (act) pos = atomicAdd(&lcnt[g], 1);
  __syncthreads();
  if (tid < 8) lbase[tid] = atomicAdd(&counts[tid], lcnt[tid]);
  if (tid == 0)
    lens[b] = lcnt[0] + lcnt[1] + lcnt[2] + lcnt[3] +
              lcnt[4] + lcnt[5] + lcnt[6] + lcnt[7];
  __syncthreads();
  if (act) idxbuf[g * 32768 + lbase[g] + pos] = n;
}

// Base embedding: shank_emb[sid] + positional encoding.
__global__ __launch_bounds__(256) void init_emb_kernel(
    const int* __restrict__ sid, const float* __restrict__ shank_emb,
    float* __restrict__ hout) {
  int i = blockIdx.x * 256 + threadIdx.x;
  int n = i >> 6, e = i & 63, s = n & 255;
  int g = sid[n];
  float div = __expf(-(float)(e & ~1) * (9.21034037f / 64.f));
  float angle = (float)s * div;
  float pe = (e & 1) ? cosf(angle) : sinf(angle);
  hout[i] = shank_emb[g * 64 + e] + pe;
}

// Conv encoder via bf16 MFMA, vectorized float4 waveform staging.
#define CONV_BPG 64
__global__ __launch_bounds__(256) void conv_mfma_kernel(
    const int* __restrict__ idxbuf, const int* __restrict__ counts,
    const float* __restrict__ wav,
    const float* __restrict__ w1_, const float* __restrict__ b1_,
    const float* __restrict__ w2_, const float* __restrict__ b2_,
    float* __restrict__ hout) {
  __shared__ __align__(16) unsigned short w1f[5][32][8];    // [tap][oc][ic pad8]
  __shared__ __align__(16) unsigned short w2f[3][64][40];   // [tap][e][ic pad40]
  __shared__ float b1s[32];
  __shared__ float b2s[64];
  __shared__ __align__(16) unsigned short xT[8][36][8];     // [tok][tpad][ic pad8]
  __shared__ __align__(16) unsigned short h1T[8][34][40];   // [tok][tpad][oc pad40]
  int g = blockIdx.x & 7, bib = blockIdx.x >> 3;
  int tid = threadIdx.x;
  int wv = tid >> 6, lane = tid & 63, quad = lane >> 4, l15 = lane & 15;
  for (int i = tid; i < 1280; i += 256) {
    int k = i >> 8, rest = i & 255, oc = rest >> 3, ic = rest & 7;
    w1f[k][oc][ic] = (ic < 6) ? f2bf(w1_[g * 960 + oc * 30 + ic * 5 + k]) : 0;
  }
  for (int i = tid; i < 7680; i += 256) {
    int k = i / 2560, rest = i % 2560, e = rest / 40, ic = rest % 40;
    w2f[k][e][ic] = (ic < 32) ? f2bf(w2_[g * 6144 + e * 96 + ic * 3 + k]) : 0;
  }
  if (tid < 32) b1s[tid] = b1_[g * 32 + tid];
  if (tid < 64) b2s[tid] = b2_[g * 64 + tid];
  // zero entire xT once (pads + ic 6,7 stay zero forever)
  {
    unsigned int* xz = (unsigned int*)&xT[0][0][0];
    for (int i = tid; i < 1152; i += 256) xz[i] = 0;
  }
  for (int i = tid; i < 640; i += 256) {
    int tok = i / 80, rest = i % 80;
    h1T[tok][(rest >= 40) ? 33 : 0][rest % 40] = 0;
  }
  __syncthreads();
  bf16x8 zf = {0, 0, 0, 0, 0, 0, 0, 0};
  bf16x8 bf1[2], bf1k4[2], bf2[3][4];
#pragma unroll
  for (int nt = 0; nt < 2; nt++) {
    bf1[nt] = ldfrag(&w1f[quad][nt * 16 + l15][0]);
    bf1k4[nt] = (quad == 0) ? ldfrag(&w1f[4][nt * 16 + l15][0]) : zf;
  }
#pragma unroll
  for (int k = 0; k < 3; k++)
#pragma unroll
    for (int nt = 0; nt < 4; nt++)
      bf2[k][nt] = ldfrag(&w2f[k][nt * 16 + l15][quad * 8]);
  float b1v0 = b1s[l15], b1v1 = b1s[16 + l15];
  int cnt = counts[g];
  for (int base = bib * 8; base < cnt; base += CONV_BPG * 8) {
    __syncthreads();
    // vectorized staging: 8 tok x 6 ic x 8 t-quads of float4
    for (int i = tid; i < 384; i += 256) {
      int tok = i / 48, rem = i % 48, ic = rem >> 3, tq = rem & 7;
      int ti = base + tok;
      float4 v = make_float4(0.f, 0.f, 0.f, 0.f);
      if (ti < cnt)
        v = *(const float4*)&wav[idxbuf[g * 32768 + ti] * 192 + ic * 32 + tq * 4];
      int r0 = tq * 4 + 2;
      xT[tok][r0 + 0][ic] = f2bf(v.x);
      xT[tok][r0 + 1][ic] = f2bf(v.y);
      xT[tok][r0 + 2][ic] = f2bf(v.z);
      xT[tok][r0 + 3][ic] = f2bf(v.w);
    }
    __syncthreads();
#pragma unroll
    for (int ts = 0; ts < 2; ts++) {
      int tk = wv * 2 + ts;
      f32x4 c1[2][2];
#pragma unroll
      for (int mt = 0; mt < 2; mt++) {
        c1[mt][0] = (f32x4){b1v0, b1v0, b1v0, b1v0};
        c1[mt][1] = (f32x4){b1v1, b1v1, b1v1, b1v1};
      }
#pragma unroll
      for (int mt = 0; mt < 2; mt++) {
        bf16x8 afm = ldfrag(&xT[tk][mt * 16 + l15 + quad][0]);
        bf16x8 af4 = (quad == 0) ? ldfrag(&xT[tk][mt * 16 + l15 + 4][0]) : zf;
#pragma unroll
        for (int nt = 0; nt < 2; nt++) {
          c1[mt][nt] = __builtin_amdgcn_mfma_f32_16x16x32_bf16(afm, bf1[nt], c1[mt][nt], 0, 0, 0);
          c1[mt][nt] = __builtin_amdgcn_mfma_f32_16x16x32_bf16(af4, bf1k4[nt], c1[mt][nt], 0, 0, 0);
        }
      }
#pragma unroll
      for (int mt = 0; mt < 2; mt++)
#pragma unroll
        for (int nt = 0; nt < 2; nt++)
#pragma unroll
          for (int r = 0; r < 4; r++) {
            int t = mt * 16 + quad * 4 + r;
            h1T[tk][t + 1][nt * 16 + l15] = f2bf(fmaxf(c1[mt][nt][r], 0.f));
          }
    }
    __syncthreads();
#pragma unroll
    for (int ts = 0; ts < 2; ts++) {
      int tk = wv * 2 + ts;
      f32x4 c2[2][4];
#pragma unroll
      for (int mt = 0; mt < 2; mt++)
#pragma unroll
        for (int nt = 0; nt < 4; nt++) {
          float bv = b2s[nt * 16 + l15];
          c2[mt][nt] = (f32x4){bv, bv, bv, bv};
        }
#pragma unroll
      for (int k = 0; k < 3; k++)
#pragma unroll
        for (int mt = 0; mt < 2; mt++) {
          bf16x8 af = ldfrag(&h1T[tk][mt * 16 + l15 + k][quad * 8]);
#pragma unroll
          for (int nt = 0; nt < 4; nt++)
            c2[mt][nt] = __builtin_amdgcn_mfma_f32_16x16x32_bf16(af, bf2[k][nt], c2[mt][nt], 0, 0, 0);
        }
      int ti = base + tk;
      float sums[4];
#pragma unroll
      for (int nt = 0; nt < 4; nt++) {
        float s = 0.f;
#pragma unroll
        for (int mt = 0; mt < 2; mt++)
#pragma unroll
          for (int r = 0; r < 4; r++) s += fmaxf(c2[mt][nt][r], 0.f);
        s += __shfl_xor(s, 16);
        s += __shfl_xor(s, 32);
        sums[nt] = s;
      }
      if (ti < cnt && quad == 0) {
        int n = idxbuf[g * 32768 + ti];
#pragma unroll
        for (int nt = 0; nt < 4; nt++)
          hout[n * 64 + nt * 16 + l15] += sums[nt] * (1.f / 32.f);
      }
    }
  }
}

// bf16-MFMA GEMM, full-N per block: out = A[M][K] @ W[N][K]^T + bias.
// MODE 0: store C. MODE 1: relu, store C. MODE 2 (NT==4): H = LayerNorm(H + out).
template <int NT, int MODE>
__global__ __launch_bounds__(256) void gemm_nt(
    const float* __restrict__ A, const float* __restrict__ W,
    const float* __restrict__ bias, float* __restrict__ C,
    float* __restrict__ H, const float* __restrict__ lng,
    const float* __restrict__ lnb, int K) {
  constexpr int N = NT * 16;
  __shared__ __align__(16) unsigned short As[64][72];
  __shared__ __align__(16) unsigned short Bs[N][72];
  int m0 = blockIdx.x * 64;
  int tid = threadIdx.x;
  int wv = tid >> 6, lane = tid & 63, quad = lane >> 4, l15 = lane & 15;
  f32x4 acc[NT];
#pragma unroll
  for (int nt = 0; nt < NT; nt++) {
    float b = bias[nt * 16 + l15];
    acc[nt] = (f32x4){b, b, b, b};
  }
  for (int kc = 0; kc < K; kc += 64) {
    __syncthreads();
    for (int i = tid; i < 1024; i += 256) {
      int r = i >> 4, c4 = (i & 15) << 2;
      float4 av = *(const float4*)&A[(size_t)(m0 + r) * K + kc + c4];
      short4 t;
      t.x = (short)f2bf(av.x); t.y = (short)f2bf(av.y);
      t.z = (short)f2bf(av.z); t.w = (short)f2bf(av.w);
      *(short4*)&As[r][c4] = t;
    }
    for (int i = tid; i < N * 16; i += 256) {
      int r = i >> 4, c4 = (i & 15) << 2;
      float4 wv4 = *(const float4*)&W[(size_t)r * K + kc + c4];
      short4 u;
      u.x = (short)f2bf(wv4.x); u.y = (short)f2bf(wv4.y);
      u.z = (short)f2bf(wv4.z); u.w = (short)f2bf(wv4.w);
      *(short4*)&Bs[r][c4] = u;
    }
    __syncthreads();
#pragma unroll
    for (int ks = 0; ks < 64; ks += 32) {
      bf16x8 af = ldfrag(&As[wv * 16 + l15][ks + quad * 8]);
#pragma unroll
      for (int nt = 0; nt < NT; nt++) {
        bf16x8 bfr = ldfrag(&Bs[nt * 16 + l15][ks + quad * 8]);
        acc[nt] = __builtin_amdgcn_mfma_f32_16x16x32_bf16(af, bfr, acc[nt], 0, 0, 0);
      }
    }
  }
  int mrow = m0 + wv * 16 + quad * 4;
  if (MODE <= 1) {
#pragma unroll
    for (int nt = 0; nt < NT; nt++)
#pragma unroll
      for (int r = 0; r < 4; r++) {
        float v = acc[nt][r];
        if (MODE == 1) v = fmaxf(v, 0.f);
        C[(size_t)(mrow + r) * N + nt * 16 + l15] = v;
      }
  } else {
#pragma unroll
    for (int r = 0; r < 4; r++) {
      float rv[4];
      float s = 0.f;
#pragma unroll
      for (int nt = 0; nt < 4; nt++) {
        float v = acc[nt][r] + H[(size_t)(mrow + r) * 64 + nt * 16 + l15];
        rv[nt] = v; s += v;
      }
      s += __shfl_xor(s, 1); s += __shfl_xor(s, 2);
      s += __shfl_xor(s, 4); s += __shfl_xor(s, 8);
      float mean = s * (1.f / 64.f);
      float vsum = 0.f;
#pragma unroll
      for (int nt = 0; nt < 4; nt++) { rv[nt] -= mean; vsum += rv[nt] * rv[nt]; }
      vsum += __shfl_xor(vsum, 1); vsum += __shfl_xor(vsum, 2);
      vsum += __shfl_xor(vsum, 4); vsum += __shfl_xor(vsum, 8);
      float inv = rsqrtf(vsum * (1.f / 64.f) + 1e-5f);
#pragma unroll
      for (int nt = 0; nt < 4; nt++) {
        int col = nt * 16 + l15;
        H[(size_t)(mrow + r) * 64 + col] = rv[nt] * inv * lng[col] + lnb[col];
      }
    }
  }
}

// MFMA flash attention. Block = (b, head), 4 waves, each wave owns 4 q-tiles
// of 16 queries. Scores S^T[key][q] via 16x16x32 MFMA (d=16 -> quads 2,3 get
// zero frags). Full-row softmax: each lane holds 64 scores all for q=lane&15;
// max/sum = local reduce + shfl_xor(16,32). P -> per-wave LDS buffer (bf16,
// no barrier needed), PV via 8 MFMA (A=V^T rows d, B=P rows q).
__global__ __launch_bounds__(256) void attn_kernel(
    const float* __restrict__ qkv, const int* __restrict__ lens,
    float* __restrict__ o) {
  __shared__ __align__(16) unsigned short qs[256][24];   // q*0.25, bf16
  __shared__ __align__(16) unsigned short kst[256][24];
  __shared__ __align__(16) unsigned short vT[16][264];   // [d][key]
  __shared__ __align__(16) unsigned short pw[4][16][264]; // per-wave P[q][key]
  int bh = blockIdx.x;
  int b_ = bh >> 2, hd = bh & 3;
  int tid = threadIdx.x;
  int wv = tid >> 6, lane = tid & 63, quad = lane >> 4, l15 = lane & 15;
  int len = lens[b_];
  const float* base = qkv + b_ * 256 * 192 + hd * 16;
  for (int i = tid; i < 1024; i += 256) {
    int s = i >> 2, c = (i & 3) << 2;
    const float* rp = base + s * 192;
    float4 q4 = *(const float4*)(rp + c);
    float4 k4 = *(const float4*)(rp + 64 + c);
    float4 v4 = *(const float4*)(rp + 128 + c);
    short4 qp, kp;
    qp.x = (short)f2bf(q4.x * 0.25f); qp.y = (short)f2bf(q4.y * 0.25f);
    qp.z = (short)f2bf(q4.z * 0.25f); qp.w = (short)f2bf(q4.w * 0.25f);
    kp.x = (short)f2bf(k4.x); kp.y = (short)f2bf(k4.y);
    kp.z = (short)f2bf(k4.z); kp.w = (short)f2bf(k4.w);
    *(short4*)&qs[s][c] = qp;
    *(short4*)&kst[s][c] = kp;
    vT[c + 0][s] = f2bf(v4.x);
    vT[c + 1][s] = f2bf(v4.y);
    vT[c + 2][s] = f2bf(v4.z);
    vT[c + 3][s] = f2bf(v4.w);
  }
  __syncthreads();
  bf16x8 zf = {0, 0, 0, 0, 0, 0, 0, 0};
  f32x4 zero = {0.f, 0.f, 0.f, 0.f};
#pragma unroll 1
  for (int j = 0; j < 4; j++) {
    int qt = wv * 4 + j;
    // scores: D[key][q], A = K (m=key), B = Q (n=q), k-dim = d (quads 0,1)
    bf16x8 bq = (quad < 2) ? ldfrag(&qs[qt * 16 + l15][quad * 8]) : zf;
    f32x4 s[16];
#pragma unroll
    for (int t = 0; t < 16; t++) {
      bf16x8 ak = (quad < 2) ? ldfrag(&kst[t * 16 + l15][quad * 8]) : zf;
      s[t] = __builtin_amdgcn_mfma_f32_16x16x32_bf16(ak, bq, zero, 0, 0, 0);
    }
    // mask + row max (this lane's 64 scores all belong to q = l15)
    float mx = -1e30f;
#pragma unroll
    for (int t = 0; t < 16; t++)
#pragma unroll
      for (int r = 0; r < 4; r++) {
        int key = t * 16 + quad * 4 + r;
        float v = (key < len) ? s[t][r] : -1e30f;
        s[t][r] = v;
        mx = fmaxf(mx, v);
      }
    mx = fmaxf(mx, __shfl_xor(mx, 16));
    mx = fmaxf(mx, __shfl_xor(mx, 32));
    float sum = 0.f;
#pragma unroll
    for (int t = 0; t < 16; t++)
#pragma unroll
      for (int r = 0; r < 4; r++) {
        float p = __expf(s[t][r] - mx);
        s[t][r] = p;
        sum += p;
      }
    sum += __shfl_xor(sum, 16);
    sum += __shfl_xor(sum, 32);
    // write P[q=l15][key] as bf16 (keys quad*4+r+16t -> short4 per tile)
#pragma unroll
    for (int t = 0; t < 16; t++) {
      short4 pp;
      pp.x = (short)f2bf(s[t][0]); pp.y = (short)f2bf(s[t][1]);
      pp.z = (short)f2bf(s[t][2]); pp.w = (short)f2bf(s[t][3]);
      *(short4*)&pw[wv][l15][t * 16 + quad * 4] = pp;
    }
    // PV: D[d][q], A = V^T (m=d), B = P (n=q), k-dim = keys (8 chunks of 32)
    f32x4 acc = zero;
#pragma unroll
    for (int c = 0; c < 8; c++) {
      bf16x8 av = ldfrag(&vT[l15][c * 32 + quad * 8]);
      bf16x8 bp = ldfrag(&pw[wv][l15][c * 32 + quad * 8]);
      acc = __builtin_amdgcn_mfma_f32_16x16x32_bf16(av, bp, acc, 0, 0, 0);
    }
    float inv = 1.f / sum;
    float4 w;
    w.x = acc[0] * inv; w.y = acc[1] * inv;
    w.z = acc[2] * inv; w.w = acc[3] * inv;
    *(float4*)&o[(size_t)(b_ * 256 + qt * 16 + l15) * 64 + hd * 16 + quad * 4] = w;
  }
}

// Masked mean pool using per-b active length.
__global__ __launch_bounds__(256) void pool_kernel(
    const float* __restrict__ h, const int* __restrict__ lens,
    float* __restrict__ pooled) {
  __shared__ float ps[4][64];
  int b = blockIdx.x;
  int e = threadIdx.x & 63, sp = threadIdx.x >> 6;
  int len = lens[b];
  float sum = 0.f;
  int send = min(sp * 64 + 64, len);
  for (int s = sp * 64; s < send; s++) sum += h[(b * 256 + s) * 64 + e];
  ps[sp][e] = sum;
  __syncthreads();
  if (sp == 0) {
    float tot = ps[0][e] + ps[1][e] + ps[2][e] + ps[3][e];
    pooled[b * 64 + e] = tot / ((float)len + 1e-8f);
  }
}

// Fused heads: cls(3), mus(6), sigmas(6), d(1) -> 16 outputs per b.
__global__ __launch_bounds__(64) void heads_kernel(
    const float* __restrict__ pooled,
    const float* __restrict__ cls_w1, const float* __restrict__ cls_b1,
    const float* __restrict__ cls_w2, const float* __restrict__ cls_b2,
    const float* __restrict__ mu_w1, const float* __restrict__ mu_b1,
    const float* __restrict__ mu_w2, const float* __restrict__ mu_b2,
    const float* __restrict__ ls_w1, const float* __restrict__ ls_b1,
    const float* __restrict__ ls_w2, const float* __restrict__ ls_b2,
    const float* __restrict__ d_w1, const float* __restrict__ d_b1,
    const float* __restrict__ d_w2, const float* __restrict__ d_b2,
    float* __restrict__ out) {
  int b = blockIdx.x, e = threadIdx.x;
  __shared__ float p[64];
  __shared__ float t1[64];
  p[e] = pooled[b * 64 + e];
  __syncthreads();
  {
    float a = cls_b1[e];
    for (int j = 0; j < 64; j++) a += p[j] * cls_w1[e * 64 + j];
    t1[e] = fmaxf(a, 0.f);
  }
  __syncthreads();
  if (e < 3) {
    float a2 = cls_b2[e];
    for (int j = 0; j < 64; j++) a2 += t1[j] * cls_w2[e * 64 + j];
    out[b * 16 + e] = a2;
  }
  for (int z = 0; z < 3; z++) {
    __syncthreads();
    {
      float a = mu_b1[z * 64 + e];
      for (int j = 0; j < 64; j++) a += p[j] * mu_w1[(z * 64 + e) * 64 + j];
      t1[e] = fmaxf(a, 0.f);
    }
    __syncthreads();
    if (e < 2) {
      float a2 = mu_b2[z * 2 + e];
      for (int j = 0; j < 64; j++) a2 += t1[j] * mu_w2[(z * 2 + e) * 64 + j];
      out[b * 16 + 3 + z * 2 + e] = a2;
    }
    __syncthreads();
    {
      float a = ls_b1[z * 64 + e];
      for (int j = 0; j < 64; j++) a += p[j] * ls_w1[(z * 64 + e) * 64 + j];
      t1[e] = fmaxf(a, 0.f);
    }
    __syncthreads();
    if (e < 2) {
      float a2 = ls_b2[z * 2 + e];
      for (int j = 0; j < 64; j++) a2 += t1[j] * ls_w2[(z * 2 + e) * 64 + j];
      out[b * 16 + 9 + z * 2 + e] = __expf(a2);
    }
  }
  __syncthreads();
  {
    float a = d_b1[e];
    for (int j = 0; j < 64; j++) a += p[j] * d_w1[e * 64 + j];
    t1[e] = fmaxf(a, 0.f);
  }
  __syncthreads();
  if (e == 0) {
    float a2 = d_b2[0];
    for (int j = 0; j < 64; j++) a2 += t1[j] * d_w2[j];
    out[b * 16 + 15] = 1.f / (1.f + __expf(-a2));
  }
}

extern "C" void kernel_launch(void* const* d_in, const int* in_sizes, int n_in,
                              void* d_out, int out_size, void* d_ws, size_t ws_size,
                              hipStream_t stream) {
  const float* wav       = (const float*)d_in[0];
  const int*   sid       = (const int*)d_in[1];
  const void*  mask      = d_in[2];
  const float* conv1_w   = (const float*)d_in[3];
  const float* conv1_b   = (const float*)d_in[4];
  const float* conv2_w   = (const float*)d_in[5];
  const float* conv2_b   = (const float*)d_in[6];
  const float* shank_emb = (const float*)d_in[7];
  const float* in_proj_w = (const float*)d_in[8];
  const float* in_proj_b = (const float*)d_in[9];
  const float* out_proj_w= (const float*)d_in[10];
  const float* out_proj_b= (const float*)d_in[11];
  const float* ln1_g     = (const float*)d_in[12];
  const float* ln1_b     = (const float*)d_in[13];
  const float* ff1_w     = (const float*)d_in[14];
  const float* ff1_b     = (const float*)d_in[15];
  const float* ff2_w     = (const float*)d_in[16];
  const float* ff2_b     = (const float*)d_in[17];
  const float* ln2_g     = (const float*)d_in[18];
  const float* ln2_b     = (const float*)d_in[19];
  const float* cls_w1    = (const float*)d_in[20];
  const float* cls_b1    = (const float*)d_in[21];
  const float* cls_w2    = (const float*)d_in[22];
  const float* cls_b2    = (const float*)d_in[23];
  const float* mu_w1     = (const float*)d_in[24];
  const float* mu_b1     = (const float*)d_in[25];
  const float* mu_w2     = (const float*)d_in[26];
  const float* mu_b2     = (const float*)d_in[27];
  const float* ls_w1     = (const float*)d_in[28];
  const float* ls_b1     = (const float*)d_in[29];
  const float* ls_w2     = (const float*)d_in[30];
  const float* ls_b2     = (const float*)d_in[31];
  const float* d_w1      = (const float*)d_in[32];
  const float* d_b1      = (const float*)d_in[33];
  const float* d_w2      = (const float*)d_in[34];
  const float* d_b2      = (const float*)d_in[35];
  float* out = (float*)d_out;

  float* ws = (float*)d_ws;
  float* h      = ws;                    // [32768,64]
  float* qkv    = ws + 2097152;          // [32768,192]
  float* obuf   = ws + 8388608;          // [32768,64] attn out
  float* ff     = ws + 2097152;          // [32768,256] aliases qkv+obuf (dead by ff1)
  float* pooled = ws + 10485760;         // [128,64]
  int*   ip     = (int*)(ws + 10493952);
  int*   flag   = ip;
  int*   counts = ip + 8;
  int*   lens   = ip + 16;               // [128]
  int*   idxbuf = ip + 144;              // [8][32768]

  detect_mask_kernel<<<1, 256, 0, stream>>>((const unsigned int*)mask, flag, counts, lens);
  bin_kernel<<<128, 256, 0, stream>>>(sid, mask, flag, counts, lens, idxbuf);
  init_emb_kernel<<<8192, 256, 0, stream>>>(sid, shank_emb, h);
  conv_mfma_kernel<<<CONV_BPG * 8, 256, 0, stream>>>(idxbuf, counts, wav, conv1_w, conv1_b,
                                                     conv2_w, conv2_b, h);
  for (int l = 0; l < 2; l++) {
    gemm_nt<12, 0><<<512, 256, 0, stream>>>(
        h, in_proj_w + l * 12288, in_proj_b + l * 192, qkv, nullptr, nullptr, nullptr, 64);
    attn_kernel<<<512, 256, 0, stream>>>(qkv, lens, obuf);
    gemm_nt<4, 2><<<512, 256, 0, stream>>>(
        obuf, out_proj_w + l * 4096, out_proj_b + l * 64, nullptr, h,
        ln1_g + l * 64, ln1_b + l * 64, 64);
    gemm_nt<16, 1><<<512, 256, 0, stream>>>(
        h, ff1_w + l * 16384, ff1_b + l * 256, ff, nullptr, nullptr, nullptr, 64);
    gemm_nt<4, 2><<<512, 256, 0, stream>>>(
        ff, ff2_w + l * 16384, ff2_b + l * 64, nullptr, h,
        ln2_g + l * 64, ln2_b + l * 64, 256);
  }
  pool_kernel<<<128, 256, 0, stream>>>(h, lens, pooled);
  heads_kernel<<<128, 64, 0, stream>>>(pooled, cls_w1, cls_b1, cls_w2, cls_b2,
                                       mu_w1, mu_b1, mu_w2, mu_b2,
                                       ls_w1, ls_b1, ls_w2, ls_b2,
                                       d_w1, d_b1, d_w2, d_b2, out);
}

// Round 8
// 368.224 us; speedup vs baseline: 4.2138x; 1.0138x over previous
//
#include <hip/hip_runtime.h>
#include <math.h>

// B=128, S=256, G=8, CMAX=6, T=32, E=64, NH=4, dh=16, L=2, DFF=256, Z=3

typedef short bf16x8 __attribute__((ext_vector_type(8)));
typedef float f32x4 __attribute__((ext_vector_type(4)));

__device__ __forceinline__ unsigned short f2bf(float f) {
  unsigned u = __float_as_uint(f);
  u += 0x7fffu + ((u >> 16) & 1u);   // RNE
  return (unsigned short)(u >> 16);
}

__device__ __forceinline__ bf16x8 ldfrag(const unsigned short* p) {
  return *reinterpret_cast<const bf16x8*>(p);
}

__device__ __forceinline__ void ld4(const float* p, float* dst) {
  float4 t = *reinterpret_cast<const float4*>(p);
  dst[0] = t.x; dst[1] = t.y; dst[2] = t.z; dst[3] = t.w;
}

__device__ __forceinline__ bool is_masked(const void* mask_, int flag, int idx) {
  return flag ? (((const unsigned char*)mask_)[idx] != 0)
              : (((const int*)mask_)[idx] != 0);
}

// Detect mask dtype (int32 vs byte-packed bool); zero counters.
__global__ void detect_mask_kernel(const unsigned int* __restrict__ mw,
                                   int* __restrict__ flag, int* __restrict__ counts,
                                   int* __restrict__ lens) {
  __shared__ int sh;
  if (threadIdx.x == 0) sh = 0;
  __syncthreads();
  int bad = 0;
  for (int i = threadIdx.x; i < 8192; i += 256)
    if (mw[i] > 1u) bad = 1;
  if (bad) atomicOr(&sh, 1);
  if (threadIdx.x < 8) counts[threadIdx.x] = 0;
  if (threadIdx.x < 128) lens[threadIdx.x] = 0;
  __syncthreads();
  if (threadIdx.x == 0) *flag = sh;
}

// Bin active tokens by shank id. Hierarchical atomics (8-way LDS -> 1 global/g).
__global__ __launch_bounds__(256) void bin_kernel(
    const int* __restrict__ sid, const void* __restrict__ mask_,
    const int* __restrict__ flagp, int* __restrict__ counts,
    int* __restrict__ lens, int* __restrict__ idxbuf) {
  __shared__ int lcnt[8];
  __shared__ int lbase[8];
  int b = blockIdx.x, tid = threadIdx.x;
  int n = b * 256 + tid;
  int flag = *flagp;
  bool act = !is_masked(mask_, flag, n);
  int g = act ? sid[n] : 0;
  if (tid < 8) lcnt[tid] = 0;
  __syncthreads();
  int pos = 0;
  if (act) pos = atomicAdd(&lcnt[g], 1);
  __syncthreads();
  if (tid < 8) lbase[tid] = atomicAdd(&counts[tid], lcnt[tid]);
  if (tid == 0)
    lens[b] = lcnt[0] + lcnt[1] + lcnt[2] + lcnt[3] +
              lcnt[4] + lcnt[5] + lcnt[6] + lcnt[7];
  __syncthreads();
  if (act) idxbuf[g * 32768 + lbase[g] + pos] = n;
}

// Base embedding: shank_emb[sid] + positional encoding. Conv kernel later
// OVERWRITES rows of active tokens (full value incl. shank+PE).
__global__ __launch_bounds__(256) void init_emb_kernel(
    const int* __restrict__ sid, const float* __restrict__ shank_emb,
    float* __restrict__ hout) {
  int i = blockIdx.x * 256 + threadIdx.x;
  int n = i >> 6, e = i & 63, s = n & 255;
  int g = sid[n];
  float div = __expf(-(float)(e & ~1) * (9.21034037f / 64.f));
  float angle = (float)s * div;
  float pe = (e & 1) ? cosf(angle) : sinf(angle);
  hout[i] = shank_emb[g * 64 + e] + pe;
}

// Conv encoder via bf16 MFMA — WAVE-INDEPENDENT: each wave owns one token per
// iteration with private xw/h1w LDS slices. No __syncthreads in the loop
// (conv2 reads only h1 rows the same wave's conv1 wrote; intra-wave LDS is
// in-order). Epilogue: shfl-redistribute -> one coalesced float store per
// lane, with shank_emb + positional encoding folded in (no RMW).
__global__ __launch_bounds__(256) void conv_mfma_kernel(
    const int* __restrict__ idxbuf, const int* __restrict__ counts,
    const float* __restrict__ wav,
    const float* __restrict__ w1_, const float* __restrict__ b1_,
    const float* __restrict__ w2_, const float* __restrict__ b2_,
    const float* __restrict__ shank_emb, float* __restrict__ hout) {
  __shared__ __align__(16) unsigned short w1f[5][32][8];    // [tap][oc][ic pad8]
  __shared__ __align__(16) unsigned short w2f[3][64][40];   // [tap][e][ic pad40]
  __shared__ float b1s[32];
  __shared__ float b2s[64];
  __shared__ __align__(16) unsigned short xw[4][36][8];     // per-wave [tpad][ic]
  __shared__ __align__(16) unsigned short h1w[4][34][40];   // per-wave [tpad][oc]
  int g = blockIdx.x & 7, bib = blockIdx.x >> 3;
  int tid = threadIdx.x;
  int wv = tid >> 6, lane = tid & 63, quad = lane >> 4, l15 = lane & 15;
  for (int i = tid; i < 1280; i += 256) {
    int k = i >> 8, rest = i & 255, oc = rest >> 3, ic = rest & 7;
    w1f[k][oc][ic] = (ic < 6) ? f2bf(w1_[g * 960 + oc * 30 + ic * 5 + k]) : 0;
  }
  for (int i = tid; i < 7680; i += 256) {
    int k = i / 2560, rest = i % 2560, e = rest / 40, ic = rest % 40;
    w2f[k][e][ic] = (ic < 32) ? f2bf(w2_[g * 6144 + e * 96 + ic * 3 + k]) : 0;
  }
  if (tid < 32) b1s[tid] = b1_[g * 32 + tid];
  if (tid < 64) b2s[tid] = b2_[g * 64 + tid];
  // per-wave: zero own xw slice fully (pads + ic 6,7 stay zero forever)
  {
    unsigned int* xz = (unsigned int*)&xw[wv][0][0];
    for (int i = lane; i < 144; i += 64) xz[i] = 0;
    // h1w rows 0 and 33 zero
    unsigned int* hz0 = (unsigned int*)&h1w[wv][0][0];
    unsigned int* hz1 = (unsigned int*)&h1w[wv][33][0];
    if (lane < 20) hz0[lane] = 0;
    else if (lane < 40) hz1[lane - 20] = 0;
  }
  __syncthreads();   // weights visible to all waves (the only barrier)
  bf16x8 zf = {0, 0, 0, 0, 0, 0, 0, 0};
  bf16x8 bf1[2], bf1k4[2], bf2[3][4];
#pragma unroll
  for (int nt = 0; nt < 2; nt++) {
    bf1[nt] = ldfrag(&w1f[quad][nt * 16 + l15][0]);
    bf1k4[nt] = (quad == 0) ? ldfrag(&w1f[4][nt * 16 + l15][0]) : zf;
  }
#pragma unroll
  for (int k = 0; k < 3; k++)
#pragma unroll
    for (int nt = 0; nt < 4; nt++)
      bf2[k][nt] = ldfrag(&w2f[k][nt * 16 + l15][quad * 8]);
  float b1v0 = b1s[l15], b1v1 = b1s[16 + l15];
  float shank = shank_emb[g * 64 + lane];
  float dive = __expf(-(float)(lane & ~1) * (9.21034037f / 64.f));
  int cnt = counts[g];
  int wvg = bib * 4 + wv;
  int ic_w = lane >> 3, t0_w = (lane & 7) * 4;   // this lane's xw write slot
  for (int ti = wvg; ti < cnt; ti += 256) {
    int n = idxbuf[g * 32768 + ti];
    // load this wave's token: 48 lanes x float4 = 192 floats
    float4 v = make_float4(0.f, 0.f, 0.f, 0.f);
    if (lane < 48) v = *(const float4*)&wav[n * 192 + lane * 4];
    if (lane < 48) {
      xw[wv][t0_w + 2][ic_w] = f2bf(v.x);
      xw[wv][t0_w + 3][ic_w] = f2bf(v.y);
      xw[wv][t0_w + 4][ic_w] = f2bf(v.z);
      xw[wv][t0_w + 5][ic_w] = f2bf(v.w);
    }
    // conv1: 8 MFMA (tap-packed)
    f32x4 c1[2][2];
#pragma unroll
    for (int mt = 0; mt < 2; mt++) {
      c1[mt][0] = (f32x4){b1v0, b1v0, b1v0, b1v0};
      c1[mt][1] = (f32x4){b1v1, b1v1, b1v1, b1v1};
    }
#pragma unroll
    for (int mt = 0; mt < 2; mt++) {
      bf16x8 afm = ldfrag(&xw[wv][mt * 16 + l15 + quad][0]);
      bf16x8 af4 = (quad == 0) ? ldfrag(&xw[wv][mt * 16 + l15 + 4][0]) : zf;
#pragma unroll
      for (int nt = 0; nt < 2; nt++) {
        c1[mt][nt] = __builtin_amdgcn_mfma_f32_16x16x32_bf16(afm, bf1[nt], c1[mt][nt], 0, 0, 0);
        c1[mt][nt] = __builtin_amdgcn_mfma_f32_16x16x32_bf16(af4, bf1k4[nt], c1[mt][nt], 0, 0, 0);
      }
    }
#pragma unroll
    for (int mt = 0; mt < 2; mt++)
#pragma unroll
      for (int nt = 0; nt < 2; nt++)
#pragma unroll
        for (int r = 0; r < 4; r++) {
          int t = mt * 16 + quad * 4 + r;
          h1w[wv][t + 1][nt * 16 + l15] = f2bf(fmaxf(c1[mt][nt][r], 0.f));
        }
    // conv2: 24 MFMA
    f32x4 c2[2][4];
#pragma unroll
    for (int mt = 0; mt < 2; mt++)
#pragma unroll
      for (int nt = 0; nt < 4; nt++) {
        float bv = b2s[nt * 16 + l15];
        c2[mt][nt] = (f32x4){bv, bv, bv, bv};
      }
#pragma unroll
    for (int k = 0; k < 3; k++)
#pragma unroll
      for (int mt = 0; mt < 2; mt++) {
        bf16x8 af = ldfrag(&h1w[wv][mt * 16 + l15 + k][quad * 8]);
#pragma unroll
        for (int nt = 0; nt < 4; nt++)
          c2[mt][nt] = __builtin_amdgcn_mfma_f32_16x16x32_bf16(af, bf2[k][nt], c2[mt][nt], 0, 0, 0);
      }
    // relu + mean over t (local 8 + shfl over quads), redistribute, store
    float sums[4];
#pragma unroll
    for (int nt = 0; nt < 4; nt++) {
      float s = 0.f;
#pragma unroll
      for (int mt = 0; mt < 2; mt++)
#pragma unroll
        for (int r = 0; r < 4; r++) s += fmaxf(c2[mt][nt][r], 0.f);
      s += __shfl_xor(s, 16);
      s += __shfl_xor(s, 32);
      sums[nt] = s;
    }
    float t0 = __shfl(sums[0], l15);
    float t1 = __shfl(sums[1], l15);
    float t2 = __shfl(sums[2], l15);
    float t3 = __shfl(sums[3], l15);
    float val = (quad == 0) ? t0 : (quad == 1) ? t1 : (quad == 2) ? t2 : t3;
    float angle = (float)(n & 255) * dive;
    float pe = (lane & 1) ? cosf(angle) : sinf(angle);
    hout[(size_t)n * 64 + lane] = val * (1.f / 32.f) + shank + pe;
  }
}

// bf16-MFMA GEMM, full-N per block: out = A[M][K] @ W[N][K]^T + bias.
// MODE 0: store C. MODE 1: relu, store C. MODE 2 (NT==4): H = LayerNorm(H + out).
template <int NT, int MODE>
__global__ __launch_bounds__(256) void gemm_nt(
    const float* __restrict__ A, const float* __restrict__ W,
    const float* __restrict__ bias, float* __restrict__ C,
    float* __restrict__ H, const float* __restrict__ lng,
    const float* __restrict__ lnb, int K) {
  constexpr int N = NT * 16;
  __shared__ __align__(16) unsigned short As[64][72];
  __shared__ __align__(16) unsigned short Bs[N][72];
  int m0 = blockIdx.x * 64;
  int tid = threadIdx.x;
  int wv = tid >> 6, lane = tid & 63, quad = lane >> 4, l15 = lane & 15;
  f32x4 acc[NT];
#pragma unroll
  for (int nt = 0; nt < NT; nt++) {
    float b = bias[nt * 16 + l15];
    acc[nt] = (f32x4){b, b, b, b};
  }
  for (int kc = 0; kc < K; kc += 64) {
    __syncthreads();
    for (int i = tid; i < 1024; i += 256) {
      int r = i >> 4, c4 = (i & 15) << 2;
      float4 av = *(const float4*)&A[(size_t)(m0 + r) * K + kc + c4];
      short4 t;
      t.x = (short)f2bf(av.x); t.y = (short)f2bf(av.y);
      t.z = (short)f2bf(av.z); t.w = (short)f2bf(av.w);
      *(short4*)&As[r][c4] = t;
    }
    for (int i = tid; i < N * 16; i += 256) {
      int r = i >> 4, c4 = (i & 15) << 2;
      float4 wv4 = *(const float4*)&W[(size_t)r * K + kc + c4];
      short4 u;
      u.x = (short)f2bf(wv4.x); u.y = (short)f2bf(wv4.y);
      u.z = (short)f2bf(wv4.z); u.w = (short)f2bf(wv4.w);
      *(short4*)&Bs[r][c4] = u;
    }
    __syncthreads();
#pragma unroll
    for (int ks = 0; ks < 64; ks += 32) {
      bf16x8 af = ldfrag(&As[wv * 16 + l15][ks + quad * 8]);
#pragma unroll
      for (int nt = 0; nt < NT; nt++) {
        bf16x8 bfr = ldfrag(&Bs[nt * 16 + l15][ks + quad * 8]);
        acc[nt] = __builtin_amdgcn_mfma_f32_16x16x32_bf16(af, bfr, acc[nt], 0, 0, 0);
      }
    }
  }
  int mrow = m0 + wv * 16 + quad * 4;
  if (MODE <= 1) {
#pragma unroll
    for (int nt = 0; nt < NT; nt++)
#pragma unroll
      for (int r = 0; r < 4; r++) {
        float v = acc[nt][r];
        if (MODE == 1) v = fmaxf(v, 0.f);
        C[(size_t)(mrow + r) * N + nt * 16 + l15] = v;
      }
  } else {
#pragma unroll
    for (int r = 0; r < 4; r++) {
      float rv[4];
      float s = 0.f;
#pragma unroll
      for (int nt = 0; nt < 4; nt++) {
        float v = acc[nt][r] + H[(size_t)(mrow + r) * 64 + nt * 16 + l15];
        rv[nt] = v; s += v;
      }
      s += __shfl_xor(s, 1); s += __shfl_xor(s, 2);
      s += __shfl_xor(s, 4); s += __shfl_xor(s, 8);
      float mean = s * (1.f / 64.f);
      float vsum = 0.f;
#pragma unroll
      for (int nt = 0; nt < 4; nt++) { rv[nt] -= mean; vsum += rv[nt] * rv[nt]; }
      vsum += __shfl_xor(vsum, 1); vsum += __shfl_xor(vsum, 2);
      vsum += __shfl_xor(vsum, 4); vsum += __shfl_xor(vsum, 8);
      float inv = rsqrtf(vsum * (1.f / 64.f) + 1e-5f);
#pragma unroll
      for (int nt = 0; nt < 4; nt++) {
        int col = nt * 16 + l15;
        H[(size_t)(mrow + r) * 64 + col] = rv[nt] * inv * lng[col] + lnb[col];
      }
    }
  }
}

// MFMA flash attention. Block = (b, head), 4 waves, each wave owns 4 q-tiles
// of 16 queries. Full-row softmax; P via per-wave LDS; PV via 8 MFMA.
__global__ __launch_bounds__(256) void attn_kernel(
    const float* __restrict__ qkv, const int* __restrict__ lens,
    float* __restrict__ o) {
  __shared__ __align__(16) unsigned short qs[256][24];   // q*0.25, bf16
  __shared__ __align__(16) unsigned short kst[256][24];
  __shared__ __align__(16) unsigned short vT[16][264];   // [d][key]
  __shared__ __align__(16) unsigned short pw[4][16][264]; // per-wave P[q][key]
  int bh = blockIdx.x;
  int b_ = bh >> 2, hd = bh & 3;
  int tid = threadIdx.x;
  int wv = tid >> 6, lane = tid & 63, quad = lane >> 4, l15 = lane & 15;
  int len = lens[b_];
  const float* base = qkv + b_ * 256 * 192 + hd * 16;
  for (int i = tid; i < 1024; i += 256) {
    int s = i >> 2, c = (i & 3) << 2;
    const float* rp = base + s * 192;
    float4 q4 = *(const float4*)(rp + c);
    float4 k4 = *(const float4*)(rp + 64 + c);
    float4 v4 = *(const float4*)(rp + 128 + c);
    short4 qp, kp;
    qp.x = (short)f2bf(q4.x * 0.25f); qp.y = (short)f2bf(q4.y * 0.25f);
    qp.z = (short)f2bf(q4.z * 0.25f); qp.w = (short)f2bf(q4.w * 0.25f);
    kp.x = (short)f2bf(k4.x); kp.y = (short)f2bf(k4.y);
    kp.z = (short)f2bf(k4.z); kp.w = (short)f2bf(k4.w);
    *(short4*)&qs[s][c] = qp;
    *(short4*)&kst[s][c] = kp;
    vT[c + 0][s] = f2bf(v4.x);
    vT[c + 1][s] = f2bf(v4.y);
    vT[c + 2][s] = f2bf(v4.z);
    vT[c + 3][s] = f2bf(v4.w);
  }
  __syncthreads();
  bf16x8 zf = {0, 0, 0, 0, 0, 0, 0, 0};
  f32x4 zero = {0.f, 0.f, 0.f, 0.f};
#pragma unroll 1
  for (int j = 0; j < 4; j++) {
    int qt = wv * 4 + j;
    bf16x8 bq = (quad < 2) ? ldfrag(&qs[qt * 16 + l15][quad * 8]) : zf;
    f32x4 s[16];
#pragma unroll
    for (int t = 0; t < 16; t++) {
      bf16x8 ak = (quad < 2) ? ldfrag(&kst[t * 16 + l15][quad * 8]) : zf;
      s[t] = __builtin_amdgcn_mfma_f32_16x16x32_bf16(ak, bq, zero, 0, 0, 0);
    }
    float mx = -1e30f;
#pragma unroll
    for (int t = 0; t < 16; t++)
#pragma unroll
      for (int r = 0; r < 4; r++) {
        int key = t * 16 + quad * 4 + r;
        float v = (key < len) ? s[t][r] : -1e30f;
        s[t][r] = v;
        mx = fmaxf(mx, v);
      }
    mx = fmaxf(mx, __shfl_xor(mx, 16));
    mx = fmaxf(mx, __shfl_xor(mx, 32));
    float sum = 0.f;
#pragma unroll
    for (int t = 0; t < 16; t++)
#pragma unroll
      for (int r = 0; r < 4; r++) {
        float p = __expf(s[t][r] - mx);
        s[t][r] = p;
        sum += p;
      }
    sum += __shfl_xor(sum, 16);
    sum += __shfl_xor(sum, 32);
#pragma unroll
    for (int t = 0; t < 16; t++) {
      short4 pp;
      pp.x = (short)f2bf(s[t][0]); pp.y = (short)f2bf(s[t][1]);
      pp.z = (short)f2bf(s[t][2]); pp.w = (short)f2bf(s[t][3]);
      *(short4*)&pw[wv][l15][t * 16 + quad * 4] = pp;
    }
    f32x4 acc = zero;
#pragma unroll
    for (int c = 0; c < 8; c++) {
      bf16x8 av = ldfrag(&vT[l15][c * 32 + quad * 8]);
      bf16x8 bp = ldfrag(&pw[wv][l15][c * 32 + quad * 8]);
      acc = __builtin_amdgcn_mfma_f32_16x16x32_bf16(av, bp, acc, 0, 0, 0);
    }
    float inv = 1.f / sum;
    float4 w;
    w.x = acc[0] * inv; w.y = acc[1] * inv;
    w.z = acc[2] * inv; w.w = acc[3] * inv;
    *(float4*)&o[(size_t)(b_ * 256 + qt * 16 + l15) * 64 + hd * 16 + quad * 4] = w;
  }
}

// Masked mean pool using per-b active length.
__global__ __launch_bounds__(256) void pool_kernel(
    const float* __restrict__ h, const int* __restrict__ lens,
    float* __restrict__ pooled) {
  __shared__ float ps[4][64];
  int b = blockIdx.x;
  int e = threadIdx.x & 63, sp = threadIdx.x >> 6;
  int len = lens[b];
  float sum = 0.f;
  int send = min(sp * 64 + 64, len);
  for (int s = sp * 64; s < send; s++) sum += h[(b * 256 + s) * 64 + e];
  ps[sp][e] = sum;
  __syncthreads();
  if (sp == 0) {
    float tot = ps[0][e] + ps[1][e] + ps[2][e] + ps[3][e];
    pooled[b * 64 + e] = tot / ((float)len + 1e-8f);
  }
}

// Fused heads: cls(3), mus(6), sigmas(6), d(1) -> 16 outputs per b.
__global__ __launch_bounds__(64) void heads_kernel(
    const float* __restrict__ pooled,
    const float* __restrict__ cls_w1, const float* __restrict__ cls_b1,
    const float* __restrict__ cls_w2, const float* __restrict__ cls_b2,
    const float* __restrict__ mu_w1, const float* __restrict__ mu_b1,
    const float* __restrict__ mu_w2, const float* __restrict__ mu_b2,
    const float* __restrict__ ls_w1, const float* __restrict__ ls_b1,
    const float* __restrict__ ls_w2, const float* __restrict__ ls_b2,
    const float* __restrict__ d_w1, const float* __restrict__ d_b1,
    const float* __restrict__ d_w2, const float* __restrict__ d_b2,
    float* __restrict__ out) {
  int b = blockIdx.x, e = threadIdx.x;
  __shared__ float p[64];
  __shared__ float t1[64];
  p[e] = pooled[b * 64 + e];
  __syncthreads();
  {
    float a = cls_b1[e];
    for (int j = 0; j < 64; j++) a += p[j] * cls_w1[e * 64 + j];
    t1[e] = fmaxf(a, 0.f);
  }
  __syncthreads();
  if (e < 3) {
    float a2 = cls_b2[e];
    for (int j = 0; j < 64; j++) a2 += t1[j] * cls_w2[e * 64 + j];
    out[b * 16 + e] = a2;
  }
  for (int z = 0; z < 3; z++) {
    __syncthreads();
    {
      float a = mu_b1[z * 64 + e];
      for (int j = 0; j < 64; j++) a += p[j] * mu_w1[(z * 64 + e) * 64 + j];
      t1[e] = fmaxf(a, 0.f);
    }
    __syncthreads();
    if (e < 2) {
      float a2 = mu_b2[z * 2 + e];
      for (int j = 0; j < 64; j++) a2 += t1[j] * mu_w2[(z * 2 + e) * 64 + j];
      out[b * 16 + 3 + z * 2 + e] = a2;
    }
    __syncthreads();
    {
      float a = ls_b1[z * 64 + e];
      for (int j = 0; j < 64; j++) a += p[j] * ls_w1[(z * 64 + e) * 64 + j];
      t1[e] = fmaxf(a, 0.f);
    }
    __syncthreads();
    if (e < 2) {
      float a2 = ls_b2[z * 2 + e];
      for (int j = 0; j < 64; j++) a2 += t1[j] * ls_w2[(z * 2 + e) * 64 + j];
      out[b * 16 + 9 + z * 2 + e] = __expf(a2);
    }
  }
  __syncthreads();
  {
    float a = d_b1[e];
    for (int j = 0; j < 64; j++) a += p[j] * d_w1[e * 64 + j];
    t1[e] = fmaxf(a, 0.f);
  }
  __syncthreads();
  if (e == 0) {
    float a2 = d_b2[0];
    for (int j = 0; j < 64; j++) a2 += t1[j] * d_w2[j];
    out[b * 16 + 15] = 1.f / (1.f + __expf(-a2));
  }
}

extern "C" void kernel_launch(void* const* d_in, const int* in_sizes, int n_in,
                              void* d_out, int out_size, void* d_ws, size_t ws_size,
                              hipStream_t stream) {
  const float* wav       = (const float*)d_in[0];
  const int*   sid       = (const int*)d_in[1];
  const void*  mask      = d_in[2];
  const float* conv1_w   = (const float*)d_in[3];
  const float* conv1_b   = (const float*)d_in[4];
  const float* conv2_w   = (const float*)d_in[5];
  const float* conv2_b   = (const float*)d_in[6];
  const float* shank_emb = (const float*)d_in[7];
  const float* in_proj_w = (const float*)d_in[8];
  const float* in_proj_b = (const float*)d_in[9];
  const float* out_proj_w= (const float*)d_in[10];
  const float* out_proj_b= (const float*)d_in[11];
  const float* ln1_g     = (const float*)d_in[12];
  const float* ln1_b     = (const float*)d_in[13];
  const float* ff1_w     = (const float*)d_in[14];
  const float* ff1_b     = (const float*)d_in[15];
  const float* ff2_w     = (const float*)d_in[16];
  const float* ff2_b     = (const float*)d_in[17];
  const float* ln2_g     = (const float*)d_in[18];
  const float* ln2_b     = (const float*)d_in[19];
  const float* cls_w1    = (const float*)d_in[20];
  const float* cls_b1    = (const float*)d_in[21];
  const float* cls_w2    = (const float*)d_in[22];
  const float* cls_b2    = (const float*)d_in[23];
  const float* mu_w1     = (const float*)d_in[24];
  const float* mu_b1     = (const float*)d_in[25];
  const float* mu_w2     = (const float*)d_in[26];
  const float* mu_b2     = (const float*)d_in[27];
  const float* ls_w1     = (const float*)d_in[28];
  const float* ls_b1     = (const float*)d_in[29];
  const float* ls_w2     = (const float*)d_in[30];
  const float* ls_b2     = (const float*)d_in[31];
  const float* d_w1      = (const float*)d_in[32];
  const float* d_b1      = (const float*)d_in[33];
  const float* d_w2      = (const float*)d_in[34];
  const float* d_b2      = (const float*)d_in[35];
  float* out = (float*)d_out;

  float* ws = (float*)d_ws;
  float* h      = ws;                    // [32768,64]
  float* qkv    = ws + 2097152;          // [32768,192]
  float* obuf   = ws + 8388608;          // [32768,64] attn out
  float* ff     = ws + 2097152;          // [32768,256] aliases qkv+obuf (dead by ff1)
  float* pooled = ws + 10485760;         // [128,64]
  int*   ip     = (int*)(ws + 10493952);
  int*   flag   = ip;
  int*   counts = ip + 8;
  int*   lens   = ip + 16;               // [128]
  int*   idxbuf = ip + 144;              // [8][32768]

  detect_mask_kernel<<<1, 256, 0, stream>>>((const unsigned int*)mask, flag, counts, lens);
  bin_kernel<<<128, 256, 0, stream>>>(sid, mask, flag, counts, lens, idxbuf);
  init_emb_kernel<<<8192, 256, 0, stream>>>(sid, shank_emb, h);
  conv_mfma_kernel<<<512, 256, 0, stream>>>(idxbuf, counts, wav, conv1_w, conv1_b,
                                            conv2_w, conv2_b, shank_emb, h);
  for (int l = 0; l < 2; l++) {
    gemm_nt<12, 0><<<512, 256, 0, stream>>>(
        h, in_proj_w + l * 12288, in_proj_b + l * 192, qkv, nullptr, nullptr, nullptr, 64);
    attn_kernel<<<512, 256, 0, stream>>>(qkv, lens, obuf);
    gemm_nt<4, 2><<<512, 256, 0, stream>>>(
        obuf, out_proj_w + l * 4096, out_proj_b + l * 64, nullptr, h,
        ln1_g + l * 64, ln1_b + l * 64, 64);
    gemm_nt<16, 1><<<512, 256, 0, stream>>>(
        h, ff1_w + l * 16384, ff1_b + l * 256, ff, nullptr, nullptr, nullptr, 64);
    gemm_nt<4, 2><<<512, 256, 0, stream>>>(
        ff, ff2_w + l * 16384, ff2_b + l * 64, nullptr, h,
        ln2_g + l * 64, ln2_b + l * 64, 256);
  }
  pool_kernel<<<128, 256, 0, stream>>>(h, lens, pooled);
  heads_kernel<<<128, 64, 0, stream>>>(pooled, cls_w1, cls_b1, cls_w2, cls_b2,
                                       mu_w1, mu_b1, mu_w2, mu_b2,
                                       ls_w1, ls_b1, ls_w2, ls_b2,
                                       d_w1, d_b1, d_w2, d_b2, out);
}

// Round 9
// 340.782 us; speedup vs baseline: 4.5531x; 1.0805x over previous
//
#include <hip/hip_runtime.h>
#include <math.h>

// B=128, S=256, G=8, CMAX=6, T=32, E=64, NH=4, dh=16, L=2, DFF=256, Z=3

typedef short bf16x8 __attribute__((ext_vector_type(8)));
typedef float f32x4 __attribute__((ext_vector_type(4)));

__device__ __forceinline__ unsigned short f2bf(float f) {
  unsigned u = __float_as_uint(f);
  u += 0x7fffu + ((u >> 16) & 1u);   // RNE
  return (unsigned short)(u >> 16);
}

__device__ __forceinline__ float bf2f(unsigned short s) {
  return __uint_as_float(((unsigned)s) << 16);
}

__device__ __forceinline__ bf16x8 ldfrag(const unsigned short* p) {
  return *reinterpret_cast<const bf16x8*>(p);
}

__device__ __forceinline__ bool is_masked(const void* mask_, int flag, int idx) {
  return flag ? (((const unsigned char*)mask_)[idx] != 0)
              : (((const int*)mask_)[idx] != 0);
}

// Detect mask dtype (int32 vs byte-packed bool); zero counters.
__global__ void detect_mask_kernel(const unsigned int* __restrict__ mw,
                                   int* __restrict__ flag, int* __restrict__ counts,
                                   int* __restrict__ lens) {
  __shared__ int sh;
  if (threadIdx.x == 0) sh = 0;
  __syncthreads();
  int bad = 0;
  for (int i = threadIdx.x; i < 8192; i += 256)
    if (mw[i] > 1u) bad = 1;
  if (bad) atomicOr(&sh, 1);
  if (threadIdx.x < 8) counts[threadIdx.x] = 0;
  if (threadIdx.x < 128) lens[threadIdx.x] = 0;
  __syncthreads();
  if (threadIdx.x == 0) *flag = sh;
}

// Bin active tokens by shank id. Hierarchical atomics (8-way LDS -> 1 global/g).
__global__ __launch_bounds__(256) void bin_kernel(
    const int* __restrict__ sid, const void* __restrict__ mask_,
    const int* __restrict__ flagp, int* __restrict__ counts,
    int* __restrict__ lens, int* __restrict__ idxbuf) {
  __shared__ int lcnt[8];
  __shared__ int lbase[8];
  int b = blockIdx.x, tid = threadIdx.x;
  int n = b * 256 + tid;
  int flag = *flagp;
  bool act = !is_masked(mask_, flag, n);
  int g = act ? sid[n] : 0;
  if (tid < 8) lcnt[tid] = 0;
  __syncthreads();
  int pos = 0;
  if (act) pos = atomicAdd(&lcnt[g], 1);
  __syncthreads();
  if (tid < 8) lbase[tid] = atomicAdd(&counts[tid], lcnt[tid]);
  if (tid == 0)
    lens[b] = lcnt[0] + lcnt[1] + lcnt[2] + lcnt[3] +
              lcnt[4] + lcnt[5] + lcnt[6] + lcnt[7];
  __syncthreads();
  if (act) idxbuf[g * 32768 + lbase[g] + pos] = n;
}

// Base embedding: shank_emb[sid] + positional encoding. Conv kernel later
// OVERWRITES rows of active tokens (full value incl. shank+PE).
__global__ __launch_bounds__(256) void init_emb_kernel(
    const int* __restrict__ sid, const float* __restrict__ shank_emb,
    float* __restrict__ hout) {
  int i = blockIdx.x * 256 + threadIdx.x;
  int n = i >> 6, e = i & 63, s = n & 255;
  int g = sid[n];
  float div = __expf(-(float)(e & ~1) * (9.21034037f / 64.f));
  float angle = (float)s * div;
  float pe = (e & 1) ? cosf(angle) : sinf(angle);
  hout[i] = shank_emb[g * 64 + e] + pe;
}

// Conv encoder via bf16 MFMA — wave-independent, 1024 blocks (4/CU).
__global__ __launch_bounds__(256) void conv_mfma_kernel(
    const int* __restrict__ idxbuf, const int* __restrict__ counts,
    const float* __restrict__ wav,
    const float* __restrict__ w1_, const float* __restrict__ b1_,
    const float* __restrict__ w2_, const float* __restrict__ b2_,
    const float* __restrict__ shank_emb, float* __restrict__ hout) {
  __shared__ __align__(16) unsigned short w1f[5][32][8];    // [tap][oc][ic pad8]
  __shared__ __align__(16) unsigned short w2f[3][64][40];   // [tap][e][ic pad40]
  __shared__ float b1s[32];
  __shared__ float b2s[64];
  __shared__ __align__(16) unsigned short xw[4][36][8];     // per-wave [tpad][ic]
  __shared__ __align__(16) unsigned short h1w[4][34][40];   // per-wave [tpad][oc]
  int g = blockIdx.x & 7, bib = blockIdx.x >> 3;
  int tid = threadIdx.x;
  int wv = tid >> 6, lane = tid & 63, quad = lane >> 4, l15 = lane & 15;
  for (int i = tid; i < 1280; i += 256) {
    int k = i >> 8, rest = i & 255, oc = rest >> 3, ic = rest & 7;
    w1f[k][oc][ic] = (ic < 6) ? f2bf(w1_[g * 960 + oc * 30 + ic * 5 + k]) : 0;
  }
  for (int i = tid; i < 7680; i += 256) {
    int k = i / 2560, rest = i % 2560, e = rest / 40, ic = rest % 40;
    w2f[k][e][ic] = (ic < 32) ? f2bf(w2_[g * 6144 + e * 96 + ic * 3 + k]) : 0;
  }
  if (tid < 32) b1s[tid] = b1_[g * 32 + tid];
  if (tid < 64) b2s[tid] = b2_[g * 64 + tid];
  {
    unsigned int* xz = (unsigned int*)&xw[wv][0][0];
    for (int i = lane; i < 144; i += 64) xz[i] = 0;
    unsigned int* hz0 = (unsigned int*)&h1w[wv][0][0];
    unsigned int* hz1 = (unsigned int*)&h1w[wv][33][0];
    if (lane < 20) hz0[lane] = 0;
    else if (lane < 40) hz1[lane - 20] = 0;
  }
  __syncthreads();   // weights visible to all waves (the only barrier)
  bf16x8 zf = {0, 0, 0, 0, 0, 0, 0, 0};
  bf16x8 bf1[2], bf1k4[2], bf2[3][4];
#pragma unroll
  for (int nt = 0; nt < 2; nt++) {
    bf1[nt] = ldfrag(&w1f[quad][nt * 16 + l15][0]);
    bf1k4[nt] = (quad == 0) ? ldfrag(&w1f[4][nt * 16 + l15][0]) : zf;
  }
#pragma unroll
  for (int k = 0; k < 3; k++)
#pragma unroll
    for (int nt = 0; nt < 4; nt++)
      bf2[k][nt] = ldfrag(&w2f[k][nt * 16 + l15][quad * 8]);
  float b1v0 = b1s[l15], b1v1 = b1s[16 + l15];
  float shank = shank_emb[g * 64 + lane];
  float dive = __expf(-(float)(lane & ~1) * (9.21034037f / 64.f));
  int cnt = counts[g];
  int wvg = bib * 4 + wv;
  int ic_w = lane >> 3, t0_w = (lane & 7) * 4;
  for (int ti = wvg; ti < cnt; ti += 512) {
    int n = idxbuf[g * 32768 + ti];
    float4 v = make_float4(0.f, 0.f, 0.f, 0.f);
    if (lane < 48) v = *(const float4*)&wav[n * 192 + lane * 4];
    if (lane < 48) {
      xw[wv][t0_w + 2][ic_w] = f2bf(v.x);
      xw[wv][t0_w + 3][ic_w] = f2bf(v.y);
      xw[wv][t0_w + 4][ic_w] = f2bf(v.z);
      xw[wv][t0_w + 5][ic_w] = f2bf(v.w);
    }
    f32x4 c1[2][2];
#pragma unroll
    for (int mt = 0; mt < 2; mt++) {
      c1[mt][0] = (f32x4){b1v0, b1v0, b1v0, b1v0};
      c1[mt][1] = (f32x4){b1v1, b1v1, b1v1, b1v1};
    }
#pragma unroll
    for (int mt = 0; mt < 2; mt++) {
      bf16x8 afm = ldfrag(&xw[wv][mt * 16 + l15 + quad][0]);
      bf16x8 af4 = (quad == 0) ? ldfrag(&xw[wv][mt * 16 + l15 + 4][0]) : zf;
#pragma unroll
      for (int nt = 0; nt < 2; nt++) {
        c1[mt][nt] = __builtin_amdgcn_mfma_f32_16x16x32_bf16(afm, bf1[nt], c1[mt][nt], 0, 0, 0);
        c1[mt][nt] = __builtin_amdgcn_mfma_f32_16x16x32_bf16(af4, bf1k4[nt], c1[mt][nt], 0, 0, 0);
      }
    }
#pragma unroll
    for (int mt = 0; mt < 2; mt++)
#pragma unroll
      for (int nt = 0; nt < 2; nt++)
#pragma unroll
        for (int r = 0; r < 4; r++) {
          int t = mt * 16 + quad * 4 + r;
          h1w[wv][t + 1][nt * 16 + l15] = f2bf(fmaxf(c1[mt][nt][r], 0.f));
        }
    f32x4 c2[2][4];
#pragma unroll
    for (int mt = 0; mt < 2; mt++)
#pragma unroll
      for (int nt = 0; nt < 4; nt++) {
        float bv = b2s[nt * 16 + l15];
        c2[mt][nt] = (f32x4){bv, bv, bv, bv};
      }
#pragma unroll
    for (int k = 0; k < 3; k++)
#pragma unroll
      for (int mt = 0; mt < 2; mt++) {
        bf16x8 af = ldfrag(&h1w[wv][mt * 16 + l15 + k][quad * 8]);
#pragma unroll
        for (int nt = 0; nt < 4; nt++)
          c2[mt][nt] = __builtin_amdgcn_mfma_f32_16x16x32_bf16(af, bf2[k][nt], c2[mt][nt], 0, 0, 0);
      }
    float sums[4];
#pragma unroll
    for (int nt = 0; nt < 4; nt++) {
      float s = 0.f;
#pragma unroll
      for (int mt = 0; mt < 2; mt++)
#pragma unroll
        for (int r = 0; r < 4; r++) s += fmaxf(c2[mt][nt][r], 0.f);
      s += __shfl_xor(s, 16);
      s += __shfl_xor(s, 32);
      sums[nt] = s;
    }
    float t0 = __shfl(sums[0], l15);
    float t1 = __shfl(sums[1], l15);
    float t2 = __shfl(sums[2], l15);
    float t3 = __shfl(sums[3], l15);
    float val = (quad == 0) ? t0 : (quad == 1) ? t1 : (quad == 2) ? t2 : t3;
    float angle = (float)(n & 255) * dive;
    float pe = (lane & 1) ? cosf(angle) : sinf(angle);
    hout[(size_t)n * 64 + lane] = val * (1.f / 32.f) + shank + pe;
  }
}

// bf16-MFMA GEMM (qkv only): C = A[M][64] @ W[192][64]^T + bias.
__global__ __launch_bounds__(256) void gemm_qkv(
    const float* __restrict__ A, const float* __restrict__ W,
    const float* __restrict__ bias, float* __restrict__ C) {
  __shared__ __align__(16) unsigned short As[64][72];
  __shared__ __align__(16) unsigned short Bs[192][72];
  int m0 = blockIdx.x * 64;
  int tid = threadIdx.x;
  int wv = tid >> 6, lane = tid & 63, quad = lane >> 4, l15 = lane & 15;
  f32x4 acc[12];
#pragma unroll
  for (int nt = 0; nt < 12; nt++) {
    float b = bias[nt * 16 + l15];
    acc[nt] = (f32x4){b, b, b, b};
  }
  for (int i = tid; i < 1024; i += 256) {
    int r = i >> 4, c4 = (i & 15) << 2;
    float4 av = *(const float4*)&A[(size_t)(m0 + r) * 64 + c4];
    short4 t;
    t.x = (short)f2bf(av.x); t.y = (short)f2bf(av.y);
    t.z = (short)f2bf(av.z); t.w = (short)f2bf(av.w);
    *(short4*)&As[r][c4] = t;
  }
  for (int i = tid; i < 3072; i += 256) {
    int r = i >> 4, c4 = (i & 15) << 2;
    float4 wv4 = *(const float4*)&W[(size_t)r * 64 + c4];
    short4 u;
    u.x = (short)f2bf(wv4.x); u.y = (short)f2bf(wv4.y);
    u.z = (short)f2bf(wv4.z); u.w = (short)f2bf(wv4.w);
    *(short4*)&Bs[r][c4] = u;
  }
  __syncthreads();
#pragma unroll
  for (int ks = 0; ks < 64; ks += 32) {
    bf16x8 af = ldfrag(&As[wv * 16 + l15][ks + quad * 8]);
#pragma unroll
    for (int nt = 0; nt < 12; nt++) {
      bf16x8 bfr = ldfrag(&Bs[nt * 16 + l15][ks + quad * 8]);
      acc[nt] = __builtin_amdgcn_mfma_f32_16x16x32_bf16(af, bfr, acc[nt], 0, 0, 0);
    }
  }
  int mrow = m0 + wv * 16 + quad * 4;
#pragma unroll
  for (int nt = 0; nt < 12; nt++)
#pragma unroll
    for (int r = 0; r < 4; r++)
      C[(size_t)(mrow + r) * 192 + nt * 16 + l15] = acc[nt][r];
}

// Fused row-local: H = LN2( LN1(H + obuf@Wout^T + bo) + relu(...)@... ).
// One weight-staging barrier; afterwards every wave touches only its own
// 16 rows (wave-independent, no further barriers). ff activations never
// leave LDS.
__global__ __launch_bounds__(256) void fused_rl_kernel(
    const float* __restrict__ obuf, float* __restrict__ H,
    const float* __restrict__ Wout, const float* __restrict__ bout,
    const float* __restrict__ ln1g, const float* __restrict__ ln1b,
    const float* __restrict__ Wff1, const float* __restrict__ bff1,
    const float* __restrict__ Wff2, const float* __restrict__ bff2,
    const float* __restrict__ ln2g, const float* __restrict__ ln2b) {
  __shared__ __align__(16) unsigned short Ao[64][72];
  __shared__ __align__(16) unsigned short Wo[64][72];
  __shared__ __align__(16) unsigned short W1s[256][72];
  __shared__ __align__(16) unsigned short W2s[64][264];
  __shared__ __align__(16) unsigned short h1b[64][72];
  __shared__ __align__(16) unsigned short ffa[64][264];
  __shared__ float h1f[64][68];
  int m0 = blockIdx.x * 64;
  int tid = threadIdx.x;
  int wv = tid >> 6, lane = tid & 63, quad = lane >> 4, l15 = lane & 15;
  for (int i = tid; i < 1024; i += 256) {
    int r = i >> 4, c4 = (i & 15) << 2;
    float4 av = *(const float4*)&obuf[(size_t)(m0 + r) * 64 + c4];
    short4 t;
    t.x = (short)f2bf(av.x); t.y = (short)f2bf(av.y);
    t.z = (short)f2bf(av.z); t.w = (short)f2bf(av.w);
    *(short4*)&Ao[r][c4] = t;
    float4 wv4 = *(const float4*)&Wout[(size_t)r * 64 + c4];
    short4 u;
    u.x = (short)f2bf(wv4.x); u.y = (short)f2bf(wv4.y);
    u.z = (short)f2bf(wv4.z); u.w = (short)f2bf(wv4.w);
    *(short4*)&Wo[r][c4] = u;
  }
  for (int i = tid; i < 4096; i += 256) {
    int r = i >> 4, c4 = (i & 15) << 2;
    float4 wv4 = *(const float4*)&Wff1[(size_t)r * 64 + c4];
    short4 u;
    u.x = (short)f2bf(wv4.x); u.y = (short)f2bf(wv4.y);
    u.z = (short)f2bf(wv4.z); u.w = (short)f2bf(wv4.w);
    *(short4*)&W1s[r][c4] = u;
  }
  for (int i = tid; i < 4096; i += 256) {
    int r = i >> 6, c4 = (i & 63) << 2;
    float4 wv4 = *(const float4*)&Wff2[(size_t)r * 256 + c4];
    short4 u;
    u.x = (short)f2bf(wv4.x); u.y = (short)f2bf(wv4.y);
    u.z = (short)f2bf(wv4.z); u.w = (short)f2bf(wv4.w);
    *(short4*)&W2s[r][c4] = u;
  }
  __syncthreads();   // the only barrier
  int lr = wv * 16 + quad * 4;          // local row base (this thread's 4 rows)
  // ---- outproj + LN1 ----
  f32x4 acc[4];
#pragma unroll
  for (int nt = 0; nt < 4; nt++) {
    float b = bout[nt * 16 + l15];
    acc[nt] = (f32x4){b, b, b, b};
  }
#pragma unroll
  for (int ks = 0; ks < 64; ks += 32) {
    bf16x8 af = ldfrag(&Ao[wv * 16 + l15][ks + quad * 8]);
#pragma unroll
    for (int nt = 0; nt < 4; nt++) {
      bf16x8 bfr = ldfrag(&Wo[nt * 16 + l15][ks + quad * 8]);
      acc[nt] = __builtin_amdgcn_mfma_f32_16x16x32_bf16(af, bfr, acc[nt], 0, 0, 0);
    }
  }
#pragma unroll
  for (int r = 0; r < 4; r++) {
    float rv[4];
    float s = 0.f;
#pragma unroll
    for (int nt = 0; nt < 4; nt++) {
      float v = acc[nt][r] + H[(size_t)(m0 + lr + r) * 64 + nt * 16 + l15];
      rv[nt] = v; s += v;
    }
    s += __shfl_xor(s, 1); s += __shfl_xor(s, 2);
    s += __shfl_xor(s, 4); s += __shfl_xor(s, 8);
    float mean = s * (1.f / 64.f);
    float vsum = 0.f;
#pragma unroll
    for (int nt = 0; nt < 4; nt++) { rv[nt] -= mean; vsum += rv[nt] * rv[nt]; }
    vsum += __shfl_xor(vsum, 1); vsum += __shfl_xor(vsum, 2);
    vsum += __shfl_xor(vsum, 4); vsum += __shfl_xor(vsum, 8);
    float inv = rsqrtf(vsum * (1.f / 64.f) + 1e-5f);
#pragma unroll
    for (int nt = 0; nt < 4; nt++) {
      int col = nt * 16 + l15;
      float hv = rv[nt] * inv * ln1g[col] + ln1b[col];
      h1f[lr + r][col] = hv;
      h1b[lr + r][col] = f2bf(hv);
    }
  }
  // ---- ff1 (relu) ----
  f32x4 a2[16];
#pragma unroll
  for (int nt = 0; nt < 16; nt++) {
    float b = bff1[nt * 16 + l15];
    a2[nt] = (f32x4){b, b, b, b};
  }
#pragma unroll
  for (int ks = 0; ks < 64; ks += 32) {
    bf16x8 af = ldfrag(&h1b[wv * 16 + l15][ks + quad * 8]);
#pragma unroll
    for (int nt = 0; nt < 16; nt++) {
      bf16x8 bfr = ldfrag(&W1s[nt * 16 + l15][ks + quad * 8]);
      a2[nt] = __builtin_amdgcn_mfma_f32_16x16x32_bf16(af, bfr, a2[nt], 0, 0, 0);
    }
  }
#pragma unroll
  for (int nt = 0; nt < 16; nt++)
#pragma unroll
    for (int r = 0; r < 4; r++)
      ffa[lr + r][nt * 16 + l15] = f2bf(fmaxf(a2[nt][r], 0.f));
  // ---- ff2 + LN2 ----
#pragma unroll
  for (int nt = 0; nt < 4; nt++) {
    float b = bff2[nt * 16 + l15];
    acc[nt] = (f32x4){b, b, b, b};
  }
#pragma unroll
  for (int ks = 0; ks < 256; ks += 32) {
    bf16x8 af = ldfrag(&ffa[wv * 16 + l15][ks + quad * 8]);
#pragma unroll
    for (int nt = 0; nt < 4; nt++) {
      bf16x8 bfr = ldfrag(&W2s[nt * 16 + l15][ks + quad * 8]);
      acc[nt] = __builtin_amdgcn_mfma_f32_16x16x32_bf16(af, bfr, acc[nt], 0, 0, 0);
    }
  }
#pragma unroll
  for (int r = 0; r < 4; r++) {
    float rv[4];
    float s = 0.f;
#pragma unroll
    for (int nt = 0; nt < 4; nt++) {
      float v = acc[nt][r] + h1f[lr + r][nt * 16 + l15];
      rv[nt] = v; s += v;
    }
    s += __shfl_xor(s, 1); s += __shfl_xor(s, 2);
    s += __shfl_xor(s, 4); s += __shfl_xor(s, 8);
    float mean = s * (1.f / 64.f);
    float vsum = 0.f;
#pragma unroll
    for (int nt = 0; nt < 4; nt++) { rv[nt] -= mean; vsum += rv[nt] * rv[nt]; }
    vsum += __shfl_xor(vsum, 1); vsum += __shfl_xor(vsum, 2);
    vsum += __shfl_xor(vsum, 4); vsum += __shfl_xor(vsum, 8);
    float inv = rsqrtf(vsum * (1.f / 64.f) + 1e-5f);
#pragma unroll
    for (int nt = 0; nt < 4; nt++) {
      int col = nt * 16 + l15;
      H[(size_t)(m0 + lr + r) * 64 + col] = rv[nt] * inv * ln2g[col] + ln2b[col];
    }
  }
}

// MFMA flash attention (unchanged from round 7).
__global__ __launch_bounds__(256) void attn_kernel(
    const float* __restrict__ qkv, const int* __restrict__ lens,
    float* __restrict__ o) {
  __shared__ __align__(16) unsigned short qs[256][24];
  __shared__ __align__(16) unsigned short kst[256][24];
  __shared__ __align__(16) unsigned short vT[16][264];
  __shared__ __align__(16) unsigned short pw[4][16][264];
  int bh = blockIdx.x;
  int b_ = bh >> 2, hd = bh & 3;
  int tid = threadIdx.x;
  int wv = tid >> 6, lane = tid & 63, quad = lane >> 4, l15 = lane & 15;
  int len = lens[b_];
  const float* base = qkv + b_ * 256 * 192 + hd * 16;
  for (int i = tid; i < 1024; i += 256) {
    int s = i >> 2, c = (i & 3) << 2;
    const float* rp = base + s * 192;
    float4 q4 = *(const float4*)(rp + c);
    float4 k4 = *(const float4*)(rp + 64 + c);
    float4 v4 = *(const float4*)(rp + 128 + c);
    short4 qp, kp;
    qp.x = (short)f2bf(q4.x * 0.25f); qp.y = (short)f2bf(q4.y * 0.25f);
    qp.z = (short)f2bf(q4.z * 0.25f); qp.w = (short)f2bf(q4.w * 0.25f);
    kp.x = (short)f2bf(k4.x); kp.y = (short)f2bf(k4.y);
    kp.z = (short)f2bf(k4.z); kp.w = (short)f2bf(k4.w);
    *(short4*)&qs[s][c] = qp;
    *(short4*)&kst[s][c] = kp;
    vT[c + 0][s] = f2bf(v4.x);
    vT[c + 1][s] = f2bf(v4.y);
    vT[c + 2][s] = f2bf(v4.z);
    vT[c + 3][s] = f2bf(v4.w);
  }
  __syncthreads();
  bf16x8 zf = {0, 0, 0, 0, 0, 0, 0, 0};
  f32x4 zero = {0.f, 0.f, 0.f, 0.f};
#pragma unroll 1
  for (int j = 0; j < 4; j++) {
    int qt = wv * 4 + j;
    bf16x8 bq = (quad < 2) ? ldfrag(&qs[qt * 16 + l15][quad * 8]) : zf;
    f32x4 s[16];
#pragma unroll
    for (int t = 0; t < 16; t++) {
      bf16x8 ak = (quad < 2) ? ldfrag(&kst[t * 16 + l15][quad * 8]) : zf;
      s[t] = __builtin_amdgcn_mfma_f32_16x16x32_bf16(ak, bq, zero, 0, 0, 0);
    }
    float mx = -1e30f;
#pragma unroll
    for (int t = 0; t < 16; t++)
#pragma unroll
      for (int r = 0; r < 4; r++) {
        int key = t * 16 + quad * 4 + r;
        float v = (key < len) ? s[t][r] : -1e30f;
        s[t][r] = v;
        mx = fmaxf(mx, v);
      }
    mx = fmaxf(mx, __shfl_xor(mx, 16));
    mx = fmaxf(mx, __shfl_xor(mx, 32));
    float sum = 0.f;
#pragma unroll
    for (int t = 0; t < 16; t++)
#pragma unroll
      for (int r = 0; r < 4; r++) {
        float p = __expf(s[t][r] - mx);
        s[t][r] = p;
        sum += p;
      }
    sum += __shfl_xor(sum, 16);
    sum += __shfl_xor(sum, 32);
#pragma unroll
    for (int t = 0; t < 16; t++) {
      short4 pp;
      pp.x = (short)f2bf(s[t][0]); pp.y = (short)f2bf(s[t][1]);
      pp.z = (short)f2bf(s[t][2]); pp.w = (short)f2bf(s[t][3]);
      *(short4*)&pw[wv][l15][t * 16 + quad * 4] = pp;
    }
    f32x4 acc = zero;
#pragma unroll
    for (int c = 0; c < 8; c++) {
      bf16x8 av = ldfrag(&vT[l15][c * 32 + quad * 8]);
      bf16x8 bp = ldfrag(&pw[wv][l15][c * 32 + quad * 8]);
      acc = __builtin_amdgcn_mfma_f32_16x16x32_bf16(av, bp, acc, 0, 0, 0);
    }
    float inv = 1.f / sum;
    float4 w;
    w.x = acc[0] * inv; w.y = acc[1] * inv;
    w.z = acc[2] * inv; w.w = acc[3] * inv;
    *(float4*)&o[(size_t)(b_ * 256 + qt * 16 + l15) * 64 + hd * 16 + quad * 4] = w;
  }
}

// Masked mean pool using per-b active length.
__global__ __launch_bounds__(256) void pool_kernel(
    const float* __restrict__ h, const int* __restrict__ lens,
    float* __restrict__ pooled) {
  __shared__ float ps[4][64];
  int b = blockIdx.x;
  int e = threadIdx.x & 63, sp = threadIdx.x >> 6;
  int len = lens[b];
  float sum = 0.f;
  int send = min(sp * 64 + 64, len);
  for (int s = sp * 64; s < send; s++) sum += h[(b * 256 + s) * 64 + e];
  ps[sp][e] = sum;
  __syncthreads();
  if (sp == 0) {
    float tot = ps[0][e] + ps[1][e] + ps[2][e] + ps[3][e];
    pooled[b * 64 + e] = tot / ((float)len + 1e-8f);
  }
}

// Fused heads: cls(3), mus(6), sigmas(6), d(1) -> 16 outputs per b.
__global__ __launch_bounds__(64) void heads_kernel(
    const float* __restrict__ pooled,
    const float* __restrict__ cls_w1, const float* __restrict__ cls_b1,
    const float* __restrict__ cls_w2, const float* __restrict__ cls_b2,
    const float* __restrict__ mu_w1, const float* __restrict__ mu_b1,
    const float* __restrict__ mu_w2, const float* __restrict__ mu_b2,
    const float* __restrict__ ls_w1, const float* __restrict__ ls_b1,
    const float* __restrict__ ls_w2, const float* __restrict__ ls_b2,
    const float* __restrict__ d_w1, const float* __restrict__ d_b1,
    const float* __restrict__ d_w2, const float* __restrict__ d_b2,
    float* __restrict__ out) {
  int b = blockIdx.x, e = threadIdx.x;
  __shared__ float p[64];
  __shared__ float t1[64];
  p[e] = pooled[b * 64 + e];
  __syncthreads();
  {
    float a = cls_b1[e];
    for (int j = 0; j < 64; j++) a += p[j] * cls_w1[e * 64 + j];
    t1[e] = fmaxf(a, 0.f);
  }
  __syncthreads();
  if (e < 3) {
    float a2 = cls_b2[e];
    for (int j = 0; j < 64; j++) a2 += t1[j] * cls_w2[e * 64 + j];
    out[b * 16 + e] = a2;
  }
  for (int z = 0; z < 3; z++) {
    __syncthreads();
    {
      float a = mu_b1[z * 64 + e];
      for (int j = 0; j < 64; j++) a += p[j] * mu_w1[(z * 64 + e) * 64 + j];
      t1[e] = fmaxf(a, 0.f);
    }
    __syncthreads();
    if (e < 2) {
      float a2 = mu_b2[z * 2 + e];
      for (int j = 0; j < 64; j++) a2 += t1[j] * mu_w2[(z * 2 + e) * 64 + j];
      out[b * 16 + 3 + z * 2 + e] = a2;
    }
    __syncthreads();
    {
      float a = ls_b1[z * 64 + e];
      for (int j = 0; j < 64; j++) a += p[j] * ls_w1[(z * 64 + e) * 64 + j];
      t1[e] = fmaxf(a, 0.f);
    }
    __syncthreads();
    if (e < 2) {
      float a2 = ls_b2[z * 2 + e];
      for (int j = 0; j < 64; j++) a2 += t1[j] * ls_w2[(z * 2 + e) * 64 + j];
      out[b * 16 + 9 + z * 2 + e] = __expf(a2);
    }
  }
  __syncthreads();
  {
    float a = d_b1[e];
    for (int j = 0; j < 64; j++) a += p[j] * d_w1[e * 64 + j];
    t1[e] = fmaxf(a, 0.f);
  }
  __syncthreads();
  if (e == 0) {
    float a2 = d_b2[0];
    for (int j = 0; j < 64; j++) a2 += t1[j] * d_w2[j];
    out[b * 16 + 15] = 1.f / (1.f + __expf(-a2));
  }
}

extern "C" void kernel_launch(void* const* d_in, const int* in_sizes, int n_in,
                              void* d_out, int out_size, void* d_ws, size_t ws_size,
                              hipStream_t stream) {
  const float* wav       = (const float*)d_in[0];
  const int*   sid       = (const int*)d_in[1];
  const void*  mask      = d_in[2];
  const float* conv1_w   = (const float*)d_in[3];
  const float* conv1_b   = (const float*)d_in[4];
  const float* conv2_w   = (const float*)d_in[5];
  const float* conv2_b   = (const float*)d_in[6];
  const float* shank_emb = (const float*)d_in[7];
  const float* in_proj_w = (const float*)d_in[8];
  const float* in_proj_b = (const float*)d_in[9];
  const float* out_proj_w= (const float*)d_in[10];
  const float* out_proj_b= (const float*)d_in[11];
  const float* ln1_g     = (const float*)d_in[12];
  const float* ln1_b     = (const float*)d_in[13];
  const float* ff1_w     = (const float*)d_in[14];
  const float* ff1_b     = (const float*)d_in[15];
  const float* ff2_w     = (const float*)d_in[16];
  const float* ff2_b     = (const float*)d_in[17];
  const float* ln2_g     = (const float*)d_in[18];
  const float* ln2_b     = (const float*)d_in[19];
  const float* cls_w1    = (const float*)d_in[20];
  const float* cls_b1    = (const float*)d_in[21];
  const float* cls_w2    = (const float*)d_in[22];
  const float* cls_b2    = (const float*)d_in[23];
  const float* mu_w1     = (const float*)d_in[24];
  const float* mu_b1     = (const float*)d_in[25];
  const float* mu_w2     = (const float*)d_in[26];
  const float* mu_b2     = (const float*)d_in[27];
  const float* ls_w1     = (const float*)d_in[28];
  const float* ls_b1     = (const float*)d_in[29];
  const float* ls_w2     = (const float*)d_in[30];
  const float* ls_b2     = (const float*)d_in[31];
  const float* d_w1      = (const float*)d_in[32];
  const float* d_b1      = (const float*)d_in[33];
  const float* d_w2      = (const float*)d_in[34];
  const float* d_b2      = (const float*)d_in[35];
  float* out = (float*)d_out;

  float* ws = (float*)d_ws;
  float* h      = ws;                    // [32768,64]
  float* qkv    = ws + 2097152;          // [32768,192]
  float* obuf   = ws + 8388608;          // [32768,64] attn out
  float* pooled = ws + 10485760;         // [128,64]
  int*   ip     = (int*)(ws + 10493952);
  int*   flag   = ip;
  int*   counts = ip + 8;
  int*   lens   = ip + 16;               // [128]
  int*   idxbuf = ip + 144;              // [8][32768]

  detect_mask_kernel<<<1, 256, 0, stream>>>((const unsigned int*)mask, flag, counts, lens);
  bin_kernel<<<128, 256, 0, stream>>>(sid, mask, flag, counts, lens, idxbuf);
  init_emb_kernel<<<8192, 256, 0, stream>>>(sid, shank_emb, h);
  conv_mfma_kernel<<<1024, 256, 0, stream>>>(idxbuf, counts, wav, conv1_w, conv1_b,
                                             conv2_w, conv2_b, shank_emb, h);
  for (int l = 0; l < 2; l++) {
    gemm_qkv<<<512, 256, 0, stream>>>(h, in_proj_w + l * 12288, in_proj_b + l * 192, qkv);
    attn_kernel<<<512, 256, 0, stream>>>(qkv, lens, obuf);
    fused_rl_kernel<<<512, 256, 0, stream>>>(
        obuf, h, out_proj_w + l * 4096, out_proj_b + l * 64,
        ln1_g + l * 64, ln1_b + l * 64,
        ff1_w + l * 16384, ff1_b + l * 256,
        ff2_w + l * 16384, ff2_b + l * 64,
        ln2_g + l * 64, ln2_b + l * 64);
  }
  pool_kernel<<<128, 256, 0, stream>>>(h, lens, pooled);
  heads_kernel<<<128, 64, 0, stream>>>(pooled, cls_w1, cls_b1, cls_w2, cls_b2,
                                       mu_w1, mu_b1, mu_w2, mu_b2,
                                       ls_w1, ls_b1, ls_w2, ls_b2,
                                       d_w1, d_b1, d_w2, d_b2, out);
}

// Round 10
// 321.926 us; speedup vs baseline: 4.8198x; 1.0586x over previous
//
#include <hip/hip_runtime.h>
#include <math.h>

// B=128, S=256, G=8, CMAX=6, T=32, E=64, NH=4, dh=16, L=2, DFF=256, Z=3

typedef short bf16x8 __attribute__((ext_vector_type(8)));
typedef float f32x4 __attribute__((ext_vector_type(4)));

__device__ __forceinline__ unsigned short f2bf(float f) {
  unsigned u = __float_as_uint(f);
  u += 0x7fffu + ((u >> 16) & 1u);   // RNE
  return (unsigned short)(u >> 16);
}

__device__ __forceinline__ bf16x8 ldfrag(const unsigned short* p) {
  return *reinterpret_cast<const bf16x8*>(p);
}

__device__ __forceinline__ bool is_masked(const void* mask_, int flag, int idx) {
  return flag ? (((const unsigned char*)mask_)[idx] != 0)
              : (((const int*)mask_)[idx] != 0);
}

// Detect mask dtype (int32 vs byte-packed bool); zero counters.
__global__ void detect_mask_kernel(const unsigned int* __restrict__ mw,
                                   int* __restrict__ flag, int* __restrict__ counts,
                                   int* __restrict__ lens) {
  __shared__ int sh;
  if (threadIdx.x == 0) sh = 0;
  __syncthreads();
  int bad = 0;
  for (int i = threadIdx.x; i < 8192; i += 256)
    if (mw[i] > 1u) bad = 1;
  if (bad) atomicOr(&sh, 1);
  if (threadIdx.x < 8) counts[threadIdx.x] = 0;
  if (threadIdx.x < 128) lens[threadIdx.x] = 0;
  __syncthreads();
  if (threadIdx.x == 0) *flag = sh;
}

// Bin active tokens by shank id. Hierarchical atomics (8-way LDS -> 1 global/g).
__global__ __launch_bounds__(256) void bin_kernel(
    const int* __restrict__ sid, const void* __restrict__ mask_,
    const int* __restrict__ flagp, int* __restrict__ counts,
    int* __restrict__ lens, int* __restrict__ idxbuf) {
  __shared__ int lcnt[8];
  __shared__ int lbase[8];
  int b = blockIdx.x, tid = threadIdx.x;
  int n = b * 256 + tid;
  int flag = *flagp;
  bool act = !is_masked(mask_, flag, n);
  int g = act ? sid[n] : 0;
  if (tid < 8) lcnt[tid] = 0;
  __syncthreads();
  int pos = 0;
  if (act) pos = atomicAdd(&lcnt[g], 1);
  __syncthreads();
  if (tid < 8) lbase[tid] = atomicAdd(&counts[tid], lcnt[tid]);
  if (tid == 0)
    lens[b] = lcnt[0] + lcnt[1] + lcnt[2] + lcnt[3] +
              lcnt[4] + lcnt[5] + lcnt[6] + lcnt[7];
  __syncthreads();
  if (act) idxbuf[g * 32768 + lbase[g] + pos] = n;
}

// Base embedding: shank_emb[sid] + positional encoding. Conv kernel later
// OVERWRITES rows of active tokens (full value incl. shank+PE).
__global__ __launch_bounds__(256) void init_emb_kernel(
    const int* __restrict__ sid, const float* __restrict__ shank_emb,
    float* __restrict__ hout) {
  int i = blockIdx.x * 256 + threadIdx.x;
  int n = i >> 6, e = i & 63, s = n & 255;
  int g = sid[n];
  float div = __expf(-(float)(e & ~1) * (9.21034037f / 64.f));
  float angle = (float)s * div;
  float pe = (e & 1) ? cosf(angle) : sinf(angle);
  hout[i] = shank_emb[g * 64 + e] + pe;
}

// Conv encoder via bf16 MFMA — wave-independent, 1024 blocks.
__global__ __launch_bounds__(256) void conv_mfma_kernel(
    const int* __restrict__ idxbuf, const int* __restrict__ counts,
    const float* __restrict__ wav,
    const float* __restrict__ w1_, const float* __restrict__ b1_,
    const float* __restrict__ w2_, const float* __restrict__ b2_,
    const float* __restrict__ shank_emb, float* __restrict__ hout) {
  __shared__ __align__(16) unsigned short w1f[5][32][8];
  __shared__ __align__(16) unsigned short w2f[3][64][40];
  __shared__ float b1s[32];
  __shared__ float b2s[64];
  __shared__ __align__(16) unsigned short xw[4][36][8];
  __shared__ __align__(16) unsigned short h1w[4][34][40];
  int g = blockIdx.x & 7, bib = blockIdx.x >> 3;
  int tid = threadIdx.x;
  int wvx = tid >> 6, lane = tid & 63, quad = lane >> 4, l15 = lane & 15;
  for (int i = tid; i < 1280; i += 256) {
    int k = i >> 8, rest = i & 255, oc = rest >> 3, ic = rest & 7;
    w1f[k][oc][ic] = (ic < 6) ? f2bf(w1_[g * 960 + oc * 30 + ic * 5 + k]) : 0;
  }
  for (int i = tid; i < 7680; i += 256) {
    int k = i / 2560, rest = i % 2560, e = rest / 40, ic = rest % 40;
    w2f[k][e][ic] = (ic < 32) ? f2bf(w2_[g * 6144 + e * 96 + ic * 3 + k]) : 0;
  }
  if (tid < 32) b1s[tid] = b1_[g * 32 + tid];
  if (tid < 64) b2s[tid] = b2_[g * 64 + tid];
  {
    unsigned int* xz = (unsigned int*)&xw[wvx][0][0];
    for (int i = lane; i < 144; i += 64) xz[i] = 0;
    unsigned int* hz0 = (unsigned int*)&h1w[wvx][0][0];
    unsigned int* hz1 = (unsigned int*)&h1w[wvx][33][0];
    if (lane < 20) hz0[lane] = 0;
    else if (lane < 40) hz1[lane - 20] = 0;
  }
  __syncthreads();
  bf16x8 zf = {0, 0, 0, 0, 0, 0, 0, 0};
  bf16x8 bf1[2], bf1k4[2], bf2[3][4];
#pragma unroll
  for (int nt = 0; nt < 2; nt++) {
    bf1[nt] = ldfrag(&w1f[quad][nt * 16 + l15][0]);
    bf1k4[nt] = (quad == 0) ? ldfrag(&w1f[4][nt * 16 + l15][0]) : zf;
  }
#pragma unroll
  for (int k = 0; k < 3; k++)
#pragma unroll
    for (int nt = 0; nt < 4; nt++)
      bf2[k][nt] = ldfrag(&w2f[k][nt * 16 + l15][quad * 8]);
  float b1v0 = b1s[l15], b1v1 = b1s[16 + l15];
  float shank = shank_emb[g * 64 + lane];
  float dive = __expf(-(float)(lane & ~1) * (9.21034037f / 64.f));
  int cnt = counts[g];
  int wvg = bib * 4 + wvx;
  int ic_w = lane >> 3, t0_w = (lane & 7) * 4;
  for (int ti = wvg; ti < cnt; ti += 512) {
    int n = idxbuf[g * 32768 + ti];
    float4 v = make_float4(0.f, 0.f, 0.f, 0.f);
    if (lane < 48) v = *(const float4*)&wav[n * 192 + lane * 4];
    if (lane < 48) {
      xw[wvx][t0_w + 2][ic_w] = f2bf(v.x);
      xw[wvx][t0_w + 3][ic_w] = f2bf(v.y);
      xw[wvx][t0_w + 4][ic_w] = f2bf(v.z);
      xw[wvx][t0_w + 5][ic_w] = f2bf(v.w);
    }
    f32x4 c1[2][2];
#pragma unroll
    for (int mt = 0; mt < 2; mt++) {
      c1[mt][0] = (f32x4){b1v0, b1v0, b1v0, b1v0};
      c1[mt][1] = (f32x4){b1v1, b1v1, b1v1, b1v1};
    }
#pragma unroll
    for (int mt = 0; mt < 2; mt++) {
      bf16x8 afm = ldfrag(&xw[wvx][mt * 16 + l15 + quad][0]);
      bf16x8 af4 = (quad == 0) ? ldfrag(&xw[wvx][mt * 16 + l15 + 4][0]) : zf;
#pragma unroll
      for (int nt = 0; nt < 2; nt++) {
        c1[mt][nt] = __builtin_amdgcn_mfma_f32_16x16x32_bf16(afm, bf1[nt], c1[mt][nt], 0, 0, 0);
        c1[mt][nt] = __builtin_amdgcn_mfma_f32_16x16x32_bf16(af4, bf1k4[nt], c1[mt][nt], 0, 0, 0);
      }
    }
#pragma unroll
    for (int mt = 0; mt < 2; mt++)
#pragma unroll
      for (int nt = 0; nt < 2; nt++)
#pragma unroll
        for (int r = 0; r < 4; r++) {
          int t = mt * 16 + quad * 4 + r;
          h1w[wvx][t + 1][nt * 16 + l15] = f2bf(fmaxf(c1[mt][nt][r], 0.f));
        }
    f32x4 c2[2][4];
#pragma unroll
    for (int mt = 0; mt < 2; mt++)
#pragma unroll
      for (int nt = 0; nt < 4; nt++) {
        float bv = b2s[nt * 16 + l15];
        c2[mt][nt] = (f32x4){bv, bv, bv, bv};
      }
#pragma unroll
    for (int k = 0; k < 3; k++)
#pragma unroll
      for (int mt = 0; mt < 2; mt++) {
        bf16x8 af = ldfrag(&h1w[wvx][mt * 16 + l15 + k][quad * 8]);
#pragma unroll
        for (int nt = 0; nt < 4; nt++)
          c2[mt][nt] = __builtin_amdgcn_mfma_f32_16x16x32_bf16(af, bf2[k][nt], c2[mt][nt], 0, 0, 0);
      }
    float sums[4];
#pragma unroll
    for (int nt = 0; nt < 4; nt++) {
      float s = 0.f;
#pragma unroll
      for (int mt = 0; mt < 2; mt++)
#pragma unroll
        for (int r = 0; r < 4; r++) s += fmaxf(c2[mt][nt][r], 0.f);
      s += __shfl_xor(s, 16);
      s += __shfl_xor(s, 32);
      sums[nt] = s;
    }
    float t0 = __shfl(sums[0], l15);
    float t1 = __shfl(sums[1], l15);
    float t2 = __shfl(sums[2], l15);
    float t3 = __shfl(sums[3], l15);
    float val = (quad == 0) ? t0 : (quad == 1) ? t1 : (quad == 2) ? t2 : t3;
    float angle = (float)(n & 255) * dive;
    float pe = (lane & 1) ? cosf(angle) : sinf(angle);
    hout[(size_t)n * 64 + lane] = val * (1.f / 32.f) + shank + pe;
  }
}

// Fused qkv-projection + flash attention. Block = (b, head).
// Stage h[b] -> bf16 LDS; compute this head's Q (pre-scaled), K, V^T via MFMA;
// then round-7 flash attention. pw buffer aliases the dead hs region.
__global__ __launch_bounds__(256) void attn_fused_kernel(
    const float* __restrict__ H, const float* __restrict__ Wqkv,
    const float* __restrict__ bqkv, const int* __restrict__ lens,
    float* __restrict__ o) {
  __shared__ __align__(16) unsigned short un[18432];     // hs[256][72] / pw[4][16][264]
  __shared__ __align__(16) unsigned short wqs[16][72];
  __shared__ __align__(16) unsigned short wks[16][72];
  __shared__ __align__(16) unsigned short wvs[16][72];
  __shared__ __align__(16) unsigned short qs[256][24];
  __shared__ __align__(16) unsigned short kst[256][24];
  __shared__ __align__(16) unsigned short vT[16][264];
  __shared__ float bqs[16], bks[16], bvs[16];
  unsigned short (*hs)[72] = (unsigned short(*)[72])un;
  unsigned short (*pw)[16][264] = (unsigned short(*)[16][264])un;
  int bh = blockIdx.x;
  int b_ = bh >> 2, hd = bh & 3;
  int tid = threadIdx.x;
  int wvx = tid >> 6, lane = tid & 63, quad = lane >> 4, l15 = lane & 15;
  int len = lens[b_];
  const float* hb = H + (size_t)b_ * 256 * 64;
  for (int i = tid; i < 4096; i += 256) {
    int r = i >> 4, c4 = (i & 15) << 2;
    float4 v = *(const float4*)&hb[r * 64 + c4];
    short4 t;
    t.x = (short)f2bf(v.x); t.y = (short)f2bf(v.y);
    t.z = (short)f2bf(v.z); t.w = (short)f2bf(v.w);
    *(short4*)&hs[r][c4] = t;
  }
  for (int i = tid; i < 768; i += 256) {
    int r = i >> 4, c4 = (i & 15) << 2;
    int which = r >> 4, rr = r & 15;
    float4 v = *(const float4*)&Wqkv[(size_t)(which * 64 + hd * 16 + rr) * 64 + c4];
    float sc = (which == 0) ? 0.25f : 1.f;
    short4 t;
    t.x = (short)f2bf(v.x * sc); t.y = (short)f2bf(v.y * sc);
    t.z = (short)f2bf(v.z * sc); t.w = (short)f2bf(v.w * sc);
    unsigned short (*dst)[72] = (which == 0) ? wqs : (which == 1) ? wks : wvs;
    *(short4*)&dst[rr][c4] = t;
  }
  if (tid < 16) {
    bqs[tid] = 0.25f * bqkv[hd * 16 + tid];
    bks[tid] = bqkv[64 + hd * 16 + tid];
    bvs[tid] = bqkv[128 + hd * 16 + tid];
  }
  __syncthreads();
  // Q/K: D[query][d]; V^T: D[d][key]. 4 tiles per wave.
#pragma unroll
  for (int t4 = 0; t4 < 4; t4++) {
    int tile = wvx * 4 + t4;
    float bq = bqs[l15], bk = bks[l15];
    f32x4 aq = (f32x4){bq, bq, bq, bq};
    f32x4 ak = (f32x4){bk, bk, bk, bk};
    f32x4 av = (f32x4){bvs[quad * 4 + 0], bvs[quad * 4 + 1],
                       bvs[quad * 4 + 2], bvs[quad * 4 + 3]};
#pragma unroll
    for (int ks = 0; ks < 64; ks += 32) {
      bf16x8 af = ldfrag(&hs[tile * 16 + l15][ks + quad * 8]);
      aq = __builtin_amdgcn_mfma_f32_16x16x32_bf16(af, ldfrag(&wqs[l15][ks + quad * 8]), aq, 0, 0, 0);
      ak = __builtin_amdgcn_mfma_f32_16x16x32_bf16(af, ldfrag(&wks[l15][ks + quad * 8]), ak, 0, 0, 0);
      av = __builtin_amdgcn_mfma_f32_16x16x32_bf16(ldfrag(&wvs[l15][ks + quad * 8]), af, av, 0, 0, 0);
    }
#pragma unroll
    for (int r = 0; r < 4; r++) {
      qs[tile * 16 + quad * 4 + r][l15] = f2bf(aq[r]);
      kst[tile * 16 + quad * 4 + r][l15] = f2bf(ak[r]);
      vT[quad * 4 + r][tile * 16 + l15] = f2bf(av[r]);
    }
  }
  __syncthreads();   // qkv visible; hs dead -> pw may reuse region
  bf16x8 zf = {0, 0, 0, 0, 0, 0, 0, 0};
  f32x4 zero = {0.f, 0.f, 0.f, 0.f};
#pragma unroll 1
  for (int j = 0; j < 4; j++) {
    int qt = wvx * 4 + j;
    bf16x8 bq = (quad < 2) ? ldfrag(&qs[qt * 16 + l15][quad * 8]) : zf;
    f32x4 s[16];
#pragma unroll
    for (int t = 0; t < 16; t++) {
      bf16x8 ak = (quad < 2) ? ldfrag(&kst[t * 16 + l15][quad * 8]) : zf;
      s[t] = __builtin_amdgcn_mfma_f32_16x16x32_bf16(ak, bq, zero, 0, 0, 0);
    }
    float mx = -1e30f;
#pragma unroll
    for (int t = 0; t < 16; t++)
#pragma unroll
      for (int r = 0; r < 4; r++) {
        int key = t * 16 + quad * 4 + r;
        float v = (key < len) ? s[t][r] : -1e30f;
        s[t][r] = v;
        mx = fmaxf(mx, v);
      }
    mx = fmaxf(mx, __shfl_xor(mx, 16));
    mx = fmaxf(mx, __shfl_xor(mx, 32));
    float sum = 0.f;
#pragma unroll
    for (int t = 0; t < 16; t++)
#pragma unroll
      for (int r = 0; r < 4; r++) {
        float p = __expf(s[t][r] - mx);
        s[t][r] = p;
        sum += p;
      }
    sum += __shfl_xor(sum, 16);
    sum += __shfl_xor(sum, 32);
#pragma unroll
    for (int t = 0; t < 16; t++) {
      short4 pp;
      pp.x = (short)f2bf(s[t][0]); pp.y = (short)f2bf(s[t][1]);
      pp.z = (short)f2bf(s[t][2]); pp.w = (short)f2bf(s[t][3]);
      *(short4*)&pw[wvx][l15][t * 16 + quad * 4] = pp;
    }
    f32x4 acc = zero;
#pragma unroll
    for (int c = 0; c < 8; c++) {
      bf16x8 avv = ldfrag(&vT[l15][c * 32 + quad * 8]);
      bf16x8 bp = ldfrag(&pw[wvx][l15][c * 32 + quad * 8]);
      acc = __builtin_amdgcn_mfma_f32_16x16x32_bf16(avv, bp, acc, 0, 0, 0);
    }
    float inv = 1.f / sum;
    float4 w;
    w.x = acc[0] * inv; w.y = acc[1] * inv;
    w.z = acc[2] * inv; w.w = acc[3] * inv;
    *(float4*)&o[(size_t)(b_ * 256 + qt * 16 + l15) * 64 + hd * 16 + quad * 4] = w;
  }
}

// Fused row-local: H = LN2( LN1(H + obuf@Wout^T + bo) + relu(...)@Wff2^T ... ).
__global__ __launch_bounds__(256) void fused_rl_kernel(
    const float* __restrict__ obuf, float* __restrict__ H,
    const float* __restrict__ Wout, const float* __restrict__ bout,
    const float* __restrict__ ln1g, const float* __restrict__ ln1b,
    const float* __restrict__ Wff1, const float* __restrict__ bff1,
    const float* __restrict__ Wff2, const float* __restrict__ bff2,
    const float* __restrict__ ln2g, const float* __restrict__ ln2b) {
  __shared__ __align__(16) unsigned short Ao[64][72];
  __shared__ __align__(16) unsigned short Wo[64][72];
  __shared__ __align__(16) unsigned short W1s[256][72];
  __shared__ __align__(16) unsigned short W2s[64][264];
  __shared__ __align__(16) unsigned short h1b[64][72];
  __shared__ __align__(16) unsigned short ffa[64][264];
  __shared__ float h1f[64][68];
  int m0 = blockIdx.x * 64;
  int tid = threadIdx.x;
  int wvx = tid >> 6, lane = tid & 63, quad = lane >> 4, l15 = lane & 15;
  for (int i = tid; i < 1024; i += 256) {
    int r = i >> 4, c4 = (i & 15) << 2;
    float4 av = *(const float4*)&obuf[(size_t)(m0 + r) * 64 + c4];
    short4 t;
    t.x = (short)f2bf(av.x); t.y = (short)f2bf(av.y);
    t.z = (short)f2bf(av.z); t.w = (short)f2bf(av.w);
    *(short4*)&Ao[r][c4] = t;
    float4 wv4 = *(const float4*)&Wout[(size_t)r * 64 + c4];
    short4 u;
    u.x = (short)f2bf(wv4.x); u.y = (short)f2bf(wv4.y);
    u.z = (short)f2bf(wv4.z); u.w = (short)f2bf(wv4.w);
    *(short4*)&Wo[r][c4] = u;
  }
  for (int i = tid; i < 4096; i += 256) {
    int r = i >> 4, c4 = (i & 15) << 2;
    float4 wv4 = *(const float4*)&Wff1[(size_t)r * 64 + c4];
    short4 u;
    u.x = (short)f2bf(wv4.x); u.y = (short)f2bf(wv4.y);
    u.z = (short)f2bf(wv4.z); u.w = (short)f2bf(wv4.w);
    *(short4*)&W1s[r][c4] = u;
  }
  for (int i = tid; i < 4096; i += 256) {
    int r = i >> 6, c4 = (i & 63) << 2;
    float4 wv4 = *(const float4*)&Wff2[(size_t)r * 256 + c4];
    short4 u;
    u.x = (short)f2bf(wv4.x); u.y = (short)f2bf(wv4.y);
    u.z = (short)f2bf(wv4.z); u.w = (short)f2bf(wv4.w);
    *(short4*)&W2s[r][c4] = u;
  }
  __syncthreads();
  int lr = wvx * 16 + quad * 4;
  f32x4 acc[4];
#pragma unroll
  for (int nt = 0; nt < 4; nt++) {
    float b = bout[nt * 16 + l15];
    acc[nt] = (f32x4){b, b, b, b};
  }
#pragma unroll
  for (int ks = 0; ks < 64; ks += 32) {
    bf16x8 af = ldfrag(&Ao[wvx * 16 + l15][ks + quad * 8]);
#pragma unroll
    for (int nt = 0; nt < 4; nt++) {
      bf16x8 bfr = ldfrag(&Wo[nt * 16 + l15][ks + quad * 8]);
      acc[nt] = __builtin_amdgcn_mfma_f32_16x16x32_bf16(af, bfr, acc[nt], 0, 0, 0);
    }
  }
#pragma unroll
  for (int r = 0; r < 4; r++) {
    float rv[4];
    float s = 0.f;
#pragma unroll
    for (int nt = 0; nt < 4; nt++) {
      float v = acc[nt][r] + H[(size_t)(m0 + lr + r) * 64 + nt * 16 + l15];
      rv[nt] = v; s += v;
    }
    s += __shfl_xor(s, 1); s += __shfl_xor(s, 2);
    s += __shfl_xor(s, 4); s += __shfl_xor(s, 8);
    float mean = s * (1.f / 64.f);
    float vsum = 0.f;
#pragma unroll
    for (int nt = 0; nt < 4; nt++) { rv[nt] -= mean; vsum += rv[nt] * rv[nt]; }
    vsum += __shfl_xor(vsum, 1); vsum += __shfl_xor(vsum, 2);
    vsum += __shfl_xor(vsum, 4); vsum += __shfl_xor(vsum, 8);
    float inv = rsqrtf(vsum * (1.f / 64.f) + 1e-5f);
#pragma unroll
    for (int nt = 0; nt < 4; nt++) {
      int col = nt * 16 + l15;
      float hv = rv[nt] * inv * ln1g[col] + ln1b[col];
      h1f[lr + r][col] = hv;
      h1b[lr + r][col] = f2bf(hv);
    }
  }
  f32x4 a2[16];
#pragma unroll
  for (int nt = 0; nt < 16; nt++) {
    float b = bff1[nt * 16 + l15];
    a2[nt] = (f32x4){b, b, b, b};
  }
#pragma unroll
  for (int ks = 0; ks < 64; ks += 32) {
    bf16x8 af = ldfrag(&h1b[wvx * 16 + l15][ks + quad * 8]);
#pragma unroll
    for (int nt = 0; nt < 16; nt++) {
      bf16x8 bfr = ldfrag(&W1s[nt * 16 + l15][ks + quad * 8]);
      a2[nt] = __builtin_amdgcn_mfma_f32_16x16x32_bf16(af, bfr, a2[nt], 0, 0, 0);
    }
  }
#pragma unroll
  for (int nt = 0; nt < 16; nt++)
#pragma unroll
    for (int r = 0; r < 4; r++)
      ffa[lr + r][nt * 16 + l15] = f2bf(fmaxf(a2[nt][r], 0.f));
#pragma unroll
  for (int nt = 0; nt < 4; nt++) {
    float b = bff2[nt * 16 + l15];
    acc[nt] = (f32x4){b, b, b, b};
  }
#pragma unroll
  for (int ks = 0; ks < 256; ks += 32) {
    bf16x8 af = ldfrag(&ffa[wvx * 16 + l15][ks + quad * 8]);
#pragma unroll
    for (int nt = 0; nt < 4; nt++) {
      bf16x8 bfr = ldfrag(&W2s[nt * 16 + l15][ks + quad * 8]);
      acc[nt] = __builtin_amdgcn_mfma_f32_16x16x32_bf16(af, bfr, acc[nt], 0, 0, 0);
    }
  }
#pragma unroll
  for (int r = 0; r < 4; r++) {
    float rv[4];
    float s = 0.f;
#pragma unroll
    for (int nt = 0; nt < 4; nt++) {
      float v = acc[nt][r] + h1f[lr + r][nt * 16 + l15];
      rv[nt] = v; s += v;
    }
    s += __shfl_xor(s, 1); s += __shfl_xor(s, 2);
    s += __shfl_xor(s, 4); s += __shfl_xor(s, 8);
    float mean = s * (1.f / 64.f);
    float vsum = 0.f;
#pragma unroll
    for (int nt = 0; nt < 4; nt++) { rv[nt] -= mean; vsum += rv[nt] * rv[nt]; }
    vsum += __shfl_xor(vsum, 1); vsum += __shfl_xor(vsum, 2);
    vsum += __shfl_xor(vsum, 4); vsum += __shfl_xor(vsum, 8);
    float inv = rsqrtf(vsum * (1.f / 64.f) + 1e-5f);
#pragma unroll
    for (int nt = 0; nt < 4; nt++) {
      int col = nt * 16 + l15;
      H[(size_t)(m0 + lr + r) * 64 + col] = rv[nt] * inv * ln2g[col] + ln2b[col];
    }
  }
}

// Fused masked mean pool + all heads. Block = batch row b, 256 threads.
__global__ __launch_bounds__(256) void pool_heads_kernel(
    const float* __restrict__ h, const int* __restrict__ lens,
    const float* __restrict__ cls_w1, const float* __restrict__ cls_b1,
    const float* __restrict__ cls_w2, const float* __restrict__ cls_b2,
    const float* __restrict__ mu_w1, const float* __restrict__ mu_b1,
    const float* __restrict__ mu_w2, const float* __restrict__ mu_b2,
    const float* __restrict__ ls_w1, const float* __restrict__ ls_b1,
    const float* __restrict__ ls_w2, const float* __restrict__ ls_b2,
    const float* __restrict__ d_w1, const float* __restrict__ d_b1,
    const float* __restrict__ d_w2, const float* __restrict__ d_b2,
    float* __restrict__ out) {
  __shared__ float ps[4][64];
  __shared__ float p[64];
  __shared__ float t1[64];
  int b = blockIdx.x, tid = threadIdx.x;
  int e = tid & 63, sp = tid >> 6;
  int len = lens[b];
  {
    float sum = 0.f;
    int send = min(sp * 64 + 64, len);
    for (int s = sp * 64; s < send; s++) sum += h[(size_t)(b * 256 + s) * 64 + e];
    ps[sp][e] = sum;
  }
  __syncthreads();
  if (sp == 0)
    p[e] = (ps[0][e] + ps[1][e] + ps[2][e] + ps[3][e]) / ((float)len + 1e-8f);
  __syncthreads();
  if (tid < 64) {
    float a = cls_b1[tid];
    for (int j = 0; j < 64; j++) a += p[j] * cls_w1[tid * 64 + j];
    t1[tid] = fmaxf(a, 0.f);
  }
  __syncthreads();
  if (tid < 3) {
    float a2 = cls_b2[tid];
    for (int j = 0; j < 64; j++) a2 += t1[j] * cls_w2[tid * 64 + j];
    out[b * 16 + tid] = a2;
  }
  for (int z = 0; z < 3; z++) {
    __syncthreads();
    if (tid < 64) {
      float a = mu_b1[z * 64 + tid];
      for (int j = 0; j < 64; j++) a += p[j] * mu_w1[(z * 64 + tid) * 64 + j];
      t1[tid] = fmaxf(a, 0.f);
    }
    __syncthreads();
    if (tid < 2) {
      float a2 = mu_b2[z * 2 + tid];
      for (int j = 0; j < 64; j++) a2 += t1[j] * mu_w2[(z * 2 + tid) * 64 + j];
      out[b * 16 + 3 + z * 2 + tid] = a2;
    }
    __syncthreads();
    if (tid < 64) {
      float a = ls_b1[z * 64 + tid];
      for (int j = 0; j < 64; j++) a += p[j] * ls_w1[(z * 64 + tid) * 64 + j];
      t1[tid] = fmaxf(a, 0.f);
    }
    __syncthreads();
    if (tid < 2) {
      float a2 = ls_b2[z * 2 + tid];
      for (int j = 0; j < 64; j++) a2 += t1[j] * ls_w2[(z * 2 + tid) * 64 + j];
      out[b * 16 + 9 + z * 2 + tid] = __expf(a2);
    }
  }
  __syncthreads();
  if (tid < 64) {
    float a = d_b1[tid];
    for (int j = 0; j < 64; j++) a += p[j] * d_w1[tid * 64 + j];
    t1[tid] = fmaxf(a, 0.f);
  }
  __syncthreads();
  if (tid == 0) {
    float a2 = d_b2[0];
    for (int j = 0; j < 64; j++) a2 += t1[j] * d_w2[j];
    out[b * 16 + 15] = 1.f / (1.f + __expf(-a2));
  }
}

extern "C" void kernel_launch(void* const* d_in, const int* in_sizes, int n_in,
                              void* d_out, int out_size, void* d_ws, size_t ws_size,
                              hipStream_t stream) {
  const float* wav       = (const float*)d_in[0];
  const int*   sid       = (const int*)d_in[1];
  const void*  mask      = d_in[2];
  const float* conv1_w   = (const float*)d_in[3];
  const float* conv1_b   = (const float*)d_in[4];
  const float* conv2_w   = (const float*)d_in[5];
  const float* conv2_b   = (const float*)d_in[6];
  const float* shank_emb = (const float*)d_in[7];
  const float* in_proj_w = (const float*)d_in[8];
  const float* in_proj_b = (const float*)d_in[9];
  const float* out_proj_w= (const float*)d_in[10];
  const float* out_proj_b= (const float*)d_in[11];
  const float* ln1_g     = (const float*)d_in[12];
  const float* ln1_b     = (const float*)d_in[13];
  const float* ff1_w     = (const float*)d_in[14];
  const float* ff1_b     = (const float*)d_in[15];
  const float* ff2_w     = (const float*)d_in[16];
  const float* ff2_b     = (const float*)d_in[17];
  const float* ln2_g     = (const float*)d_in[18];
  const float* ln2_b     = (const float*)d_in[19];
  const float* cls_w1    = (const float*)d_in[20];
  const float* cls_b1    = (const float*)d_in[21];
  const float* cls_w2    = (const float*)d_in[22];
  const float* cls_b2    = (const float*)d_in[23];
  const float* mu_w1     = (const float*)d_in[24];
  const float* mu_b1     = (const float*)d_in[25];
  const float* mu_w2     = (const float*)d_in[26];
  const float* mu_b2     = (const float*)d_in[27];
  const float* ls_w1     = (const float*)d_in[28];
  const float* ls_b1     = (const float*)d_in[29];
  const float* ls_w2     = (const float*)d_in[30];
  const float* ls_b2     = (const float*)d_in[31];
  const float* d_w1      = (const float*)d_in[32];
  const float* d_b1      = (const float*)d_in[33];
  const float* d_w2      = (const float*)d_in[34];
  const float* d_b2      = (const float*)d_in[35];
  float* out = (float*)d_out;

  float* ws = (float*)d_ws;
  float* h      = ws;                    // [32768,64]
  float* obuf   = ws + 2097152;          // [32768,64] attn out
  int*   ip     = (int*)(ws + 10493952);
  int*   flag   = ip;
  int*   counts = ip + 8;
  int*   lens   = ip + 16;               // [128]
  int*   idxbuf = ip + 144;              // [8][32768]

  detect_mask_kernel<<<1, 256, 0, stream>>>((const unsigned int*)mask, flag, counts, lens);
  bin_kernel<<<128, 256, 0, stream>>>(sid, mask, flag, counts, lens, idxbuf);
  init_emb_kernel<<<8192, 256, 0, stream>>>(sid, shank_emb, h);
  conv_mfma_kernel<<<1024, 256, 0, stream>>>(idxbuf, counts, wav, conv1_w, conv1_b,
                                             conv2_w, conv2_b, shank_emb, h);
  for (int l = 0; l < 2; l++) {
    attn_fused_kernel<<<512, 256, 0, stream>>>(h, in_proj_w + l * 12288,
                                               in_proj_b + l * 192, lens, obuf);
    fused_rl_kernel<<<512, 256, 0, stream>>>(
        obuf, h, out_proj_w + l * 4096, out_proj_b + l * 64,
        ln1_g + l * 64, ln1_b + l * 64,
        ff1_w + l * 16384, ff1_b + l * 256,
        ff2_w + l * 16384, ff2_b + l * 64,
        ln2_g + l * 64, ln2_b + l * 64);
  }
  pool_heads_kernel<<<128, 256, 0, stream>>>(h, lens, cls_w1, cls_b1, cls_w2, cls_b2,
                                             mu_w1, mu_b1, mu_w2, mu_b2,
                                             ls_w1, ls_b1, ls_w2, ls_b2,
                                             d_w1, d_b1, d_w2, d_b2, out);
}

// Round 11
// 307.982 us; speedup vs baseline: 5.0380x; 1.0453x over previous
//
#include <hip/hip_runtime.h>
#include <math.h>

// B=128, S=256, G=8, CMAX=6, T=32, E=64, NH=4, dh=16, L=2, DFF=256, Z=3

typedef short bf16x8 __attribute__((ext_vector_type(8)));
typedef float f32x4 __attribute__((ext_vector_type(4)));

__device__ __forceinline__ unsigned short f2bf(float f) {
  unsigned u = __float_as_uint(f);
  u += 0x7fffu + ((u >> 16) & 1u);   // RNE
  return (unsigned short)(u >> 16);
}

__device__ __forceinline__ bf16x8 ldfrag(const unsigned short* p) {
  return *reinterpret_cast<const bf16x8*>(p);
}

__device__ __forceinline__ bool is_masked(const void* mask_, int flag, int idx) {
  return flag ? (((const unsigned char*)mask_)[idx] != 0)
              : (((const int*)mask_)[idx] != 0);
}

// Weight prep (one launch): all transformer weights -> bf16 (Wq pre-scaled
// 0.25), conv weights pre-packed into the MFMA-friendly tap-major layouts.
// wb layout (shorts): [0,24576) qkv  [24576,32768) wout  [32768,65536) ff1
// [65536,98304) ff2  [98304,108544) w1p[g][5][32][8]  [108544,169984) w2p[g][3][64][40]
__global__ __launch_bounds__(256) void prep_weights_kernel(
    const float* __restrict__ in_proj_w, const float* __restrict__ out_proj_w,
    const float* __restrict__ ff1_w, const float* __restrict__ ff2_w,
    const float* __restrict__ w1_, const float* __restrict__ w2_,
    unsigned short* __restrict__ wb) {
  int i = blockIdx.x * 256 + threadIdx.x;
  if (i < 24576) {
    int rem = i % 12288, row = rem / 64;
    float v = in_proj_w[i];
    if (row < 64) v *= 0.25f;
    wb[i] = f2bf(v);
  } else if (i < 32768) {
    wb[i] = f2bf(out_proj_w[i - 24576]);
  } else if (i < 65536) {
    wb[i] = f2bf(ff1_w[i - 32768]);
  } else if (i < 98304) {
    wb[i] = f2bf(ff2_w[i - 65536]);
  } else if (i < 108544) {
    int j = i - 98304;
    int g = j / 1280, rem = j % 1280;
    int k = rem >> 8, rest = rem & 255, oc = rest >> 3, ic = rest & 7;
    wb[i] = (ic < 6) ? f2bf(w1_[g * 960 + oc * 30 + ic * 5 + k]) : 0;
  } else if (i < 169984) {
    int j = i - 108544;
    int g = j / 7680, rem = j % 7680;
    int k = rem / 2560, rest = rem % 2560, e = rest / 40, ic = rest % 40;
    wb[i] = (ic < 32) ? f2bf(w2_[g * 6144 + e * 96 + ic * 3 + k]) : 0;
  }
}

// Detect mask dtype (int32 vs byte-packed bool); zero counters.
__global__ void detect_mask_kernel(const unsigned int* __restrict__ mw,
                                   int* __restrict__ flag, int* __restrict__ counts,
                                   int* __restrict__ lens) {
  __shared__ int sh;
  if (threadIdx.x == 0) sh = 0;
  __syncthreads();
  int bad = 0;
  for (int i = threadIdx.x; i < 8192; i += 256)
    if (mw[i] > 1u) bad = 1;
  if (bad) atomicOr(&sh, 1);
  if (threadIdx.x < 8) counts[threadIdx.x] = 0;
  if (threadIdx.x < 128) lens[threadIdx.x] = 0;
  __syncthreads();
  if (threadIdx.x == 0) *flag = sh;
}

// Bin active tokens by shank id. Hierarchical atomics (8-way LDS -> 1 global/g).
__global__ __launch_bounds__(256) void bin_kernel(
    const int* __restrict__ sid, const void* __restrict__ mask_,
    const int* __restrict__ flagp, int* __restrict__ counts,
    int* __restrict__ lens, int* __restrict__ idxbuf) {
  __shared__ int lcnt[8];
  __shared__ int lbase[8];
  int b = blockIdx.x, tid = threadIdx.x;
  int n = b * 256 + tid;
  int flag = *flagp;
  bool act = !is_masked(mask_, flag, n);
  int g = act ? sid[n] : 0;
  if (tid < 8) lcnt[tid] = 0;
  __syncthreads();
  int pos = 0;
  if (act) pos = atomicAdd(&lcnt[g], 1);
  __syncthreads();
  if (tid < 8) lbase[tid] = atomicAdd(&counts[tid], lcnt[tid]);
  if (tid == 0)
    lens[b] = lcnt[0] + lcnt[1] + lcnt[2] + lcnt[3] +
              lcnt[4] + lcnt[5] + lcnt[6] + lcnt[7];
  __syncthreads();
  if (act) idxbuf[g * 32768 + lbase[g] + pos] = n;
}

// Base embedding (fp32 + bf16 mirror). Conv overwrites active rows.
__global__ __launch_bounds__(256) void init_emb_kernel(
    const int* __restrict__ sid, const float* __restrict__ shank_emb,
    float* __restrict__ hout, unsigned short* __restrict__ hb) {
  int i = blockIdx.x * 256 + threadIdx.x;
  int n = i >> 6, e = i & 63, s = n & 255;
  int g = sid[n];
  float div = __expf(-(float)(e & ~1) * (9.21034037f / 64.f));
  float angle = (float)s * div;
  float pe = (e & 1) ? cosf(angle) : sinf(angle);
  float v = shank_emb[g * 64 + e] + pe;
  hout[i] = v;
  hb[i] = f2bf(v);
}

// Conv encoder via bf16 MFMA — wave-independent; weights pre-packed (uint4
// LDS copies, no f2bf); 1280 blocks (5/CU).
__global__ __launch_bounds__(256) void conv_mfma_kernel(
    const int* __restrict__ idxbuf, const int* __restrict__ counts,
    const float* __restrict__ wav, const unsigned short* __restrict__ wb,
    const float* __restrict__ b1_, const float* __restrict__ b2_,
    const float* __restrict__ shank_emb, float* __restrict__ hout,
    unsigned short* __restrict__ hb) {
  __shared__ __align__(16) unsigned short w1f[5][32][8];
  __shared__ __align__(16) unsigned short w2f[3][64][40];
  __shared__ float b1s[32];
  __shared__ float b2s[64];
  __shared__ __align__(16) unsigned short xw[4][36][8];
  __shared__ __align__(16) unsigned short h1w[4][34][40];
  int g = blockIdx.x & 7, bib = blockIdx.x >> 3;
  int tid = threadIdx.x;
  int wvx = tid >> 6, lane = tid & 63, quad = lane >> 4, l15 = lane & 15;
  {
    const uint4* s1 = (const uint4*)(wb + 98304 + g * 1280);
    uint4* d1 = (uint4*)&w1f[0][0][0];
    for (int i = tid; i < 160; i += 256) d1[i] = s1[i];
    const uint4* s2 = (const uint4*)(wb + 108544 + g * 7680);
    uint4* d2 = (uint4*)&w2f[0][0][0];
    for (int i = tid; i < 960; i += 256) d2[i] = s2[i];
  }
  if (tid < 32) b1s[tid] = b1_[g * 32 + tid];
  if (tid < 64) b2s[tid] = b2_[g * 64 + tid];
  {
    unsigned int* xz = (unsigned int*)&xw[wvx][0][0];
    for (int i = lane; i < 144; i += 64) xz[i] = 0;
    unsigned int* hz0 = (unsigned int*)&h1w[wvx][0][0];
    unsigned int* hz1 = (unsigned int*)&h1w[wvx][33][0];
    if (lane < 20) hz0[lane] = 0;
    else if (lane < 40) hz1[lane - 20] = 0;
  }
  __syncthreads();
  bf16x8 zf = {0, 0, 0, 0, 0, 0, 0, 0};
  bf16x8 bf1[2], bf1k4[2], bf2[3][4];
#pragma unroll
  for (int nt = 0; nt < 2; nt++) {
    bf1[nt] = ldfrag(&w1f[quad][nt * 16 + l15][0]);
    bf1k4[nt] = (quad == 0) ? ldfrag(&w1f[4][nt * 16 + l15][0]) : zf;
  }
#pragma unroll
  for (int k = 0; k < 3; k++)
#pragma unroll
    for (int nt = 0; nt < 4; nt++)
      bf2[k][nt] = ldfrag(&w2f[k][nt * 16 + l15][quad * 8]);
  float b1v0 = b1s[l15], b1v1 = b1s[16 + l15];
  float shank = shank_emb[g * 64 + lane];
  float dive = __expf(-(float)(lane & ~1) * (9.21034037f / 64.f));
  int cnt = counts[g];
  int wvg = bib * 4 + wvx;
  int ic_w = lane >> 3, t0_w = (lane & 7) * 4;
  for (int ti = wvg; ti < cnt; ti += 640) {
    int n = idxbuf[g * 32768 + ti];
    float4 v = make_float4(0.f, 0.f, 0.f, 0.f);
    if (lane < 48) v = *(const float4*)&wav[n * 192 + lane * 4];
    if (lane < 48) {
      xw[wvx][t0_w + 2][ic_w] = f2bf(v.x);
      xw[wvx][t0_w + 3][ic_w] = f2bf(v.y);
      xw[wvx][t0_w + 4][ic_w] = f2bf(v.z);
      xw[wvx][t0_w + 5][ic_w] = f2bf(v.w);
    }
    f32x4 c1[2][2];
#pragma unroll
    for (int mt = 0; mt < 2; mt++) {
      c1[mt][0] = (f32x4){b1v0, b1v0, b1v0, b1v0};
      c1[mt][1] = (f32x4){b1v1, b1v1, b1v1, b1v1};
    }
#pragma unroll
    for (int mt = 0; mt < 2; mt++) {
      bf16x8 afm = ldfrag(&xw[wvx][mt * 16 + l15 + quad][0]);
      bf16x8 af4 = (quad == 0) ? ldfrag(&xw[wvx][mt * 16 + l15 + 4][0]) : zf;
#pragma unroll
      for (int nt = 0; nt < 2; nt++) {
        c1[mt][nt] = __builtin_amdgcn_mfma_f32_16x16x32_bf16(afm, bf1[nt], c1[mt][nt], 0, 0, 0);
        c1[mt][nt] = __builtin_amdgcn_mfma_f32_16x16x32_bf16(af4, bf1k4[nt], c1[mt][nt], 0, 0, 0);
      }
    }
#pragma unroll
    for (int mt = 0; mt < 2; mt++)
#pragma unroll
      for (int nt = 0; nt < 2; nt++)
#pragma unroll
        for (int r = 0; r < 4; r++) {
          int t = mt * 16 + quad * 4 + r;
          h1w[wvx][t + 1][nt * 16 + l15] = f2bf(fmaxf(c1[mt][nt][r], 0.f));
        }
    f32x4 c2[2][4];
#pragma unroll
    for (int mt = 0; mt < 2; mt++)
#pragma unroll
      for (int nt = 0; nt < 4; nt++) {
        float bv = b2s[nt * 16 + l15];
        c2[mt][nt] = (f32x4){bv, bv, bv, bv};
      }
#pragma unroll
    for (int k = 0; k < 3; k++)
#pragma unroll
      for (int mt = 0; mt < 2; mt++) {
        bf16x8 af = ldfrag(&h1w[wvx][mt * 16 + l15 + k][quad * 8]);
#pragma unroll
        for (int nt = 0; nt < 4; nt++)
          c2[mt][nt] = __builtin_amdgcn_mfma_f32_16x16x32_bf16(af, bf2[k][nt], c2[mt][nt], 0, 0, 0);
      }
    float sums[4];
#pragma unroll
    for (int nt = 0; nt < 4; nt++) {
      float s = 0.f;
#pragma unroll
      for (int mt = 0; mt < 2; mt++)
#pragma unroll
        for (int r = 0; r < 4; r++) s += fmaxf(c2[mt][nt][r], 0.f);
      s += __shfl_xor(s, 16);
      s += __shfl_xor(s, 32);
      sums[nt] = s;
    }
    float t0 = __shfl(sums[0], l15);
    float t1 = __shfl(sums[1], l15);
    float t2 = __shfl(sums[2], l15);
    float t3 = __shfl(sums[3], l15);
    float val = (quad == 0) ? t0 : (quad == 1) ? t1 : (quad == 2) ? t2 : t3;
    float angle = (float)(n & 255) * dive;
    float pe = (lane & 1) ? cosf(angle) : sinf(angle);
    float hv = val * (1.f / 32.f) + shank + pe;
    hout[(size_t)n * 64 + lane] = hv;
    hb[(size_t)n * 64 + lane] = f2bf(hv);
  }
}

// Fused qkv + flash attention. A/B fragments read directly from global bf16
// (hb, prepped weights). One barrier (qkv visibility). Output bf16 obuf.
__global__ __launch_bounds__(256) void attn_fused_kernel(
    const unsigned short* __restrict__ hb, const unsigned short* __restrict__ wqkv,
    const float* __restrict__ bqkv, const int* __restrict__ lens,
    unsigned short* __restrict__ obuf) {
  __shared__ __align__(16) unsigned short qs[256][24];
  __shared__ __align__(16) unsigned short kst[256][24];
  __shared__ __align__(16) unsigned short vT[16][264];
  __shared__ __align__(16) unsigned short pw[4][16][264];
  int bh = blockIdx.x;
  int b_ = bh >> 2, hd = bh & 3;
  int tid = threadIdx.x;
  int wvx = tid >> 6, lane = tid & 63, quad = lane >> 4, l15 = lane & 15;
  int len = lens[b_];
  const unsigned short* hbb = hb + (size_t)b_ * 256 * 64;
  const unsigned short* wq = wqkv + (hd * 16) * 64;        // pre-scaled 0.25
  const unsigned short* wk = wqkv + (64 + hd * 16) * 64;
  const unsigned short* wv = wqkv + (128 + hd * 16) * 64;
  float bq_ = 0.25f * bqkv[hd * 16 + l15];
  float bk_ = bqkv[64 + hd * 16 + l15];
  f32x4 bv_;
#pragma unroll
  for (int r = 0; r < 4; r++) bv_[r] = bqkv[128 + hd * 16 + quad * 4 + r];
#pragma unroll
  for (int t4 = 0; t4 < 4; t4++) {
    int tile = wvx * 4 + t4;
    f32x4 aq = (f32x4){bq_, bq_, bq_, bq_};
    f32x4 ak = (f32x4){bk_, bk_, bk_, bk_};
    f32x4 av = bv_;
#pragma unroll
    for (int ks = 0; ks < 64; ks += 32) {
      bf16x8 af = ldfrag(hbb + (tile * 16 + l15) * 64 + ks + quad * 8);
      aq = __builtin_amdgcn_mfma_f32_16x16x32_bf16(af, ldfrag(wq + l15 * 64 + ks + quad * 8), aq, 0, 0, 0);
      ak = __builtin_amdgcn_mfma_f32_16x16x32_bf16(af, ldfrag(wk + l15 * 64 + ks + quad * 8), ak, 0, 0, 0);
      av = __builtin_amdgcn_mfma_f32_16x16x32_bf16(ldfrag(wv + l15 * 64 + ks + quad * 8), af, av, 0, 0, 0);
    }
#pragma unroll
    for (int r = 0; r < 4; r++) {
      qs[tile * 16 + quad * 4 + r][l15] = f2bf(aq[r]);
      kst[tile * 16 + quad * 4 + r][l15] = f2bf(ak[r]);
      vT[quad * 4 + r][tile * 16 + l15] = f2bf(av[r]);
    }
  }
  __syncthreads();
  bf16x8 zf = {0, 0, 0, 0, 0, 0, 0, 0};
  f32x4 zero = {0.f, 0.f, 0.f, 0.f};
#pragma unroll 1
  for (int j = 0; j < 4; j++) {
    int qt = wvx * 4 + j;
    bf16x8 bq = (quad < 2) ? ldfrag(&qs[qt * 16 + l15][quad * 8]) : zf;
    f32x4 s[16];
#pragma unroll
    for (int t = 0; t < 16; t++) {
      bf16x8 ak = (quad < 2) ? ldfrag(&kst[t * 16 + l15][quad * 8]) : zf;
      s[t] = __builtin_amdgcn_mfma_f32_16x16x32_bf16(ak, bq, zero, 0, 0, 0);
    }
    float mx = -1e30f;
#pragma unroll
    for (int t = 0; t < 16; t++)
#pragma unroll
      for (int r = 0; r < 4; r++) {
        int key = t * 16 + quad * 4 + r;
        float v = (key < len) ? s[t][r] : -1e30f;
        s[t][r] = v;
        mx = fmaxf(mx, v);
      }
    mx = fmaxf(mx, __shfl_xor(mx, 16));
    mx = fmaxf(mx, __shfl_xor(mx, 32));
    float sum = 0.f;
#pragma unroll
    for (int t = 0; t < 16; t++)
#pragma unroll
      for (int r = 0; r < 4; r++) {
        float p = __expf(s[t][r] - mx);
        s[t][r] = p;
        sum += p;
      }
    sum += __shfl_xor(sum, 16);
    sum += __shfl_xor(sum, 32);
#pragma unroll
    for (int t = 0; t < 16; t++) {
      short4 pp;
      pp.x = (short)f2bf(s[t][0]); pp.y = (short)f2bf(s[t][1]);
      pp.z = (short)f2bf(s[t][2]); pp.w = (short)f2bf(s[t][3]);
      *(short4*)&pw[wvx][l15][t * 16 + quad * 4] = pp;
    }
    f32x4 acc = zero;
#pragma unroll
    for (int c = 0; c < 8; c++) {
      bf16x8 avv = ldfrag(&vT[l15][c * 32 + quad * 8]);
      bf16x8 bp = ldfrag(&pw[wvx][l15][c * 32 + quad * 8]);
      acc = __builtin_amdgcn_mfma_f32_16x16x32_bf16(avv, bp, acc, 0, 0, 0);
    }
    float inv = 1.f / sum;
    short4 w;
    w.x = (short)f2bf(acc[0] * inv); w.y = (short)f2bf(acc[1] * inv);
    w.z = (short)f2bf(acc[2] * inv); w.w = (short)f2bf(acc[3] * inv);
    *(short4*)&obuf[(size_t)(b_ * 256 + qt * 16 + l15) * 64 + hd * 16 + quad * 4] = w;
  }
}

// Fused row-local trio — zero barriers, zero weight staging. A-frags from
// global bf16 obuf, B-frags from global bf16 weights; LN1 output kept in
// registers for the ff2 residual (same (row,col) per thread both times).
__global__ __launch_bounds__(256) void fused_rl_kernel(
    const unsigned short* __restrict__ obuf, float* __restrict__ H,
    unsigned short* __restrict__ Hb,
    const unsigned short* __restrict__ wout, const float* __restrict__ bout,
    const float* __restrict__ ln1g, const float* __restrict__ ln1b,
    const unsigned short* __restrict__ wff1, const float* __restrict__ bff1,
    const unsigned short* __restrict__ wff2, const float* __restrict__ bff2,
    const float* __restrict__ ln2g, const float* __restrict__ ln2b) {
  __shared__ __align__(16) unsigned short h1b[64][72];
  __shared__ __align__(16) unsigned short ffa[64][264];
  int m0 = blockIdx.x * 64;
  int tid = threadIdx.x;
  int wvx = tid >> 6, lane = tid & 63, quad = lane >> 4, l15 = lane & 15;
  int lr = wvx * 16 + quad * 4;
  // ---- outproj + LN1 ----
  f32x4 acc[4];
#pragma unroll
  for (int nt = 0; nt < 4; nt++) {
    float b = bout[nt * 16 + l15];
    acc[nt] = (f32x4){b, b, b, b};
  }
#pragma unroll
  for (int ks = 0; ks < 64; ks += 32) {
    bf16x8 af = ldfrag(obuf + (size_t)(m0 + wvx * 16 + l15) * 64 + ks + quad * 8);
#pragma unroll
    for (int nt = 0; nt < 4; nt++) {
      bf16x8 bfr = ldfrag(wout + (nt * 16 + l15) * 64 + ks + quad * 8);
      acc[nt] = __builtin_amdgcn_mfma_f32_16x16x32_bf16(af, bfr, acc[nt], 0, 0, 0);
    }
  }
  float h1reg[4][4];
#pragma unroll
  for (int r = 0; r < 4; r++) {
    float rv[4];
    float s = 0.f;
#pragma unroll
    for (int nt = 0; nt < 4; nt++) {
      float v = acc[nt][r] + H[(size_t)(m0 + lr + r) * 64 + nt * 16 + l15];
      rv[nt] = v; s += v;
    }
    s += __shfl_xor(s, 1); s += __shfl_xor(s, 2);
    s += __shfl_xor(s, 4); s += __shfl_xor(s, 8);
    float mean = s * (1.f / 64.f);
    float vsum = 0.f;
#pragma unroll
    for (int nt = 0; nt < 4; nt++) { rv[nt] -= mean; vsum += rv[nt] * rv[nt]; }
    vsum += __shfl_xor(vsum, 1); vsum += __shfl_xor(vsum, 2);
    vsum += __shfl_xor(vsum, 4); vsum += __shfl_xor(vsum, 8);
    float inv = rsqrtf(vsum * (1.f / 64.f) + 1e-5f);
#pragma unroll
    for (int nt = 0; nt < 4; nt++) {
      int col = nt * 16 + l15;
      float hv = rv[nt] * inv * ln1g[col] + ln1b[col];
      h1reg[r][nt] = hv;
      h1b[lr + r][col] = f2bf(hv);
    }
  }
  // ---- ff1 (relu) ----
  f32x4 a2[16];
#pragma unroll
  for (int nt = 0; nt < 16; nt++) {
    float b = bff1[nt * 16 + l15];
    a2[nt] = (f32x4){b, b, b, b};
  }
#pragma unroll
  for (int ks = 0; ks < 64; ks += 32) {
    bf16x8 af = ldfrag(&h1b[wvx * 16 + l15][ks + quad * 8]);
#pragma unroll
    for (int nt = 0; nt < 16; nt++) {
      bf16x8 bfr = ldfrag(wff1 + (nt * 16 + l15) * 64 + ks + quad * 8);
      a2[nt] = __builtin_amdgcn_mfma_f32_16x16x32_bf16(af, bfr, a2[nt], 0, 0, 0);
    }
  }
#pragma unroll
  for (int nt = 0; nt < 16; nt++)
#pragma unroll
    for (int r = 0; r < 4; r++)
      ffa[lr + r][nt * 16 + l15] = f2bf(fmaxf(a2[nt][r], 0.f));
  // ---- ff2 + LN2 ----
#pragma unroll
  for (int nt = 0; nt < 4; nt++) {
    float b = bff2[nt * 16 + l15];
    acc[nt] = (f32x4){b, b, b, b};
  }
#pragma unroll
  for (int ks = 0; ks < 256; ks += 32) {
    bf16x8 af = ldfrag(&ffa[wvx * 16 + l15][ks + quad * 8]);
#pragma unroll
    for (int nt = 0; nt < 4; nt++) {
      bf16x8 bfr = ldfrag(wff2 + (nt * 16 + l15) * 256 + ks + quad * 8);
      acc[nt] = __builtin_amdgcn_mfma_f32_16x16x32_bf16(af, bfr, acc[nt], 0, 0, 0);
    }
  }
#pragma unroll
  for (int r = 0; r < 4; r++) {
    float rv[4];
    float s = 0.f;
#pragma unroll
    for (int nt = 0; nt < 4; nt++) {
      float v = acc[nt][r] + h1reg[r][nt];
      rv[nt] = v; s += v;
    }
    s += __shfl_xor(s, 1); s += __shfl_xor(s, 2);
    s += __shfl_xor(s, 4); s += __shfl_xor(s, 8);
    float mean = s * (1.f / 64.f);
    float vsum = 0.f;
#pragma unroll
    for (int nt = 0; nt < 4; nt++) { rv[nt] -= mean; vsum += rv[nt] * rv[nt]; }
    vsum += __shfl_xor(vsum, 1); vsum += __shfl_xor(vsum, 2);
    vsum += __shfl_xor(vsum, 4); vsum += __shfl_xor(vsum, 8);
    float inv = rsqrtf(vsum * (1.f / 64.f) + 1e-5f);
#pragma unroll
    for (int nt = 0; nt < 4; nt++) {
      int col = nt * 16 + l15;
      float hv = rv[nt] * inv * ln2g[col] + ln2b[col];
      H[(size_t)(m0 + lr + r) * 64 + col] = hv;
      Hb[(size_t)(m0 + lr + r) * 64 + col] = f2bf(hv);
    }
  }
}

// Fused masked mean pool + all heads.
__global__ __launch_bounds__(256) void pool_heads_kernel(
    const float* __restrict__ h, const int* __restrict__ lens,
    const float* __restrict__ cls_w1, const float* __restrict__ cls_b1,
    const float* __restrict__ cls_w2, const float* __restrict__ cls_b2,
    const float* __restrict__ mu_w1, const float* __restrict__ mu_b1,
    const float* __restrict__ mu_w2, const float* __restrict__ mu_b2,
    const float* __restrict__ ls_w1, const float* __restrict__ ls_b1,
    const float* __restrict__ ls_w2, const float* __restrict__ ls_b2,
    const float* __restrict__ d_w1, const float* __restrict__ d_b1,
    const float* __restrict__ d_w2, const float* __restrict__ d_b2,
    float* __restrict__ out) {
  __shared__ float ps[4][64];
  __shared__ float p[64];
  __shared__ float t1[64];
  int b = blockIdx.x, tid = threadIdx.x;
  int e = tid & 63, sp = tid >> 6;
  int len = lens[b];
  {
    float sum = 0.f;
    int send = min(sp * 64 + 64, len);
    for (int s = sp * 64; s < send; s++) sum += h[(size_t)(b * 256 + s) * 64 + e];
    ps[sp][e] = sum;
  }
  __syncthreads();
  if (sp == 0)
    p[e] = (ps[0][e] + ps[1][e] + ps[2][e] + ps[3][e]) / ((float)len + 1e-8f);
  __syncthreads();
  if (tid < 64) {
    float a = cls_b1[tid];
    for (int j = 0; j < 64; j++) a += p[j] * cls_w1[tid * 64 + j];
    t1[tid] = fmaxf(a, 0.f);
  }
  __syncthreads();
  if (tid < 3) {
    float a2 = cls_b2[tid];
    for (int j = 0; j < 64; j++) a2 += t1[j] * cls_w2[tid * 64 + j];
    out[b * 16 + tid] = a2;
  }
  for (int z = 0; z < 3; z++) {
    __syncthreads();
    if (tid < 64) {
      float a = mu_b1[z * 64 + tid];
      for (int j = 0; j < 64; j++) a += p[j] * mu_w1[(z * 64 + tid) * 64 + j];
      t1[tid] = fmaxf(a, 0.f);
    }
    __syncthreads();
    if (tid < 2) {
      float a2 = mu_b2[z * 2 + tid];
      for (int j = 0; j < 64; j++) a2 += t1[j] * mu_w2[(z * 2 + tid) * 64 + j];
      out[b * 16 + 3 + z * 2 + tid] = a2;
    }
    __syncthreads();
    if (tid < 64) {
      float a = ls_b1[z * 64 + tid];
      for (int j = 0; j < 64; j++) a += p[j] * ls_w1[(z * 64 + tid) * 64 + j];
      t1[tid] = fmaxf(a, 0.f);
    }
    __syncthreads();
    if (tid < 2) {
      float a2 = ls_b2[z * 2 + tid];
      for (int j = 0; j < 64; j++) a2 += t1[j] * ls_w2[(z * 2 + tid) * 64 + j];
      out[b * 16 + 9 + z * 2 + tid] = __expf(a2);
    }
  }
  __syncthreads();
  if (tid < 64) {
    float a = d_b1[tid];
    for (int j = 0; j < 64; j++) a += p[j] * d_w1[tid * 64 + j];
    t1[tid] = fmaxf(a, 0.f);
  }
  __syncthreads();
  if (tid == 0) {
    float a2 = d_b2[0];
    for (int j = 0; j < 64; j++) a2 += t1[j] * d_w2[j];
    out[b * 16 + 15] = 1.f / (1.f + __expf(-a2));
  }
}

extern "C" void kernel_launch(void* const* d_in, const int* in_sizes, int n_in,
                              void* d_out, int out_size, void* d_ws, size_t ws_size,
                              hipStream_t stream) {
  const float* wav       = (const float*)d_in[0];
  const int*   sid       = (const int*)d_in[1];
  const void*  mask      = d_in[2];
  const float* conv1_w   = (const float*)d_in[3];
  const float* conv1_b   = (const float*)d_in[4];
  const float* conv2_w   = (const float*)d_in[5];
  const float* conv2_b   = (const float*)d_in[6];
  const float* shank_emb = (const float*)d_in[7];
  const float* in_proj_w = (const float*)d_in[8];
  const float* in_proj_b = (const float*)d_in[9];
  const float* out_proj_w= (const float*)d_in[10];
  const float* out_proj_b= (const float*)d_in[11];
  const float* ln1_g     = (const float*)d_in[12];
  const float* ln1_b     = (const float*)d_in[13];
  const float* ff1_w     = (const float*)d_in[14];
  const float* ff1_b     = (const float*)d_in[15];
  const float* ff2_w     = (const float*)d_in[16];
  const float* ff2_b     = (const float*)d_in[17];
  const float* ln2_g     = (const float*)d_in[18];
  const float* ln2_b     = (const float*)d_in[19];
  const float* cls_w1    = (const float*)d_in[20];
  const float* cls_b1    = (const float*)d_in[21];
  const float* cls_w2    = (const float*)d_in[22];
  const float* cls_b2    = (const float*)d_in[23];
  const float* mu_w1     = (const float*)d_in[24];
  const float* mu_b1     = (const float*)d_in[25];
  const float* mu_w2     = (const float*)d_in[26];
  const float* mu_b2     = (const float*)d_in[27];
  const float* ls_w1     = (const float*)d_in[28];
  const float* ls_b1     = (const float*)d_in[29];
  const float* ls_w2     = (const float*)d_in[30];
  const float* ls_b2     = (const float*)d_in[31];
  const float* d_w1      = (const float*)d_in[32];
  const float* d_b1      = (const float*)d_in[33];
  const float* d_w2      = (const float*)d_in[34];
  const float* d_b2      = (const float*)d_in[35];
  float* out = (float*)d_out;

  float* ws = (float*)d_ws;
  float*          h     = ws;                                  // [32768,64] fp32
  unsigned short* hb    = (unsigned short*)(ws + 2097152);     // bf16 mirror
  unsigned short* obufb = (unsigned short*)(ws + 3145728);     // attn out bf16
  unsigned short* wb    = (unsigned short*)(ws + 4194304);     // prepped weights
  int*   ip     = (int*)(ws + 10493952);
  int*   flag   = ip;
  int*   counts = ip + 8;
  int*   lens   = ip + 16;
  int*   idxbuf = ip + 144;

  prep_weights_kernel<<<664, 256, 0, stream>>>(in_proj_w, out_proj_w, ff1_w, ff2_w,
                                               conv1_w, conv2_w, wb);
  detect_mask_kernel<<<1, 256, 0, stream>>>((const unsigned int*)mask, flag, counts, lens);
  bin_kernel<<<128, 256, 0, stream>>>(sid, mask, flag, counts, lens, idxbuf);
  init_emb_kernel<<<8192, 256, 0, stream>>>(sid, shank_emb, h, hb);
  conv_mfma_kernel<<<1280, 256, 0, stream>>>(idxbuf, counts, wav, wb, conv1_b, conv2_b,
                                             shank_emb, h, hb);
  for (int l = 0; l < 2; l++) {
    attn_fused_kernel<<<512, 256, 0, stream>>>(hb, wb + l * 12288,
                                               in_proj_b + l * 192, lens, obufb);
    fused_rl_kernel<<<512, 256, 0, stream>>>(
        obufb, h, hb,
        wb + 24576 + l * 4096, out_proj_b + l * 64,
        ln1_g + l * 64, ln1_b + l * 64,
        wb + 32768 + l * 16384, ff1_b + l * 256,
        wb + 65536 + l * 16384, ff2_b + l * 64,
        ln2_g + l * 64, ln2_b + l * 64);
  }
  pool_heads_kernel<<<128, 256, 0, stream>>>(h, lens, cls_w1, cls_b1, cls_w2, cls_b2,
                                             mu_w1, mu_b1, mu_w2, mu_b2,
                                             ls_w1, ls_b1, ls_w2, ls_b2,
                                             d_w1, d_b1, d_w2, d_b2, out);
}

// Round 12
// 303.189 us; speedup vs baseline: 5.1177x; 1.0158x over previous
//
#include <hip/hip_runtime.h>
#include <math.h>

// B=128, S=256, G=8, CMAX=6, T=32, E=64, NH=4, dh=16, L=2, DFF=256, Z=3

typedef short bf16x8 __attribute__((ext_vector_type(8)));
typedef float f32x4 __attribute__((ext_vector_type(4)));

__device__ __forceinline__ unsigned short f2bf(float f) {
  unsigned u = __float_as_uint(f);
  u += 0x7fffu + ((u >> 16) & 1u);   // RNE
  return (unsigned short)(u >> 16);
}

__device__ __forceinline__ bf16x8 ldfrag(const unsigned short* p) {
  return *reinterpret_cast<const bf16x8*>(p);
}

__device__ __forceinline__ bool is_masked(const void* mask_, int flag, int idx) {
  return flag ? (((const unsigned char*)mask_)[idx] != 0)
              : (((const int*)mask_)[idx] != 0);
}

// Weight prep + mask-dtype detect + counter zeroing (one launch).
// wb layout (shorts): [0,24576) qkv  [24576,32768) wout  [32768,65536) ff1
// [65536,98304) ff2  [98304,108544) w1p[g][5][32][8]  [108544,169984) w2p[g][3][64][40]
__global__ __launch_bounds__(256) void prep_all_kernel(
    const float* __restrict__ in_proj_w, const float* __restrict__ out_proj_w,
    const float* __restrict__ ff1_w, const float* __restrict__ ff2_w,
    const float* __restrict__ w1_, const float* __restrict__ w2_,
    unsigned short* __restrict__ wb, const unsigned int* __restrict__ mw,
    int* __restrict__ flag, int* __restrict__ counts, int* __restrict__ lens) {
  int tid = threadIdx.x;
  int i = blockIdx.x * 256 + tid;
  if (i < 24576) {
    int rem = i % 12288, row = rem / 64;
    float v = in_proj_w[i];
    if (row < 64) v *= 0.25f;
    wb[i] = f2bf(v);
  } else if (i < 32768) {
    wb[i] = f2bf(out_proj_w[i - 24576]);
  } else if (i < 65536) {
    wb[i] = f2bf(ff1_w[i - 32768]);
  } else if (i < 98304) {
    wb[i] = f2bf(ff2_w[i - 65536]);
  } else if (i < 108544) {
    int j = i - 98304;
    int g = j / 1280, rem = j % 1280;
    int k = rem >> 8, rest = rem & 255, oc = rest >> 3, ic = rest & 7;
    wb[i] = (ic < 6) ? f2bf(w1_[g * 960 + oc * 30 + ic * 5 + k]) : 0;
  } else if (i < 169984) {
    int j = i - 108544;
    int g = j / 7680, rem = j % 7680;
    int k = rem / 2560, rest = rem % 2560, e = rest / 40, ic = rest % 40;
    wb[i] = (ic < 32) ? f2bf(w2_[g * 6144 + e * 96 + ic * 3 + k]) : 0;
  }
  if (blockIdx.x == 0) {
    __shared__ int sh;
    if (tid == 0) sh = 0;
    __syncthreads();
    int bad = 0;
    for (int k = tid; k < 8192; k += 256)
      if (mw[k] > 1u) bad = 1;
    if (bad) atomicOr(&sh, 1);
    if (tid < 8) counts[tid] = 0;
    if (tid < 128) lens[tid] = 0;
    __syncthreads();
    if (tid == 0) *flag = sh;
  }
}

// Base embedding (fp32 + bf16 mirror); blocks < 128 also bin active tokens
// by shank id (hierarchical atomics). Conv overwrites active rows later.
__global__ __launch_bounds__(256) void init_bin_kernel(
    const int* __restrict__ sid, const float* __restrict__ shank_emb,
    const void* __restrict__ mask_, const int* __restrict__ flagp,
    int* __restrict__ counts, int* __restrict__ lens, int* __restrict__ idxbuf,
    float* __restrict__ hout, unsigned short* __restrict__ hb) {
  __shared__ int lcnt[8];
  __shared__ int lbase[8];
  int tid = threadIdx.x;
  int i = blockIdx.x * 256 + tid;
  {
    int n = i >> 6, e = i & 63, s = n & 255;
    int g = sid[n];
    float div = __expf(-(float)(e & ~1) * (9.21034037f / 64.f));
    float angle = (float)s * div;
    float pe = (e & 1) ? cosf(angle) : sinf(angle);
    float v = shank_emb[g * 64 + e] + pe;
    hout[i] = v;
    hb[i] = f2bf(v);
  }
  if (blockIdx.x < 128) {
    int b = blockIdx.x;
    int n = b * 256 + tid;
    int flag = *flagp;
    bool act = !is_masked(mask_, flag, n);
    int g = act ? sid[n] : 0;
    if (tid < 8) lcnt[tid] = 0;
    __syncthreads();
    int pos = 0;
    if (act) pos = atomicAdd(&lcnt[g], 1);
    __syncthreads();
    if (tid < 8) lbase[tid] = atomicAdd(&counts[tid], lcnt[tid]);
    if (tid == 0)
      lens[b] = lcnt[0] + lcnt[1] + lcnt[2] + lcnt[3] +
                lcnt[4] + lcnt[5] + lcnt[6] + lcnt[7];
    __syncthreads();
    if (act) idxbuf[g * 32768 + lbase[g] + pos] = n;
  }
}

// Conv encoder via bf16 MFMA — wave-independent, software-pipelined: next
// token's idxbuf+waveform prefetched into registers before the MFMA chain.
__global__ __launch_bounds__(256) void conv_mfma_kernel(
    const int* __restrict__ idxbuf, const int* __restrict__ counts,
    const float* __restrict__ wav, const unsigned short* __restrict__ wb,
    const float* __restrict__ b1_, const float* __restrict__ b2_,
    const float* __restrict__ shank_emb, float* __restrict__ hout,
    unsigned short* __restrict__ hb) {
  __shared__ __align__(16) unsigned short w1f[5][32][8];
  __shared__ __align__(16) unsigned short w2f[3][64][40];
  __shared__ float b1s[32];
  __shared__ float b2s[64];
  __shared__ __align__(16) unsigned short xw[4][36][8];
  __shared__ __align__(16) unsigned short h1w[4][34][40];
  int g = blockIdx.x & 7, bib = blockIdx.x >> 3;
  int tid = threadIdx.x;
  int wvx = tid >> 6, lane = tid & 63, quad = lane >> 4, l15 = lane & 15;
  {
    const uint4* s1 = (const uint4*)(wb + 98304 + g * 1280);
    uint4* d1 = (uint4*)&w1f[0][0][0];
    for (int i = tid; i < 160; i += 256) d1[i] = s1[i];
    const uint4* s2 = (const uint4*)(wb + 108544 + g * 7680);
    uint4* d2 = (uint4*)&w2f[0][0][0];
    for (int i = tid; i < 960; i += 256) d2[i] = s2[i];
  }
  if (tid < 32) b1s[tid] = b1_[g * 32 + tid];
  if (tid < 64) b2s[tid] = b2_[g * 64 + tid];
  {
    unsigned int* xz = (unsigned int*)&xw[wvx][0][0];
    for (int i = lane; i < 144; i += 64) xz[i] = 0;
    unsigned int* hz0 = (unsigned int*)&h1w[wvx][0][0];
    unsigned int* hz1 = (unsigned int*)&h1w[wvx][33][0];
    if (lane < 20) hz0[lane] = 0;
    else if (lane < 40) hz1[lane - 20] = 0;
  }
  __syncthreads();
  bf16x8 zf = {0, 0, 0, 0, 0, 0, 0, 0};
  bf16x8 bf1[2], bf1k4[2], bf2[3][4];
#pragma unroll
  for (int nt = 0; nt < 2; nt++) {
    bf1[nt] = ldfrag(&w1f[quad][nt * 16 + l15][0]);
    bf1k4[nt] = (quad == 0) ? ldfrag(&w1f[4][nt * 16 + l15][0]) : zf;
  }
#pragma unroll
  for (int k = 0; k < 3; k++)
#pragma unroll
    for (int nt = 0; nt < 4; nt++)
      bf2[k][nt] = ldfrag(&w2f[k][nt * 16 + l15][quad * 8]);
  float b1v0 = b1s[l15], b1v1 = b1s[16 + l15];
  float shank = shank_emb[g * 64 + lane];
  float dive = __expf(-(float)(lane & ~1) * (9.21034037f / 64.f));
  int cnt = counts[g];
  int ic_w = lane >> 3, t0_w = (lane & 7) * 4;
  int ti = bib * 4 + wvx;
  int n = 0;
  float4 v = make_float4(0.f, 0.f, 0.f, 0.f);
  if (ti < cnt) {
    n = idxbuf[g * 32768 + ti];
    if (lane < 48) v = *(const float4*)&wav[n * 192 + lane * 4];
  }
  while (ti < cnt) {
    // prefetch next token (overlaps MFMA chain below)
    int tn = ti + 640;
    int n2 = 0;
    float4 v2 = make_float4(0.f, 0.f, 0.f, 0.f);
    if (tn < cnt) {
      n2 = idxbuf[g * 32768 + tn];
      if (lane < 48) v2 = *(const float4*)&wav[n2 * 192 + lane * 4];
    }
    if (lane < 48) {
      xw[wvx][t0_w + 2][ic_w] = f2bf(v.x);
      xw[wvx][t0_w + 3][ic_w] = f2bf(v.y);
      xw[wvx][t0_w + 4][ic_w] = f2bf(v.z);
      xw[wvx][t0_w + 5][ic_w] = f2bf(v.w);
    }
    f32x4 c1[2][2];
#pragma unroll
    for (int mt = 0; mt < 2; mt++) {
      c1[mt][0] = (f32x4){b1v0, b1v0, b1v0, b1v0};
      c1[mt][1] = (f32x4){b1v1, b1v1, b1v1, b1v1};
    }
#pragma unroll
    for (int mt = 0; mt < 2; mt++) {
      bf16x8 afm = ldfrag(&xw[wvx][mt * 16 + l15 + quad][0]);
      bf16x8 af4 = (quad == 0) ? ldfrag(&xw[wvx][mt * 16 + l15 + 4][0]) : zf;
#pragma unroll
      for (int nt = 0; nt < 2; nt++) {
        c1[mt][nt] = __builtin_amdgcn_mfma_f32_16x16x32_bf16(afm, bf1[nt], c1[mt][nt], 0, 0, 0);
        c1[mt][nt] = __builtin_amdgcn_mfma_f32_16x16x32_bf16(af4, bf1k4[nt], c1[mt][nt], 0, 0, 0);
      }
    }
#pragma unroll
    for (int mt = 0; mt < 2; mt++)
#pragma unroll
      for (int nt = 0; nt < 2; nt++)
#pragma unroll
        for (int r = 0; r < 4; r++) {
          int t = mt * 16 + quad * 4 + r;
          h1w[wvx][t + 1][nt * 16 + l15] = f2bf(fmaxf(c1[mt][nt][r], 0.f));
        }
    f32x4 c2[2][4];
#pragma unroll
    for (int mt = 0; mt < 2; mt++)
#pragma unroll
      for (int nt = 0; nt < 4; nt++) {
        float bv = b2s[nt * 16 + l15];
        c2[mt][nt] = (f32x4){bv, bv, bv, bv};
      }
#pragma unroll
    for (int k = 0; k < 3; k++)
#pragma unroll
      for (int mt = 0; mt < 2; mt++) {
        bf16x8 af = ldfrag(&h1w[wvx][mt * 16 + l15 + k][quad * 8]);
#pragma unroll
        for (int nt = 0; nt < 4; nt++)
          c2[mt][nt] = __builtin_amdgcn_mfma_f32_16x16x32_bf16(af, bf2[k][nt], c2[mt][nt], 0, 0, 0);
      }
    float sums[4];
#pragma unroll
    for (int nt = 0; nt < 4; nt++) {
      float s = 0.f;
#pragma unroll
      for (int mt = 0; mt < 2; mt++)
#pragma unroll
        for (int r = 0; r < 4; r++) s += fmaxf(c2[mt][nt][r], 0.f);
      s += __shfl_xor(s, 16);
      s += __shfl_xor(s, 32);
      sums[nt] = s;
    }
    float t0 = __shfl(sums[0], l15);
    float t1 = __shfl(sums[1], l15);
    float t2 = __shfl(sums[2], l15);
    float t3 = __shfl(sums[3], l15);
    float val = (quad == 0) ? t0 : (quad == 1) ? t1 : (quad == 2) ? t2 : t3;
    float angle = (float)(n & 255) * dive;
    float pe = (lane & 1) ? cosf(angle) : sinf(angle);
    float hv = val * (1.f / 32.f) + shank + pe;
    hout[(size_t)n * 64 + lane] = hv;
    hb[(size_t)n * 64 + lane] = f2bf(hv);
    ti = tn; n = n2; v = v2;
  }
}

// Fused qkv + flash attention. A/B fragments read directly from global bf16.
__global__ __launch_bounds__(256) void attn_fused_kernel(
    const unsigned short* __restrict__ hb, const unsigned short* __restrict__ wqkv,
    const float* __restrict__ bqkv, const int* __restrict__ lens,
    unsigned short* __restrict__ obuf) {
  __shared__ __align__(16) unsigned short qs[256][24];
  __shared__ __align__(16) unsigned short kst[256][24];
  __shared__ __align__(16) unsigned short vT[16][264];
  __shared__ __align__(16) unsigned short pw[4][16][264];
  int bh = blockIdx.x;
  int b_ = bh >> 2, hd = bh & 3;
  int tid = threadIdx.x;
  int wvx = tid >> 6, lane = tid & 63, quad = lane >> 4, l15 = lane & 15;
  int len = lens[b_];
  const unsigned short* hbb = hb + (size_t)b_ * 256 * 64;
  const unsigned short* wq = wqkv + (hd * 16) * 64;        // pre-scaled 0.25
  const unsigned short* wk = wqkv + (64 + hd * 16) * 64;
  const unsigned short* wv = wqkv + (128 + hd * 16) * 64;
  float bq_ = 0.25f * bqkv[hd * 16 + l15];
  float bk_ = bqkv[64 + hd * 16 + l15];
  f32x4 bv_;
#pragma unroll
  for (int r = 0; r < 4; r++) bv_[r] = bqkv[128 + hd * 16 + quad * 4 + r];
#pragma unroll
  for (int t4 = 0; t4 < 4; t4++) {
    int tile = wvx * 4 + t4;
    f32x4 aq = (f32x4){bq_, bq_, bq_, bq_};
    f32x4 ak = (f32x4){bk_, bk_, bk_, bk_};
    f32x4 av = bv_;
#pragma unroll
    for (int ks = 0; ks < 64; ks += 32) {
      bf16x8 af = ldfrag(hbb + (tile * 16 + l15) * 64 + ks + quad * 8);
      aq = __builtin_amdgcn_mfma_f32_16x16x32_bf16(af, ldfrag(wq + l15 * 64 + ks + quad * 8), aq, 0, 0, 0);
      ak = __builtin_amdgcn_mfma_f32_16x16x32_bf16(af, ldfrag(wk + l15 * 64 + ks + quad * 8), ak, 0, 0, 0);
      av = __builtin_amdgcn_mfma_f32_16x16x32_bf16(ldfrag(wv + l15 * 64 + ks + quad * 8), af, av, 0, 0, 0);
    }
#pragma unroll
    for (int r = 0; r < 4; r++) {
      qs[tile * 16 + quad * 4 + r][l15] = f2bf(aq[r]);
      kst[tile * 16 + quad * 4 + r][l15] = f2bf(ak[r]);
      vT[quad * 4 + r][tile * 16 + l15] = f2bf(av[r]);
    }
  }
  __syncthreads();
  bf16x8 zf = {0, 0, 0, 0, 0, 0, 0, 0};
  f32x4 zero = {0.f, 0.f, 0.f, 0.f};
#pragma unroll 1
  for (int j = 0; j < 4; j++) {
    int qt = wvx * 4 + j;
    bf16x8 bq = (quad < 2) ? ldfrag(&qs[qt * 16 + l15][quad * 8]) : zf;
    f32x4 s[16];
#pragma unroll
    for (int t = 0; t < 16; t++) {
      bf16x8 ak = (quad < 2) ? ldfrag(&kst[t * 16 + l15][quad * 8]) : zf;
      s[t] = __builtin_amdgcn_mfma_f32_16x16x32_bf16(ak, bq, zero, 0, 0, 0);
    }
    float mx = -1e30f;
#pragma unroll
    for (int t = 0; t < 16; t++)
#pragma unroll
      for (int r = 0; r < 4; r++) {
        int key = t * 16 + quad * 4 + r;
        float v = (key < len) ? s[t][r] : -1e30f;
        s[t][r] = v;
        mx = fmaxf(mx, v);
      }
    mx = fmaxf(mx, __shfl_xor(mx, 16));
    mx = fmaxf(mx, __shfl_xor(mx, 32));
    float sum = 0.f;
#pragma unroll
    for (int t = 0; t < 16; t++)
#pragma unroll
      for (int r = 0; r < 4; r++) {
        float p = __expf(s[t][r] - mx);
        s[t][r] = p;
        sum += p;
      }
    sum += __shfl_xor(sum, 16);
    sum += __shfl_xor(sum, 32);
#pragma unroll
    for (int t = 0; t < 16; t++) {
      short4 pp;
      pp.x = (short)f2bf(s[t][0]); pp.y = (short)f2bf(s[t][1]);
      pp.z = (short)f2bf(s[t][2]); pp.w = (short)f2bf(s[t][3]);
      *(short4*)&pw[wvx][l15][t * 16 + quad * 4] = pp;
    }
    f32x4 acc = zero;
#pragma unroll
    for (int c = 0; c < 8; c++) {
      bf16x8 avv = ldfrag(&vT[l15][c * 32 + quad * 8]);
      bf16x8 bp = ldfrag(&pw[wvx][l15][c * 32 + quad * 8]);
      acc = __builtin_amdgcn_mfma_f32_16x16x32_bf16(avv, bp, acc, 0, 0, 0);
    }
    float inv = 1.f / sum;
    short4 w;
    w.x = (short)f2bf(acc[0] * inv); w.y = (short)f2bf(acc[1] * inv);
    w.z = (short)f2bf(acc[2] * inv); w.w = (short)f2bf(acc[3] * inv);
    *(short4*)&obuf[(size_t)(b_ * 256 + qt * 16 + l15) * 64 + hd * 16 + quad * 4] = w;
  }
}

// Fused row-local trio — zero barriers, zero weight staging.
__global__ __launch_bounds__(256) void fused_rl_kernel(
    const unsigned short* __restrict__ obuf, float* __restrict__ H,
    unsigned short* __restrict__ Hb,
    const unsigned short* __restrict__ wout, const float* __restrict__ bout,
    const float* __restrict__ ln1g, const float* __restrict__ ln1b,
    const unsigned short* __restrict__ wff1, const float* __restrict__ bff1,
    const unsigned short* __restrict__ wff2, const float* __restrict__ bff2,
    const float* __restrict__ ln2g, const float* __restrict__ ln2b) {
  __shared__ __align__(16) unsigned short h1b[64][72];
  __shared__ __align__(16) unsigned short ffa[64][264];
  int m0 = blockIdx.x * 64;
  int tid = threadIdx.x;
  int wvx = tid >> 6, lane = tid & 63, quad = lane >> 4, l15 = lane & 15;
  int lr = wvx * 16 + quad * 4;
  f32x4 acc[4];
#pragma unroll
  for (int nt = 0; nt < 4; nt++) {
    float b = bout[nt * 16 + l15];
    acc[nt] = (f32x4){b, b, b, b};
  }
#pragma unroll
  for (int ks = 0; ks < 64; ks += 32) {
    bf16x8 af = ldfrag(obuf + (size_t)(m0 + wvx * 16 + l15) * 64 + ks + quad * 8);
#pragma unroll
    for (int nt = 0; nt < 4; nt++) {
      bf16x8 bfr = ldfrag(wout + (nt * 16 + l15) * 64 + ks + quad * 8);
      acc[nt] = __builtin_amdgcn_mfma_f32_16x16x32_bf16(af, bfr, acc[nt], 0, 0, 0);
    }
  }
  float h1reg[4][4];
#pragma unroll
  for (int r = 0; r < 4; r++) {
    float rv[4];
    float s = 0.f;
#pragma unroll
    for (int nt = 0; nt < 4; nt++) {
      float v = acc[nt][r] + H[(size_t)(m0 + lr + r) * 64 + nt * 16 + l15];
      rv[nt] = v; s += v;
    }
    s += __shfl_xor(s, 1); s += __shfl_xor(s, 2);
    s += __shfl_xor(s, 4); s += __shfl_xor(s, 8);
    float mean = s * (1.f / 64.f);
    float vsum = 0.f;
#pragma unroll
    for (int nt = 0; nt < 4; nt++) { rv[nt] -= mean; vsum += rv[nt] * rv[nt]; }
    vsum += __shfl_xor(vsum, 1); vsum += __shfl_xor(vsum, 2);
    vsum += __shfl_xor(vsum, 4); vsum += __shfl_xor(vsum, 8);
    float inv = rsqrtf(vsum * (1.f / 64.f) + 1e-5f);
#pragma unroll
    for (int nt = 0; nt < 4; nt++) {
      int col = nt * 16 + l15;
      float hv = rv[nt] * inv * ln1g[col] + ln1b[col];
      h1reg[r][nt] = hv;
      h1b[lr + r][col] = f2bf(hv);
    }
  }
  f32x4 a2[16];
#pragma unroll
  for (int nt = 0; nt < 16; nt++) {
    float b = bff1[nt * 16 + l15];
    a2[nt] = (f32x4){b, b, b, b};
  }
#pragma unroll
  for (int ks = 0; ks < 64; ks += 32) {
    bf16x8 af = ldfrag(&h1b[wvx * 16 + l15][ks + quad * 8]);
#pragma unroll
    for (int nt = 0; nt < 16; nt++) {
      bf16x8 bfr = ldfrag(wff1 + (nt * 16 + l15) * 64 + ks + quad * 8);
      a2[nt] = __builtin_amdgcn_mfma_f32_16x16x32_bf16(af, bfr, a2[nt], 0, 0, 0);
    }
  }
#pragma unroll
  for (int nt = 0; nt < 16; nt++)
#pragma unroll
    for (int r = 0; r < 4; r++)
      ffa[lr + r][nt * 16 + l15] = f2bf(fmaxf(a2[nt][r], 0.f));
#pragma unroll
  for (int nt = 0; nt < 4; nt++) {
    float b = bff2[nt * 16 + l15];
    acc[nt] = (f32x4){b, b, b, b};
  }
#pragma unroll
  for (int ks = 0; ks < 256; ks += 32) {
    bf16x8 af = ldfrag(&ffa[wvx * 16 + l15][ks + quad * 8]);
#pragma unroll
    for (int nt = 0; nt < 4; nt++) {
      bf16x8 bfr = ldfrag(wff2 + (nt * 16 + l15) * 256 + ks + quad * 8);
      acc[nt] = __builtin_amdgcn_mfma_f32_16x16x32_bf16(af, bfr, acc[nt], 0, 0, 0);
    }
  }
#pragma unroll
  for (int r = 0; r < 4; r++) {
    float rv[4];
    float s = 0.f;
#pragma unroll
    for (int nt = 0; nt < 4; nt++) {
      float v = acc[nt][r] + h1reg[r][nt];
      rv[nt] = v; s += v;
    }
    s += __shfl_xor(s, 1); s += __shfl_xor(s, 2);
    s += __shfl_xor(s, 4); s += __shfl_xor(s, 8);
    float mean = s * (1.f / 64.f);
    float vsum = 0.f;
#pragma unroll
    for (int nt = 0; nt < 4; nt++) { rv[nt] -= mean; vsum += rv[nt] * rv[nt]; }
    vsum += __shfl_xor(vsum, 1); vsum += __shfl_xor(vsum, 2);
    vsum += __shfl_xor(vsum, 4); vsum += __shfl_xor(vsum, 8);
    float inv = rsqrtf(vsum * (1.f / 64.f) + 1e-5f);
#pragma unroll
    for (int nt = 0; nt < 4; nt++) {
      int col = nt * 16 + l15;
      float hv = rv[nt] * inv * ln2g[col] + ln2b[col];
      H[(size_t)(m0 + lr + r) * 64 + col] = hv;
      Hb[(size_t)(m0 + lr + r) * 64 + col] = f2bf(hv);
    }
  }
}

// Fused masked mean pool + all heads.
__global__ __launch_bounds__(256) void pool_heads_kernel(
    const float* __restrict__ h, const int* __restrict__ lens,
    const float* __restrict__ cls_w1, const float* __restrict__ cls_b1,
    const float* __restrict__ cls_w2, const float* __restrict__ cls_b2,
    const float* __restrict__ mu_w1, const float* __restrict__ mu_b1,
    const float* __restrict__ mu_w2, const float* __restrict__ mu_b2,
    const float* __restrict__ ls_w1, const float* __restrict__ ls_b1,
    const float* __restrict__ ls_w2, const float* __restrict__ ls_b2,
    const float* __restrict__ d_w1, const float* __restrict__ d_b1,
    const float* __restrict__ d_w2, const float* __restrict__ d_b2,
    float* __restrict__ out) {
  __shared__ float ps[4][64];
  __shared__ float p[64];
  __shared__ float t1[64];
  int b = blockIdx.x, tid = threadIdx.x;
  int e = tid & 63, sp = tid >> 6;
  int len = lens[b];
  {
    float sum = 0.f;
    int send = min(sp * 64 + 64, len);
    for (int s = sp * 64; s < send; s++) sum += h[(size_t)(b * 256 + s) * 64 + e];
    ps[sp][e] = sum;
  }
  __syncthreads();
  if (sp == 0)
    p[e] = (ps[0][e] + ps[1][e] + ps[2][e] + ps[3][e]) / ((float)len + 1e-8f);
  __syncthreads();
  if (tid < 64) {
    float a = cls_b1[tid];
    for (int j = 0; j < 64; j++) a += p[j] * cls_w1[tid * 64 + j];
    t1[tid] = fmaxf(a, 0.f);
  }
  __syncthreads();
  if (tid < 3) {
    float a2 = cls_b2[tid];
    for (int j = 0; j < 64; j++) a2 += t1[j] * cls_w2[tid * 64 + j];
    out[b * 16 + tid] = a2;
  }
  for (int z = 0; z < 3; z++) {
    __syncthreads();
    if (tid < 64) {
      float a = mu_b1[z * 64 + tid];
      for (int j = 0; j < 64; j++) a += p[j] * mu_w1[(z * 64 + tid) * 64 + j];
      t1[tid] = fmaxf(a, 0.f);
    }
    __syncthreads();
    if (tid < 2) {
      float a2 = mu_b2[z * 2 + tid];
      for (int j = 0; j < 64; j++) a2 += t1[j] * mu_w2[(z * 2 + tid) * 64 + j];
      out[b * 16 + 3 + z * 2 + tid] = a2;
    }
    __syncthreads();
    if (tid < 64) {
      float a = ls_b1[z * 64 + tid];
      for (int j = 0; j < 64; j++) a += p[j] * ls_w1[(z * 64 + tid) * 64 + j];
      t1[tid] = fmaxf(a, 0.f);
    }
    __syncthreads();
    if (tid < 2) {
      float a2 = ls_b2[z * 2 + tid];
      for (int j = 0; j < 64; j++) a2 += t1[j] * ls_w2[(z * 2 + tid) * 64 + j];
      out[b * 16 + 9 + z * 2 + tid] = __expf(a2);
    }
  }
  __syncthreads();
  if (tid < 64) {
    float a = d_b1[tid];
    for (int j = 0; j < 64; j++) a += p[j] * d_w1[tid * 64 + j];
    t1[tid] = fmaxf(a, 0.f);
  }
  __syncthreads();
  if (tid == 0) {
    float a2 = d_b2[0];
    for (int j = 0; j < 64; j++) a2 += t1[j] * d_w2[j];
    out[b * 16 + 15] = 1.f / (1.f + __expf(-a2));
  }
}

extern "C" void kernel_launch(void* const* d_in, const int* in_sizes, int n_in,
                              void* d_out, int out_size, void* d_ws, size_t ws_size,
                              hipStream_t stream) {
  const float* wav       = (const float*)d_in[0];
  const int*   sid       = (const int*)d_in[1];
  const void*  mask      = d_in[2];
  const float* conv1_w   = (const float*)d_in[3];
  const float* conv1_b   = (const float*)d_in[4];
  const float* conv2_w   = (const float*)d_in[5];
  const float* conv2_b   = (const float*)d_in[6];
  const float* shank_emb = (const float*)d_in[7];
  const float* in_proj_w = (const float*)d_in[8];
  const float* in_proj_b = (const float*)d_in[9];
  const float* out_proj_w= (const float*)d_in[10];
  const float* out_proj_b= (const float*)d_in[11];
  const float* ln1_g     = (const float*)d_in[12];
  const float* ln1_b     = (const float*)d_in[13];
  const float* ff1_w     = (const float*)d_in[14];
  const float* ff1_b     = (const float*)d_in[15];
  const float* ff2_w     = (const float*)d_in[16];
  const float* ff2_b     = (const float*)d_in[17];
  const float* ln2_g     = (const float*)d_in[18];
  const float* ln2_b     = (const float*)d_in[19];
  const float* cls_w1    = (const float*)d_in[20];
  const float* cls_b1    = (const float*)d_in[21];
  const float* cls_w2    = (const float*)d_in[22];
  const float* cls_b2    = (const float*)d_in[23];
  const float* mu_w1     = (const float*)d_in[24];
  const float* mu_b1     = (const float*)d_in[25];
  const float* mu_w2     = (const float*)d_in[26];
  const float* mu_b2     = (const float*)d_in[27];
  const float* ls_w1     = (const float*)d_in[28];
  const float* ls_b1     = (const float*)d_in[29];
  const float* ls_w2     = (const float*)d_in[30];
  const float* ls_b2     = (const float*)d_in[31];
  const float* d_w1      = (const float*)d_in[32];
  const float* d_b1      = (const float*)d_in[33];
  const float* d_w2      = (const float*)d_in[34];
  const float* d_b2      = (const float*)d_in[35];
  float* out = (float*)d_out;

  float* ws = (float*)d_ws;
  float*          h     = ws;                                  // [32768,64] fp32
  unsigned short* hb    = (unsigned short*)(ws + 2097152);     // bf16 mirror
  unsigned short* obufb = (unsigned short*)(ws + 3145728);     // attn out bf16
  unsigned short* wb    = (unsigned short*)(ws + 4194304);     // prepped weights
  int*   ip     = (int*)(ws + 10493952);
  int*   flag   = ip;
  int*   counts = ip + 8;
  int*   lens   = ip + 16;
  int*   idxbuf = ip + 144;

  prep_all_kernel<<<664, 256, 0, stream>>>(in_proj_w, out_proj_w, ff1_w, ff2_w,
                                           conv1_w, conv2_w, wb,
                                           (const unsigned int*)mask, flag, counts, lens);
  init_bin_kernel<<<8192, 256, 0, stream>>>(sid, shank_emb, mask, flag, counts,
                                            lens, idxbuf, h, hb);
  conv_mfma_kernel<<<1280, 256, 0, stream>>>(idxbuf, counts, wav, wb, conv1_b, conv2_b,
                                             shank_emb, h, hb);
  for (int l = 0; l < 2; l++) {
    attn_fused_kernel<<<512, 256, 0, stream>>>(hb, wb + l * 12288,
                                               in_proj_b + l * 192, lens, obufb);
    fused_rl_kernel<<<512, 256, 0, stream>>>(
        obufb, h, hb,
        wb + 24576 + l * 4096, out_proj_b + l * 64,
        ln1_g + l * 64, ln1_b + l * 64,
        wb + 32768 + l * 16384, ff1_b + l * 256,
        wb + 65536 + l * 16384, ff2_b + l * 64,
        ln2_g + l * 64, ln2_b + l * 64);
  }
  pool_heads_kernel<<<128, 256, 0, stream>>>(h, lens, cls_w1, cls_b1, cls_w2, cls_b2,
                                             mu_w1, mu_b1, mu_w2, mu_b2,
                                             ls_w1, ls_b1, ls_w2, ls_b2,
                                             d_w1, d_b1, d_w2, d_b2, out);
}